// Round 4
// baseline (1535.145 us; speedup 1.0000x reference)
//
#include <hip/hip_runtime.h>

static constexpr int Wd  = 128;
static constexpr int Hd  = 128;
static constexpr int HWc = Wd * Hd;    // 16384
static constexpr int Cc  = 128;
static constexpr int NHc = 4;
static constexpr int Bc  = 2;

__device__ __forceinline__ int refl(int i, int L) {
    i = i < 0 ? -i : i;
    return i >= L ? 2 * (L - 1) - i : i;
}

// ---------------- Kernel A: depthwise 3x3 + bias + relu (zero padding) ----------------
__global__ __launch_bounds__(256) void dw_kernel(
    const float* __restrict__ vid,
    const float* __restrict__ wq, const float* __restrict__ bq,
    const float* __restrict__ wk, const float* __restrict__ bk,
    const float* __restrict__ wv, const float* __restrict__ bv,
    float* __restrict__ yq, float* __restrict__ yk, float* __restrict__ yv)
{
    int pix  = blockIdx.x * 256 + threadIdx.x;
    int bc   = blockIdx.y;           // b*C + c
    int conv = blockIdx.z;
    const float* wsel = conv == 0 ? wq : (conv == 1 ? wk : wv);
    const float* bsel = conv == 0 ? bq : (conv == 1 ? bk : bv);
    float* osel       = conv == 0 ? yq : (conv == 1 ? yk : yv);
    int c = bc & (Cc - 1);
    int y = pix >> 7, x = pix & (Wd - 1);
    const float* src = vid + (size_t)bc * HWc;
    const float* wp  = wsel + c * 9;
    float acc = 0.f;
    #pragma unroll
    for (int ky = 0; ky < 3; ++ky) {
        int iy = y + ky - 1;
        if (iy < 0 || iy >= Hd) continue;
        #pragma unroll
        for (int kx = 0; kx < 3; ++kx) {
            int ix = x + kx - 1;
            if (ix < 0 || ix >= Wd) continue;
            acc = fmaf(src[iy * Wd + ix], wp[ky * 3 + kx], acc);
        }
    }
    acc += bsel[c];
    osel[(size_t)bc * HWc + pix] = fmaxf(acc, 0.f);
}

// ---------------- Kernel B/D: pointwise GEMM, c-major in/out, in-place safe ----------
__global__ __launch_bounds__(256) void pw_kernel(
    const float* y0p, const float* y1p, const float* y2p,
    const float* __restrict__ w0,  const float* __restrict__ w1,  const float* __restrict__ w2,
    const float* __restrict__ b0,  const float* __restrict__ b1,  const float* __restrict__ b2,
    float* o0, float* o1, float* o2,
    float scale0)
{
    extern __shared__ float lds[];
    float* wl = lds;            // [64 cc][129]
    float* yl = lds + 8256;     // [64 cc][128 p]

    int z = blockIdx.z;
    const float* yin  = z == 0 ? y0p : (z == 1 ? y1p : y2p);
    const float* wmat = z == 0 ? w0  : (z == 1 ? w1  : w2);
    const float* bias = z == 0 ? b0  : (z == 1 ? b1  : b2);
    float* out        = z == 0 ? o0  : (z == 1 ? o1  : o2);
    float scale       = z == 0 ? scale0 : 1.f;

    int tid = threadIdx.x;
    int ot = tid & 15, pt = tid >> 4;
    int gp  = blockIdx.x * 128;
    int b   = gp >> 14;
    int pof = gp & (HWc - 1);
    const float* yb = yin + (size_t)b * Cc * HWc + pof;

    float acc[8][8];
    #pragma unroll
    for (int i = 0; i < 8; ++i)
        #pragma unroll
        for (int j = 0; j < 8; ++j) acc[i][j] = 0.f;

    for (int kh = 0; kh < 2; ++kh) {
        int c0 = kh * 64;
        for (int i = tid; i < 8192; i += 256) {
            int cc = i & 63, o = i >> 6;
            wl[cc * 129 + o] = wmat[o * 128 + c0 + cc];
        }
        for (int i = tid; i < 8192; i += 256) {
            int p = i & 127, cc = i >> 7;
            yl[cc * 128 + p] = yb[(size_t)(c0 + cc) * HWc + p];
        }
        __syncthreads();
        #pragma unroll 4
        for (int cc = 0; cc < 64; ++cc) {
            float wv[8], pv[8];
            #pragma unroll
            for (int oi = 0; oi < 8; ++oi) wv[oi] = wl[cc * 129 + oi * 16 + ot];
            #pragma unroll
            for (int pi = 0; pi < 8; ++pi) pv[pi] = yl[cc * 128 + pi * 16 + pt];
            #pragma unroll
            for (int oi = 0; oi < 8; ++oi)
                #pragma unroll
                for (int pi = 0; pi < 8; ++pi)
                    acc[oi][pi] = fmaf(wv[oi], pv[pi], acc[oi][pi]);
        }
        __syncthreads();
    }

    float bia[8];
    #pragma unroll
    for (int oi = 0; oi < 8; ++oi) bia[oi] = bias[oi * 16 + ot];

    #pragma unroll
    for (int oi = 0; oi < 8; ++oi)
        #pragma unroll
        for (int pi = 0; pi < 8; ++pi)
            lds[(pi * 16 + pt) * 133 + oi * 16 + ot] = (acc[oi][pi] + bia[oi]) * scale;
    __syncthreads();

    for (int i = tid; i < 16384; i += 256) {
        int p = i & 127, o = i >> 7;
        out[(size_t)b * Cc * HWc + (size_t)o * HWc + pof + p] = lds[p * 133 + o];
    }
}

// ---------------- Kernel C: neighborhood attention, split-channel ---------------------
// 512 threads: lane pair (2*pl, 2*pl+1) shares pixel pl; each handles 16 channels.
// q,k,v c-major (B,C,H,W); att in-place over q.
// __launch_bounds__(512, 2): cap 256 VGPR — kernel needs ~110 live regs (d[64]+rk[16]
// +acc[16]); the (512,4) variant forced VGPR=64 and spilled everything to scratch
// (FETCH 870 MB, WRITE 1.6 GB). Natural allocation <=128 still gives 4 waves/SIMD,
// matching the 76 KB LDS limit of 2 blocks/CU.
__global__ __launch_bounds__(512, 2) void attn_kernel(
    const float* q, const float* kk, const float* vv, float* att)
{
    extern __shared__ float lds[];   // [529 pix][36 floats] (144B pixel stride)
    int tid = threadIdx.x;
    int x0 = blockIdx.x * 16, y0 = blockIdx.y * 16;
    int bn = blockIdx.z;
    const float* kb = kk + (size_t)bn * 32 * HWc;
    const float* vb = vv + (size_t)bn * 32 * HWc;

    // ---- staging geometry: thread tid stages region pixel tid (+ tail 512..528)
    int sry = tid / 23, srx = tid - sry * 23;
    int sgo = refl(y0 - 4 + sry, Hd) * Wd + refl(x0 - 4 + srx, Wd);
    int t2 = tid + 512;
    int sry2 = t2 / 23, srx2 = t2 - sry2 * 23;
    int sgo2 = refl(y0 - 4 + sry2, Hd) * Wd + refl(x0 - 4 + srx2, Wd);
    bool tail = (tid < 529 - 512);

    // ---- compute geometry
    int half = tid & 1;            // which 16 channels
    int pl   = tid >> 1;           // pixel 0..255
    int px = pl & 15, py = pl >> 4;
    int gq = (y0 + py) * Wd + (x0 + px);
    int rbase = py * 23 + px;      // region idx of offset (dy=-4,dx=-4)
    float* myk = lds + rbase * 36 + half * 16;   // 4 quads at +0,4,8,12 floats

    // ================= stage K =================
    #pragma unroll
    for (int cbq = 0; cbq < 8; ++cbq) {
        float4 v;
        v.x = kb[(size_t)(cbq * 4 + 0) * HWc + sgo];
        v.y = kb[(size_t)(cbq * 4 + 1) * HWc + sgo];
        v.z = kb[(size_t)(cbq * 4 + 2) * HWc + sgo];
        v.w = kb[(size_t)(cbq * 4 + 3) * HWc + sgo];
        *(float4*)(lds + tid * 36 + cbq * 4) = v;
    }
    if (tail) {
        #pragma unroll
        for (int cbq = 0; cbq < 8; ++cbq) {
            float4 v;
            v.x = kb[(size_t)(cbq * 4 + 0) * HWc + sgo2];
            v.y = kb[(size_t)(cbq * 4 + 1) * HWc + sgo2];
            v.z = kb[(size_t)(cbq * 4 + 2) * HWc + sgo2];
            v.w = kb[(size_t)(cbq * 4 + 3) * HWc + sgo2];
            *(float4*)(lds + t2 * 36 + cbq * 4) = v;
        }
    }
    __syncthreads();

    // ================= QK over my 16 channels =================
    float d[64];
    #pragma unroll
    for (int i = 0; i < 64; ++i) d[i] = 0.f;
    {
        const float* qp = q + (size_t)(bn * 32 + half * 16) * HWc + gq;
        #pragma unroll
        for (int cbq = 0; cbq < 4; ++cbq) {
            float4 q4;
            q4.x = qp[(size_t)(cbq * 4 + 0) * HWc];
            q4.y = qp[(size_t)(cbq * 4 + 1) * HWc];
            q4.z = qp[(size_t)(cbq * 4 + 2) * HWc];
            q4.w = qp[(size_t)(cbq * 4 + 3) * HWc];
            #pragma unroll
            for (int off = 0; off < 64; ++off) {
                int dy = off >> 3, dx = off & 7;
                const float4 kv = *(const float4*)(myk + (dy * 23 + dx) * 36 + cbq * 4);
                d[off] = fmaf(q4.x, kv.x, fmaf(q4.y, kv.y, fmaf(q4.z, kv.z, fmaf(q4.w, kv.w, d[off]))));
            }
        }
    }
    __syncthreads();   // all QK reads done before V overwrites

    // ================= stage V (overlaps following VALU) =================
    #pragma unroll
    for (int cbq = 0; cbq < 8; ++cbq) {
        float4 v;
        v.x = vb[(size_t)(cbq * 4 + 0) * HWc + sgo];
        v.y = vb[(size_t)(cbq * 4 + 1) * HWc + sgo];
        v.z = vb[(size_t)(cbq * 4 + 2) * HWc + sgo];
        v.w = vb[(size_t)(cbq * 4 + 3) * HWc + sgo];
        *(float4*)(lds + tid * 36 + cbq * 4) = v;
    }
    if (tail) {
        #pragma unroll
        for (int cbq = 0; cbq < 8; ++cbq) {
            float4 v;
            v.x = vb[(size_t)(cbq * 4 + 0) * HWc + sgo2];
            v.y = vb[(size_t)(cbq * 4 + 1) * HWc + sgo2];
            v.z = vb[(size_t)(cbq * 4 + 2) * HWc + sgo2];
            v.w = vb[(size_t)(cbq * 4 + 3) * HWc + sgo2];
            *(float4*)(lds + t2 * 36 + cbq * 4) = v;
        }
    }

    // ---- combine channel halves (lane^1 shares the pixel) — DPP, no LDS
    #pragma unroll
    for (int i = 0; i < 64; ++i) d[i] += __shfl_xor(d[i], 1);

    // ---- top-16 ranking (lower index wins ties == lax.top_k), packed ranks
    unsigned rk[16];
    #pragma unroll
    for (int i = 0; i < 16; ++i) rk[i] = 0u;
    #pragma unroll
    for (int i = 0; i < 63; ++i) {
        #pragma unroll
        for (int j = i + 1; j < 64; ++j) {
            bool ge = d[i] >= d[j];
            rk[i >> 2] += ge ? 0u : (1u << (8 * (i & 3)));
            rk[j >> 2] += ge ? (1u << (8 * (j & 3))) : 0u;
        }
    }
    float m = d[0];
    #pragma unroll
    for (int i = 1; i < 64; ++i) m = fmaxf(m, d[i]);
    float s = 0.f;
    #pragma unroll
    for (int i = 0; i < 64; ++i) {
        unsigned r = (rk[i >> 2] >> (8 * (i & 3))) & 255u;
        float e = (r < 16u) ? __expf(d[i] - m) : 0.f;
        d[i] = e;
        s += e;
    }
    float inv = 1.0f / s;
    __syncthreads();   // V fully staged

    // ================= PV over my 16 channels =================
    float acc[16];
    #pragma unroll
    for (int c = 0; c < 16; ++c) acc[c] = 0.f;
    #pragma unroll
    for (int cbq = 0; cbq < 4; ++cbq) {
        #pragma unroll
        for (int off = 0; off < 64; ++off) {
            int dy = off >> 3, dx = off & 7;
            const float4 vv4 = *(const float4*)(myk + (dy * 23 + dx) * 36 + cbq * 4);
            float wg = d[off];
            acc[cbq*4+0] = fmaf(wg, vv4.x, acc[cbq*4+0]);
            acc[cbq*4+1] = fmaf(wg, vv4.y, acc[cbq*4+1]);
            acc[cbq*4+2] = fmaf(wg, vv4.z, acc[cbq*4+2]);
            acc[cbq*4+3] = fmaf(wg, vv4.w, acc[cbq*4+3]);
        }
    }

    float* op = att + (size_t)(bn * 32 + half * 16) * HWc + gq;
    #pragma unroll
    for (int c = 0; c < 16; ++c) op[(size_t)c * HWc] = acc[c] * inv;
}

// ---------------------------------- launcher ------------------------------------------
extern "C" void kernel_launch(void* const* d_in, const int* in_sizes, int n_in,
                              void* d_out, int out_size, void* d_ws, size_t ws_size,
                              hipStream_t stream)
{
    const float* vid  = (const float*)d_in[0];
    const float* qdww = (const float*)d_in[1];
    const float* qdwb = (const float*)d_in[2];
    const float* qpww = (const float*)d_in[3];
    const float* qpwb = (const float*)d_in[4];
    const float* kdww = (const float*)d_in[5];
    const float* kdwb = (const float*)d_in[6];
    const float* kpww = (const float*)d_in[7];
    const float* kpwb = (const float*)d_in[8];
    const float* vdww = (const float*)d_in[9];
    const float* vdwb = (const float*)d_in[10];
    const float* vpww = (const float*)d_in[11];
    const float* vpwb = (const float*)d_in[12];
    const float* pjw  = (const float*)d_in[13];
    const float* pjb  = (const float*)d_in[14];

    float* ws = (float*)d_ws;
    const size_t SZ = (size_t)Bc * Cc * HWc;   // 16 MB each
    float* buf0 = ws;            // q-dw -> q -> att
    float* buf1 = ws + SZ;       // k-dw -> k
    float* buf2 = ws + 2 * SZ;   // v-dw -> v

    hipFuncSetAttribute((const void*)pw_kernel,   hipFuncAttributeMaxDynamicSharedMemorySize, 68096);
    hipFuncSetAttribute((const void*)attn_kernel, hipFuncAttributeMaxDynamicSharedMemorySize, 76176);

    dw_kernel<<<dim3(HWc / 256, Bc * Cc, 3), 256, 0, stream>>>(
        vid, qdww, qdwb, kdww, kdwb, vdww, vdwb, buf0, buf1, buf2);

    const float scale = 0.17677669529663687f;
    pw_kernel<<<dim3((Bc * HWc) / 128, 1, 3), 256, 68096, stream>>>(
        buf0, buf1, buf2, qpww, kpww, vpww, qpwb, kpwb, vpwb, buf0, buf1, buf2, scale);

    attn_kernel<<<dim3(Wd / 16, Hd / 16, Bc * NHc), 512, 76176, stream>>>(buf0, buf1, buf2, buf0);

    pw_kernel<<<dim3((Bc * HWc) / 128, 1, 1), 256, 68096, stream>>>(
        buf0, buf0, buf0, pjw, pjw, pjw, pjb, pjb, pjb, (float*)d_out, (float*)d_out, (float*)d_out, 1.f);
}

// Round 5
// 1340.823 us; speedup vs baseline: 1.1449x; 1.1449x over previous
//
#include <hip/hip_runtime.h>

static constexpr int Wd  = 128;
static constexpr int Hd  = 128;
static constexpr int HWc = Wd * Hd;    // 16384
static constexpr int Cc  = 128;
static constexpr int NHc = 4;
static constexpr int Bc  = 2;

__device__ __forceinline__ int refl(int i, int L) {
    i = i < 0 ? -i : i;
    return i >= L ? 2 * (L - 1) - i : i;
}

// ---------------- Kernel A: depthwise 3x3 + bias + relu (zero padding) ----------------
__global__ __launch_bounds__(256) void dw_kernel(
    const float* __restrict__ vid,
    const float* __restrict__ wq, const float* __restrict__ bq,
    const float* __restrict__ wk, const float* __restrict__ bk,
    const float* __restrict__ wv, const float* __restrict__ bv,
    float* __restrict__ yq, float* __restrict__ yk, float* __restrict__ yv)
{
    int pix  = blockIdx.x * 256 + threadIdx.x;
    int bc   = blockIdx.y;           // b*C + c
    int conv = blockIdx.z;
    const float* wsel = conv == 0 ? wq : (conv == 1 ? wk : wv);
    const float* bsel = conv == 0 ? bq : (conv == 1 ? bk : bv);
    float* osel       = conv == 0 ? yq : (conv == 1 ? yk : yv);
    int c = bc & (Cc - 1);
    int y = pix >> 7, x = pix & (Wd - 1);
    const float* src = vid + (size_t)bc * HWc;
    const float* wp  = wsel + c * 9;
    float acc = 0.f;
    #pragma unroll
    for (int ky = 0; ky < 3; ++ky) {
        int iy = y + ky - 1;
        if (iy < 0 || iy >= Hd) continue;
        #pragma unroll
        for (int kx = 0; kx < 3; ++kx) {
            int ix = x + kx - 1;
            if (ix < 0 || ix >= Wd) continue;
            acc = fmaf(src[iy * Wd + ix], wp[ky * 3 + kx], acc);
        }
    }
    acc += bsel[c];
    osel[(size_t)bc * HWc + pix] = fmaxf(acc, 0.f);
}

// ---------------- Kernel B/D: pointwise GEMM, c-major in/out, in-place safe ----------
__global__ __launch_bounds__(256) void pw_kernel(
    const float* y0p, const float* y1p, const float* y2p,
    const float* __restrict__ w0,  const float* __restrict__ w1,  const float* __restrict__ w2,
    const float* __restrict__ b0,  const float* __restrict__ b1,  const float* __restrict__ b2,
    float* o0, float* o1, float* o2,
    float scale0)
{
    extern __shared__ float lds[];
    float* wl = lds;            // [64 cc][129]
    float* yl = lds + 8256;     // [64 cc][128 p]

    int z = blockIdx.z;
    const float* yin  = z == 0 ? y0p : (z == 1 ? y1p : y2p);
    const float* wmat = z == 0 ? w0  : (z == 1 ? w1  : w2);
    const float* bias = z == 0 ? b0  : (z == 1 ? b1  : b2);
    float* out        = z == 0 ? o0  : (z == 1 ? o1  : o2);
    float scale       = z == 0 ? scale0 : 1.f;

    int tid = threadIdx.x;
    int ot = tid & 15, pt = tid >> 4;
    int gp  = blockIdx.x * 128;
    int b   = gp >> 14;
    int pof = gp & (HWc - 1);
    const float* yb = yin + (size_t)b * Cc * HWc + pof;

    float acc[8][8];
    #pragma unroll
    for (int i = 0; i < 8; ++i)
        #pragma unroll
        for (int j = 0; j < 8; ++j) acc[i][j] = 0.f;

    for (int kh = 0; kh < 2; ++kh) {
        int c0 = kh * 64;
        for (int i = tid; i < 8192; i += 256) {
            int cc = i & 63, o = i >> 6;
            wl[cc * 129 + o] = wmat[o * 128 + c0 + cc];
        }
        for (int i = tid; i < 8192; i += 256) {
            int p = i & 127, cc = i >> 7;
            yl[cc * 128 + p] = yb[(size_t)(c0 + cc) * HWc + p];
        }
        __syncthreads();
        #pragma unroll 4
        for (int cc = 0; cc < 64; ++cc) {
            float wv[8], pv[8];
            #pragma unroll
            for (int oi = 0; oi < 8; ++oi) wv[oi] = wl[cc * 129 + oi * 16 + ot];
            #pragma unroll
            for (int pi = 0; pi < 8; ++pi) pv[pi] = yl[cc * 128 + pi * 16 + pt];
            #pragma unroll
            for (int oi = 0; oi < 8; ++oi)
                #pragma unroll
                for (int pi = 0; pi < 8; ++pi)
                    acc[oi][pi] = fmaf(wv[oi], pv[pi], acc[oi][pi]);
        }
        __syncthreads();
    }

    float bia[8];
    #pragma unroll
    for (int oi = 0; oi < 8; ++oi) bia[oi] = bias[oi * 16 + ot];

    #pragma unroll
    for (int oi = 0; oi < 8; ++oi)
        #pragma unroll
        for (int pi = 0; pi < 8; ++pi)
            lds[(pi * 16 + pt) * 133 + oi * 16 + ot] = (acc[oi][pi] + bia[oi]) * scale;
    __syncthreads();

    for (int i = tid; i < 16384; i += 256) {
        int p = i & 127, o = i >> 7;
        out[(size_t)b * Cc * HWc + (size_t)o * HWc + pof + p] = lds[p * 133 + o];
    }
}

// ---------------- Kernel C: neighborhood attention, split-OFFSET ----------------------
// 512 threads; lane pair (2*pl, 2*pl+1) shares pixel pl. Even lane owns window offsets
// 0..31 (dy 0..3), odd owns 32..63 (dy 4..7); each computes its 32 dists over ALL 32
// channels (q loaded transiently per quad). Peak live state: PV w[32]+acc[32] ~ 90 regs
// -> genuinely fits the 128-VGPR tier (4 waves/SIMD) with NO spill. Round-4 lesson:
// capping VGPRs below the kernel's real pressure (150) just converts regs to scratch
// traffic (1.9 GB writes); this restructure reduces the real pressure instead.
__global__ __launch_bounds__(512, 2) void attn_kernel(
    const float* q, const float* kk, const float* vv, float* att)
{
    extern __shared__ float lds[];   // [529 pix][36 floats] (144B pixel stride)
    int tid = threadIdx.x;
    int x0 = blockIdx.x * 16, y0 = blockIdx.y * 16;
    int bn = blockIdx.z;
    const float* kb = kk + (size_t)bn * 32 * HWc;
    const float* vb = vv + (size_t)bn * 32 * HWc;

    // ---- staging geometry: thread tid stages region pixel tid (+ tail 512..528)
    int sry = tid / 23, srx = tid - sry * 23;
    int sgo = refl(y0 - 4 + sry, Hd) * Wd + refl(x0 - 4 + srx, Wd);
    int t2 = tid + 512;
    int sry2 = t2 / 23, srx2 = t2 - sry2 * 23;
    int sgo2 = refl(y0 - 4 + sry2, Hd) * Wd + refl(x0 - 4 + srx2, Wd);
    bool tail = (tid < 529 - 512);

    // ---- compute geometry
    int half = tid & 1;            // 0: offsets 0..31 (dy 0..3); 1: offsets 32..63
    int pl   = tid >> 1;           // pixel 0..255
    int px = pl & 15, py = pl >> 4;
    int gq = (y0 + py) * Wd + (x0 + px);
    // region base for my offset half: (dy=half*4, dx=0) relative to (py,px)
    float* myr = lds + ((py + half * 4) * 23 + px) * 36;

    // ================= stage K =================
    #pragma unroll
    for (int cbq = 0; cbq < 8; ++cbq) {
        float4 v;
        v.x = kb[(size_t)(cbq * 4 + 0) * HWc + sgo];
        v.y = kb[(size_t)(cbq * 4 + 1) * HWc + sgo];
        v.z = kb[(size_t)(cbq * 4 + 2) * HWc + sgo];
        v.w = kb[(size_t)(cbq * 4 + 3) * HWc + sgo];
        *(float4*)(lds + tid * 36 + cbq * 4) = v;
    }
    if (tail) {
        #pragma unroll
        for (int cbq = 0; cbq < 8; ++cbq) {
            float4 v;
            v.x = kb[(size_t)(cbq * 4 + 0) * HWc + sgo2];
            v.y = kb[(size_t)(cbq * 4 + 1) * HWc + sgo2];
            v.z = kb[(size_t)(cbq * 4 + 2) * HWc + sgo2];
            v.w = kb[(size_t)(cbq * 4 + 3) * HWc + sgo2];
            *(float4*)(lds + t2 * 36 + cbq * 4) = v;
        }
    }
    __syncthreads();

    // ================= QK: my 32 offsets x all 32 channels =================
    float d[32];
    #pragma unroll
    for (int i = 0; i < 32; ++i) d[i] = 0.f;
    {
        const float* qp = q + (size_t)(bn * 32) * HWc + gq;
        #pragma unroll
        for (int cq = 0; cq < 8; ++cq) {
            float4 q4;
            q4.x = qp[(size_t)(cq * 4 + 0) * HWc];
            q4.y = qp[(size_t)(cq * 4 + 1) * HWc];
            q4.z = qp[(size_t)(cq * 4 + 2) * HWc];
            q4.w = qp[(size_t)(cq * 4 + 3) * HWc];
            #pragma unroll
            for (int off = 0; off < 32; ++off) {
                int dy = off >> 3, dx = off & 7;
                const float4 kv = *(const float4*)(myr + (dy * 23 + dx) * 36 + cq * 4);
                d[off] = fmaf(q4.x, kv.x, fmaf(q4.y, kv.y, fmaf(q4.z, kv.z, fmaf(q4.w, kv.w, d[off]))));
            }
        }
    }
    __syncthreads();   // all QK reads done before V overwrites

    // ================= stage V (overlaps ranking VALU below) =================
    #pragma unroll
    for (int cbq = 0; cbq < 8; ++cbq) {
        float4 v;
        v.x = vb[(size_t)(cbq * 4 + 0) * HWc + sgo];
        v.y = vb[(size_t)(cbq * 4 + 1) * HWc + sgo];
        v.z = vb[(size_t)(cbq * 4 + 2) * HWc + sgo];
        v.w = vb[(size_t)(cbq * 4 + 3) * HWc + sgo];
        *(float4*)(lds + tid * 36 + cbq * 4) = v;
    }
    if (tail) {
        #pragma unroll
        for (int cbq = 0; cbq < 8; ++cbq) {
            float4 v;
            v.x = vb[(size_t)(cbq * 4 + 0) * HWc + sgo2];
            v.y = vb[(size_t)(cbq * 4 + 1) * HWc + sgo2];
            v.z = vb[(size_t)(cbq * 4 + 2) * HWc + sgo2];
            v.w = vb[(size_t)(cbq * 4 + 3) * HWc + sgo2];
            *(float4*)(lds + t2 * 36 + cbq * 4) = v;
        }
    }

    // ================= cooperative top-16 ranking (exact lax.top_k ties) =========
    // global rank of i = #{j: d[j]>d[i]} + #{j<i: d[j]==d[i]}; selected iff rank<16.
    unsigned rk[8];
    #pragma unroll
    for (int i = 0; i < 8; ++i) rk[i] = 0u;
    // within my 32 (my indices are consecutive; i<j in-half => global i<j)
    #pragma unroll
    for (int i = 0; i < 31; ++i) {
        #pragma unroll
        for (int j = i + 1; j < 32; ++j) {
            bool ge = d[i] >= d[j];
            rk[i >> 2] += ge ? 0u : (1u << (8 * (i & 3)));
            rk[j >> 2] += ge ? (1u << (8 * (j & 3))) : 0u;
        }
    }
    // cross-half: partner's 32 values, one shuffle each.
    // even lane (global idx low): partner (higher idx) beats me only on strict >
    // odd  lane (global idx high): partner (lower idx) beats me on >=
    #pragma unroll
    for (int j = 0; j < 32; ++j) {
        float dp = __shfl_xor(d[j], 1);
        #pragma unroll
        for (int i = 0; i < 32; ++i) {
            bool beat = (dp > d[i]) || (half && (dp == d[i]));
            rk[i >> 2] += beat ? (1u << (8 * (i & 3))) : 0u;
        }
    }

    // ================= softmax over the selected 16 (pairwise reduce) ============
    float m = d[0];
    #pragma unroll
    for (int i = 1; i < 32; ++i) m = fmaxf(m, d[i]);
    m = fmaxf(m, __shfl_xor(m, 1));
    float s = 0.f;
    #pragma unroll
    for (int i = 0; i < 32; ++i) {
        unsigned r = (rk[i >> 2] >> (8 * (i & 3))) & 255u;
        float e = (r < 16u) ? __expf(d[i] - m) : 0.f;
        d[i] = e;                    // d[] now holds unnormalized weights
        s += e;
    }
    s += __shfl_xor(s, 1);
    float inv = 1.0f / s;
    __syncthreads();   // V fully staged

    // ================= PV: my 32 offsets, ALL 32 channels =================
    float acc[32];
    #pragma unroll
    for (int c = 0; c < 32; ++c) acc[c] = 0.f;
    #pragma unroll
    for (int cq = 0; cq < 8; ++cq) {
        #pragma unroll
        for (int off = 0; off < 32; ++off) {
            int dy = off >> 3, dx = off & 7;
            const float4 vv4 = *(const float4*)(myr + (dy * 23 + dx) * 36 + cq * 4);
            float wg = d[off];
            acc[cq*4+0] = fmaf(wg, vv4.x, acc[cq*4+0]);
            acc[cq*4+1] = fmaf(wg, vv4.y, acc[cq*4+1]);
            acc[cq*4+2] = fmaf(wg, vv4.z, acc[cq*4+2]);
            acc[cq*4+3] = fmaf(wg, vv4.w, acc[cq*4+3]);
        }
    }

    // combine offset halves per channel; even lane stores c 0..15, odd c 16..31
    float* op = att + (size_t)(bn * 32) * HWc + gq;
    #pragma unroll
    for (int c = 0; c < 32; ++c) {
        float tot = acc[c] + __shfl_xor(acc[c], 1);
        if ((c >> 4) == half) op[(size_t)c * HWc] = tot * inv;
    }
}

// ---------------------------------- launcher ------------------------------------------
extern "C" void kernel_launch(void* const* d_in, const int* in_sizes, int n_in,
                              void* d_out, int out_size, void* d_ws, size_t ws_size,
                              hipStream_t stream)
{
    const float* vid  = (const float*)d_in[0];
    const float* qdww = (const float*)d_in[1];
    const float* qdwb = (const float*)d_in[2];
    const float* qpww = (const float*)d_in[3];
    const float* qpwb = (const float*)d_in[4];
    const float* kdww = (const float*)d_in[5];
    const float* kdwb = (const float*)d_in[6];
    const float* kpww = (const float*)d_in[7];
    const float* kpwb = (const float*)d_in[8];
    const float* vdww = (const float*)d_in[9];
    const float* vdwb = (const float*)d_in[10];
    const float* vpww = (const float*)d_in[11];
    const float* vpwb = (const float*)d_in[12];
    const float* pjw  = (const float*)d_in[13];
    const float* pjb  = (const float*)d_in[14];

    float* ws = (float*)d_ws;
    const size_t SZ = (size_t)Bc * Cc * HWc;   // 16 MB each
    float* buf0 = ws;            // q-dw -> q -> att
    float* buf1 = ws + SZ;       // k-dw -> k
    float* buf2 = ws + 2 * SZ;   // v-dw -> v

    hipFuncSetAttribute((const void*)pw_kernel,   hipFuncAttributeMaxDynamicSharedMemorySize, 68096);
    hipFuncSetAttribute((const void*)attn_kernel, hipFuncAttributeMaxDynamicSharedMemorySize, 76176);

    dw_kernel<<<dim3(HWc / 256, Bc * Cc, 3), 256, 0, stream>>>(
        vid, qdww, qdwb, kdww, kdwb, vdww, vdwb, buf0, buf1, buf2);

    const float scale = 0.17677669529663687f;
    pw_kernel<<<dim3((Bc * HWc) / 128, 1, 3), 256, 68096, stream>>>(
        buf0, buf1, buf2, qpww, kpww, vpww, qpwb, kpwb, vpwb, buf0, buf1, buf2, scale);

    attn_kernel<<<dim3(Wd / 16, Hd / 16, Bc * NHc), 512, 76176, stream>>>(buf0, buf1, buf2, buf0);

    pw_kernel<<<dim3((Bc * HWc) / 128, 1, 1), 256, 68096, stream>>>(
        buf0, buf0, buf0, pjw, pjw, pjw, pjb, pjb, pjb, (float*)d_out, (float*)d_out, (float*)d_out, 1.f);
}

// Round 6
// 976.799 us; speedup vs baseline: 1.5716x; 1.3727x over previous
//
#include <hip/hip_runtime.h>

static constexpr int Wd  = 128;
static constexpr int Hd  = 128;
static constexpr int HWc = Wd * Hd;    // 16384
static constexpr int Cc  = 128;
static constexpr int NHc = 4;
static constexpr int Bc  = 2;

__device__ __forceinline__ int refl(int i, int L) {
    i = i < 0 ? -i : i;
    return i >= L ? 2 * (L - 1) - i : i;
}

// ---------------- Kernel A: depthwise 3x3 + bias + relu (zero padding) ----------------
__global__ __launch_bounds__(256) void dw_kernel(
    const float* __restrict__ vid,
    const float* __restrict__ wq, const float* __restrict__ bq,
    const float* __restrict__ wk, const float* __restrict__ bk,
    const float* __restrict__ wv, const float* __restrict__ bv,
    float* __restrict__ yq, float* __restrict__ yk, float* __restrict__ yv)
{
    int pix  = blockIdx.x * 256 + threadIdx.x;
    int bc   = blockIdx.y;           // b*C + c
    int conv = blockIdx.z;
    const float* wsel = conv == 0 ? wq : (conv == 1 ? wk : wv);
    const float* bsel = conv == 0 ? bq : (conv == 1 ? bk : bv);
    float* osel       = conv == 0 ? yq : (conv == 1 ? yk : yv);
    int c = bc & (Cc - 1);
    int y = pix >> 7, x = pix & (Wd - 1);
    const float* src = vid + (size_t)bc * HWc;
    const float* wp  = wsel + c * 9;
    float acc = 0.f;
    #pragma unroll
    for (int ky = 0; ky < 3; ++ky) {
        int iy = y + ky - 1;
        if (iy < 0 || iy >= Hd) continue;
        #pragma unroll
        for (int kx = 0; kx < 3; ++kx) {
            int ix = x + kx - 1;
            if (ix < 0 || ix >= Wd) continue;
            acc = fmaf(src[iy * Wd + ix], wp[ky * 3 + kx], acc);
        }
    }
    acc += bsel[c];
    osel[(size_t)bc * HWc + pix] = fmaxf(acc, 0.f);
}

// ---------------- Kernel B/D: pointwise GEMM, c-major in/out, in-place safe ----------
__global__ __launch_bounds__(256) void pw_kernel(
    const float* y0p, const float* y1p, const float* y2p,
    const float* __restrict__ w0,  const float* __restrict__ w1,  const float* __restrict__ w2,
    const float* __restrict__ b0,  const float* __restrict__ b1,  const float* __restrict__ b2,
    float* o0, float* o1, float* o2,
    float scale0)
{
    extern __shared__ float lds[];
    float* wl = lds;            // [64 cc][129]
    float* yl = lds + 8256;     // [64 cc][128 p]

    int z = blockIdx.z;
    const float* yin  = z == 0 ? y0p : (z == 1 ? y1p : y2p);
    const float* wmat = z == 0 ? w0  : (z == 1 ? w1  : w2);
    const float* bias = z == 0 ? b0  : (z == 1 ? b1  : b2);
    float* out        = z == 0 ? o0  : (z == 1 ? o1  : o2);
    float scale       = z == 0 ? scale0 : 1.f;

    int tid = threadIdx.x;
    int ot = tid & 15, pt = tid >> 4;
    int gp  = blockIdx.x * 128;
    int b   = gp >> 14;
    int pof = gp & (HWc - 1);
    const float* yb = yin + (size_t)b * Cc * HWc + pof;

    float acc[8][8];
    #pragma unroll
    for (int i = 0; i < 8; ++i)
        #pragma unroll
        for (int j = 0; j < 8; ++j) acc[i][j] = 0.f;

    for (int kh = 0; kh < 2; ++kh) {
        int c0 = kh * 64;
        for (int i = tid; i < 8192; i += 256) {
            int cc = i & 63, o = i >> 6;
            wl[cc * 129 + o] = wmat[o * 128 + c0 + cc];
        }
        for (int i = tid; i < 8192; i += 256) {
            int p = i & 127, cc = i >> 7;
            yl[cc * 128 + p] = yb[(size_t)(c0 + cc) * HWc + p];
        }
        __syncthreads();
        #pragma unroll 4
        for (int cc = 0; cc < 64; ++cc) {
            float wv[8], pv[8];
            #pragma unroll
            for (int oi = 0; oi < 8; ++oi) wv[oi] = wl[cc * 129 + oi * 16 + ot];
            #pragma unroll
            for (int pi = 0; pi < 8; ++pi) pv[pi] = yl[cc * 128 + pi * 16 + pt];
            #pragma unroll
            for (int oi = 0; oi < 8; ++oi)
                #pragma unroll
                for (int pi = 0; pi < 8; ++pi)
                    acc[oi][pi] = fmaf(wv[oi], pv[pi], acc[oi][pi]);
        }
        __syncthreads();
    }

    float bia[8];
    #pragma unroll
    for (int oi = 0; oi < 8; ++oi) bia[oi] = bias[oi * 16 + ot];

    #pragma unroll
    for (int oi = 0; oi < 8; ++oi)
        #pragma unroll
        for (int pi = 0; pi < 8; ++pi)
            lds[(pi * 16 + pt) * 133 + oi * 16 + ot] = (acc[oi][pi] + bia[oi]) * scale;
    __syncthreads();

    for (int i = tid; i < 16384; i += 256) {
        int p = i & 127, o = i >> 7;
        out[(size_t)b * Cc * HWc + (size_t)o * HWc + pof + p] = lds[p * 133 + o];
    }
}

// ---------------- Kernel C: neighborhood attention, quarter-lane split ----------------
// 8x8 pixel tile, 256 threads. Lane QUAD shares pixel pl = tid>>2; lane q = tid&3 owns
// window offsets q*16..q*16+15 (rows dy = 2q, 2q+1) over ALL 32 channels.
// Core state d[16]+rk[4]+acc[32] ~ 90 regs -> fits the 128-VGPR tier (4 waves/SIMD)
// WITHOUT spilling (rounds 3-5 lesson: capping below real pressure = scratch traffic).
// Region 15x15 x 32ch, stride 36 floats -> LDS 32.4 KB -> 4 blocks/CU.
__global__ __launch_bounds__(256, 4) void attn_kernel(
    const float* q, const float* kk, const float* vv, float* att)
{
    __shared__ float lds[225 * 36];  // [225 region pix][36] (144B pixel stride)
    int tid = threadIdx.x;
    int x0 = blockIdx.x * 8, y0 = blockIdx.y * 8;
    int bn = blockIdx.z;
    const float* kb = kk + (size_t)bn * 32 * HWc;
    const float* vb = vv + (size_t)bn * 32 * HWc;

    // ---- compute geometry
    int qq = tid & 3;              // offset quarter (rows 2q, 2q+1)
    int pl = tid >> 2;             // pixel 0..63
    int px = pl & 7, py = pl >> 3;
    int gq = (y0 + py) * Wd + (x0 + px);
    // region base for my quarter: (dy=2q, dx=0) relative to (py,px); region origin -4
    float* myr = lds + ((py + 2 * qq) * 15 + px) * 36;

    // ================= stage K (225 pix x 8 quads = 1800 units) =================
    for (int u = tid; u < 1800; u += 256) {
        int pix = u >> 3, cb = u & 7;
        int ry = pix / 15, rx = pix - ry * 15;
        int go = refl(y0 - 4 + ry, Hd) * Wd + refl(x0 - 4 + rx, Wd);
        float4 v;
        v.x = kb[(size_t)(cb * 4 + 0) * HWc + go];
        v.y = kb[(size_t)(cb * 4 + 1) * HWc + go];
        v.z = kb[(size_t)(cb * 4 + 2) * HWc + go];
        v.w = kb[(size_t)(cb * 4 + 3) * HWc + go];
        *(float4*)(lds + pix * 36 + cb * 4) = v;
    }
    __syncthreads();

    // ================= QK: my 16 offsets x all 32 channels =================
    float d[16];
    #pragma unroll
    for (int i = 0; i < 16; ++i) d[i] = 0.f;
    {
        const float* qp = q + (size_t)(bn * 32) * HWc + gq;
        #pragma unroll
        for (int cq = 0; cq < 8; ++cq) {
            float4 q4;
            q4.x = qp[(size_t)(cq * 4 + 0) * HWc];
            q4.y = qp[(size_t)(cq * 4 + 1) * HWc];
            q4.z = qp[(size_t)(cq * 4 + 2) * HWc];
            q4.w = qp[(size_t)(cq * 4 + 3) * HWc];
            #pragma unroll
            for (int t = 0; t < 16; ++t) {
                int dyl = t >> 3, dx = t & 7;
                const float4 kv = *(const float4*)(myr + (dyl * 15 + dx) * 36 + cq * 4);
                d[t] = fmaf(q4.x, kv.x, fmaf(q4.y, kv.y, fmaf(q4.z, kv.z, fmaf(q4.w, kv.w, d[t]))));
            }
        }
    }
    __syncthreads();   // all QK reads done before V overwrites

    // ================= stage V (latency overlaps ranking below) =================
    for (int u = tid; u < 1800; u += 256) {
        int pix = u >> 3, cb = u & 7;
        int ry = pix / 15, rx = pix - ry * 15;
        int go = refl(y0 - 4 + ry, Hd) * Wd + refl(x0 - 4 + rx, Wd);
        float4 v;
        v.x = vb[(size_t)(cb * 4 + 0) * HWc + go];
        v.y = vb[(size_t)(cb * 4 + 1) * HWc + go];
        v.z = vb[(size_t)(cb * 4 + 2) * HWc + go];
        v.w = vb[(size_t)(cb * 4 + 3) * HWc + go];
        *(float4*)(lds + pix * 36 + cb * 4) = v;
    }

    // ================= cooperative top-16 ranking (exact lax.top_k ties) =========
    // rank(i) = #{j: d_j > d_i} + #{j<i globally: d_j == d_i}; selected iff rank<16.
    unsigned rk[4];
    #pragma unroll
    for (int i = 0; i < 4; ++i) rk[i] = 0u;
    // within my 16 (consecutive global indices)
    #pragma unroll
    for (int i = 0; i < 15; ++i) {
        #pragma unroll
        for (int j = i + 1; j < 16; ++j) {
            bool ge = d[i] >= d[j];
            rk[i >> 2] += ge ? 0u : (1u << (8 * (i & 3)));
            rk[j >> 2] += ge ? (1u << (8 * (j & 3))) : 0u;
        }
    }
    // cross-quad: partner q^m; partner's indices lower iff (q & msb(m)).
    #pragma unroll
    for (int m = 1; m <= 3; ++m) {
        bool plow = (m == 1) ? ((qq & 1) != 0) : ((qq & 2) != 0);
        #pragma unroll
        for (int j = 0; j < 16; ++j) {
            float dp = __shfl_xor(d[j], m);
            #pragma unroll
            for (int i = 0; i < 16; ++i) {
                bool beat = (dp > d[i]) || (plow && (dp == d[i]));
                rk[i >> 2] += beat ? (1u << (8 * (i & 3))) : 0u;
            }
        }
    }

    // ================= softmax over the selected 16 (quad butterfly) ============
    float mx = d[0];
    #pragma unroll
    for (int i = 1; i < 16; ++i) mx = fmaxf(mx, d[i]);
    mx = fmaxf(mx, __shfl_xor(mx, 1));
    mx = fmaxf(mx, __shfl_xor(mx, 2));
    float s = 0.f;
    #pragma unroll
    for (int i = 0; i < 16; ++i) {
        unsigned r = (rk[i >> 2] >> (8 * (i & 3))) & 255u;
        float e = (r < 16u) ? __expf(d[i] - mx) : 0.f;
        d[i] = e;                    // d[] now holds unnormalized weights
        s += e;
    }
    s += __shfl_xor(s, 1);
    s += __shfl_xor(s, 2);
    float inv = 1.0f / s;
    __syncthreads();   // V fully staged

    // ================= PV: my 16 offsets, ALL 32 channels =================
    float acc[32];
    #pragma unroll
    for (int c = 0; c < 32; ++c) acc[c] = 0.f;
    #pragma unroll
    for (int cq = 0; cq < 8; ++cq) {
        #pragma unroll
        for (int t = 0; t < 16; ++t) {
            int dyl = t >> 3, dx = t & 7;
            const float4 vv4 = *(const float4*)(myr + (dyl * 15 + dx) * 36 + cq * 4);
            float wg = d[t];
            acc[cq*4+0] = fmaf(wg, vv4.x, acc[cq*4+0]);
            acc[cq*4+1] = fmaf(wg, vv4.y, acc[cq*4+1]);
            acc[cq*4+2] = fmaf(wg, vv4.z, acc[cq*4+2]);
            acc[cq*4+3] = fmaf(wg, vv4.w, acc[cq*4+3]);
        }
    }

    // combine offset quarters per channel (butterfly); lane q stores channels q*8..q*8+7
    float* op = att + (size_t)(bn * 32) * HWc + gq;
    #pragma unroll
    for (int c = 0; c < 32; ++c) {
        float t1 = acc[c] + __shfl_xor(acc[c], 1);
        float tot = t1 + __shfl_xor(t1, 2);
        if ((c >> 3) == qq) op[(size_t)c * HWc] = tot * inv;
    }
}

// ---------------------------------- launcher ------------------------------------------
extern "C" void kernel_launch(void* const* d_in, const int* in_sizes, int n_in,
                              void* d_out, int out_size, void* d_ws, size_t ws_size,
                              hipStream_t stream)
{
    const float* vid  = (const float*)d_in[0];
    const float* qdww = (const float*)d_in[1];
    const float* qdwb = (const float*)d_in[2];
    const float* qpww = (const float*)d_in[3];
    const float* qpwb = (const float*)d_in[4];
    const float* kdww = (const float*)d_in[5];
    const float* kdwb = (const float*)d_in[6];
    const float* kpww = (const float*)d_in[7];
    const float* kpwb = (const float*)d_in[8];
    const float* vdww = (const float*)d_in[9];
    const float* vdwb = (const float*)d_in[10];
    const float* vpww = (const float*)d_in[11];
    const float* vpwb = (const float*)d_in[12];
    const float* pjw  = (const float*)d_in[13];
    const float* pjb  = (const float*)d_in[14];

    float* ws = (float*)d_ws;
    const size_t SZ = (size_t)Bc * Cc * HWc;   // 16 MB each
    float* buf0 = ws;            // q-dw -> q -> att
    float* buf1 = ws + SZ;       // k-dw -> k
    float* buf2 = ws + 2 * SZ;   // v-dw -> v

    hipFuncSetAttribute((const void*)pw_kernel, hipFuncAttributeMaxDynamicSharedMemorySize, 68096);

    dw_kernel<<<dim3(HWc / 256, Bc * Cc, 3), 256, 0, stream>>>(
        vid, qdww, qdwb, kdww, kdwb, vdww, vdwb, buf0, buf1, buf2);

    const float scale = 0.17677669529663687f;
    pw_kernel<<<dim3((Bc * HWc) / 128, 1, 3), 256, 68096, stream>>>(
        buf0, buf1, buf2, qpww, kpww, vpww, qpwb, kpwb, vpwb, buf0, buf1, buf2, scale);

    attn_kernel<<<dim3(Wd / 8, Hd / 8, Bc * NHc), 256, 0, stream>>>(buf0, buf1, buf2, buf0);

    pw_kernel<<<dim3((Bc * HWc) / 128, 1, 1), 256, 68096, stream>>>(
        buf0, buf0, buf0, pjw, pjw, pjw, pjb, pjb, pjb, (float*)d_out, (float*)d_out, (float*)d_out, 1.f);
}

// Round 7
// 469.147 us; speedup vs baseline: 3.2722x; 2.0821x over previous
//
#include <hip/hip_runtime.h>

static constexpr int Wd  = 128;
static constexpr int Hd  = 128;
static constexpr int HWc = Wd * Hd;    // 16384
static constexpr int Cc  = 128;
static constexpr int NHc = 4;
static constexpr int Bc  = 2;

__device__ __forceinline__ int refl(int i, int L) {
    i = i < 0 ? -i : i;
    return i >= L ? 2 * (L - 1) - i : i;
}

// ---------------- Kernel A: depthwise 3x3 + bias + relu (zero padding) ----------------
__global__ __launch_bounds__(256) void dw_kernel(
    const float* __restrict__ vid,
    const float* __restrict__ wq, const float* __restrict__ bq,
    const float* __restrict__ wk, const float* __restrict__ bk,
    const float* __restrict__ wv, const float* __restrict__ bv,
    float* __restrict__ yq, float* __restrict__ yk, float* __restrict__ yv)
{
    int pix  = blockIdx.x * 256 + threadIdx.x;
    int bc   = blockIdx.y;           // b*C + c
    int conv = blockIdx.z;
    const float* wsel = conv == 0 ? wq : (conv == 1 ? wk : wv);
    const float* bsel = conv == 0 ? bq : (conv == 1 ? bk : bv);
    float* osel       = conv == 0 ? yq : (conv == 1 ? yk : yv);
    int c = bc & (Cc - 1);
    int y = pix >> 7, x = pix & (Wd - 1);
    const float* src = vid + (size_t)bc * HWc;
    const float* wp  = wsel + c * 9;
    float acc = 0.f;
    #pragma unroll
    for (int ky = 0; ky < 3; ++ky) {
        int iy = y + ky - 1;
        if (iy < 0 || iy >= Hd) continue;
        #pragma unroll
        for (int kx = 0; kx < 3; ++kx) {
            int ix = x + kx - 1;
            if (ix < 0 || ix >= Wd) continue;
            acc = fmaf(src[iy * Wd + ix], wp[ky * 3 + kx], acc);
        }
    }
    acc += bsel[c];
    osel[(size_t)bc * HWc + pix] = fmaxf(acc, 0.f);
}

// ---------------- Kernel B/D: pointwise GEMM, c-major in/out, in-place safe ----------
__global__ __launch_bounds__(256) void pw_kernel(
    const float* y0p, const float* y1p, const float* y2p,
    const float* __restrict__ w0,  const float* __restrict__ w1,  const float* __restrict__ w2,
    const float* __restrict__ b0,  const float* __restrict__ b1,  const float* __restrict__ b2,
    float* o0, float* o1, float* o2,
    float scale0)
{
    extern __shared__ float lds[];
    float* wl = lds;            // [64 cc][129]
    float* yl = lds + 8256;     // [64 cc][128 p]

    int z = blockIdx.z;
    const float* yin  = z == 0 ? y0p : (z == 1 ? y1p : y2p);
    const float* wmat = z == 0 ? w0  : (z == 1 ? w1  : w2);
    const float* bias = z == 0 ? b0  : (z == 1 ? b1  : b2);
    float* out        = z == 0 ? o0  : (z == 1 ? o1  : o2);
    float scale       = z == 0 ? scale0 : 1.f;

    int tid = threadIdx.x;
    int ot = tid & 15, pt = tid >> 4;
    int gp  = blockIdx.x * 128;
    int b   = gp >> 14;
    int pof = gp & (HWc - 1);
    const float* yb = yin + (size_t)b * Cc * HWc + pof;

    float acc[8][8];
    #pragma unroll
    for (int i = 0; i < 8; ++i)
        #pragma unroll
        for (int j = 0; j < 8; ++j) acc[i][j] = 0.f;

    for (int kh = 0; kh < 2; ++kh) {
        int c0 = kh * 64;
        for (int i = tid; i < 8192; i += 256) {
            int cc = i & 63, o = i >> 6;
            wl[cc * 129 + o] = wmat[o * 128 + c0 + cc];
        }
        for (int i = tid; i < 8192; i += 256) {
            int p = i & 127, cc = i >> 7;
            yl[cc * 128 + p] = yb[(size_t)(c0 + cc) * HWc + p];
        }
        __syncthreads();
        #pragma unroll 4
        for (int cc = 0; cc < 64; ++cc) {
            float wv[8], pv[8];
            #pragma unroll
            for (int oi = 0; oi < 8; ++oi) wv[oi] = wl[cc * 129 + oi * 16 + ot];
            #pragma unroll
            for (int pi = 0; pi < 8; ++pi) pv[pi] = yl[cc * 128 + pi * 16 + pt];
            #pragma unroll
            for (int oi = 0; oi < 8; ++oi)
                #pragma unroll
                for (int pi = 0; pi < 8; ++pi)
                    acc[oi][pi] = fmaf(wv[oi], pv[pi], acc[oi][pi]);
        }
        __syncthreads();
    }

    float bia[8];
    #pragma unroll
    for (int oi = 0; oi < 8; ++oi) bia[oi] = bias[oi * 16 + ot];

    #pragma unroll
    for (int oi = 0; oi < 8; ++oi)
        #pragma unroll
        for (int pi = 0; pi < 8; ++pi)
            lds[(pi * 16 + pt) * 133 + oi * 16 + ot] = (acc[oi][pi] + bia[oi]) * scale;
    __syncthreads();

    for (int i = tid; i < 16384; i += 256) {
        int p = i & 127, o = i >> 7;
        out[(size_t)b * Cc * HWc + (size_t)o * HWc + pof + p] = lds[p * 133 + o];
    }
}

// ---------------- Kernel C: neighborhood attention, quarter-lane split ----------------
// 8x8 pixel tile, 256 threads. Lane QUAD shares pixel pl = tid>>2; lane q = tid&3 owns
// window offsets q*16..q*16+15 (rows dy = 2q, 2q+1) over ALL 32 channels.
// __launch_bounds__(256) with NO second arg: empirically on this compiler the 2nd arg
// caps VGPRs at 256/arg2 regardless of block size ((512,4)->64, (512,2)->128,
// (256,4)->64), and every capped variant spilled (0.9-1.9 GB scratch writes). Natural
// allocation (round 2: 152 regs, zero spill) is the only non-spilling config.
// Region 15x15 x 32ch, stride 36 floats -> LDS 32.4 KB -> 4-5 blocks/CU.
__global__ __launch_bounds__(256) void attn_kernel(
    const float* q, const float* kk, const float* vv, float* att)
{
    __shared__ float lds[225 * 36];  // [225 region pix][36] (144B pixel stride)
    int tid = threadIdx.x;
    int x0 = blockIdx.x * 8, y0 = blockIdx.y * 8;
    int bn = blockIdx.z;
    const float* kb = kk + (size_t)bn * 32 * HWc;
    const float* vb = vv + (size_t)bn * 32 * HWc;

    // ---- compute geometry
    int qq = tid & 3;              // offset quarter (rows 2q, 2q+1)
    int pl = tid >> 2;             // pixel 0..63
    int px = pl & 7, py = pl >> 3;
    int gq = (y0 + py) * Wd + (x0 + px);
    // region base for my quarter: (dy=2q, dx=0) relative to (py,px); region origin -4
    float* myr = lds + ((py + 2 * qq) * 15 + px) * 36;

    // ================= stage K (225 pix x 8 quads = 1800 units) =================
    for (int u = tid; u < 1800; u += 256) {
        int pix = u >> 3, cb = u & 7;
        int ry = pix / 15, rx = pix - ry * 15;
        int go = refl(y0 - 4 + ry, Hd) * Wd + refl(x0 - 4 + rx, Wd);
        float4 v;
        v.x = kb[(size_t)(cb * 4 + 0) * HWc + go];
        v.y = kb[(size_t)(cb * 4 + 1) * HWc + go];
        v.z = kb[(size_t)(cb * 4 + 2) * HWc + go];
        v.w = kb[(size_t)(cb * 4 + 3) * HWc + go];
        *(float4*)(lds + pix * 36 + cb * 4) = v;
    }
    __syncthreads();

    // ================= QK: my 16 offsets x all 32 channels =================
    float d[16];
    #pragma unroll
    for (int i = 0; i < 16; ++i) d[i] = 0.f;
    {
        const float* qp = q + (size_t)(bn * 32) * HWc + gq;
        #pragma unroll
        for (int cq = 0; cq < 8; ++cq) {
            float4 q4;
            q4.x = qp[(size_t)(cq * 4 + 0) * HWc];
            q4.y = qp[(size_t)(cq * 4 + 1) * HWc];
            q4.z = qp[(size_t)(cq * 4 + 2) * HWc];
            q4.w = qp[(size_t)(cq * 4 + 3) * HWc];
            #pragma unroll
            for (int t = 0; t < 16; ++t) {
                int dyl = t >> 3, dx = t & 7;
                const float4 kv = *(const float4*)(myr + (dyl * 15 + dx) * 36 + cq * 4);
                d[t] = fmaf(q4.x, kv.x, fmaf(q4.y, kv.y, fmaf(q4.z, kv.z, fmaf(q4.w, kv.w, d[t]))));
            }
        }
    }
    __syncthreads();   // all QK reads done before V overwrites

    // ================= stage V (latency overlaps ranking below) =================
    for (int u = tid; u < 1800; u += 256) {
        int pix = u >> 3, cb = u & 7;
        int ry = pix / 15, rx = pix - ry * 15;
        int go = refl(y0 - 4 + ry, Hd) * Wd + refl(x0 - 4 + rx, Wd);
        float4 v;
        v.x = vb[(size_t)(cb * 4 + 0) * HWc + go];
        v.y = vb[(size_t)(cb * 4 + 1) * HWc + go];
        v.z = vb[(size_t)(cb * 4 + 2) * HWc + go];
        v.w = vb[(size_t)(cb * 4 + 3) * HWc + go];
        *(float4*)(lds + pix * 36 + cb * 4) = v;
    }

    // ================= cooperative top-16 ranking (exact lax.top_k ties) =========
    // rank(i) = #{j: d_j > d_i} + #{j<i globally: d_j == d_i}; selected iff rank<16.
    unsigned rk[4];
    #pragma unroll
    for (int i = 0; i < 4; ++i) rk[i] = 0u;
    // within my 16 (consecutive global indices)
    #pragma unroll
    for (int i = 0; i < 15; ++i) {
        #pragma unroll
        for (int j = i + 1; j < 16; ++j) {
            bool ge = d[i] >= d[j];
            rk[i >> 2] += ge ? 0u : (1u << (8 * (i & 3)));
            rk[j >> 2] += ge ? (1u << (8 * (j & 3))) : 0u;
        }
    }
    // cross-quad: partner q^m; partner's indices lower iff (q & msb(m)).
    #pragma unroll
    for (int m = 1; m <= 3; ++m) {
        bool plow = (m == 1) ? ((qq & 1) != 0) : ((qq & 2) != 0);
        #pragma unroll
        for (int j = 0; j < 16; ++j) {
            float dp = __shfl_xor(d[j], m);
            #pragma unroll
            for (int i = 0; i < 16; ++i) {
                bool beat = (dp > d[i]) || (plow && (dp == d[i]));
                rk[i >> 2] += beat ? (1u << (8 * (i & 3))) : 0u;
            }
        }
    }

    // ================= softmax over the selected 16 (quad butterfly) ============
    float mx = d[0];
    #pragma unroll
    for (int i = 1; i < 16; ++i) mx = fmaxf(mx, d[i]);
    mx = fmaxf(mx, __shfl_xor(mx, 1));
    mx = fmaxf(mx, __shfl_xor(mx, 2));
    float s = 0.f;
    #pragma unroll
    for (int i = 0; i < 16; ++i) {
        unsigned r = (rk[i >> 2] >> (8 * (i & 3))) & 255u;
        float e = (r < 16u) ? __expf(d[i] - mx) : 0.f;
        d[i] = e;                    // d[] now holds unnormalized weights
        s += e;
    }
    s += __shfl_xor(s, 1);
    s += __shfl_xor(s, 2);
    float inv = 1.0f / s;
    __syncthreads();   // V fully staged

    // ================= PV: my 16 offsets, ALL 32 channels =================
    float acc[32];
    #pragma unroll
    for (int c = 0; c < 32; ++c) acc[c] = 0.f;
    #pragma unroll
    for (int cq = 0; cq < 8; ++cq) {
        #pragma unroll
        for (int t = 0; t < 16; ++t) {
            int dyl = t >> 3, dx = t & 7;
            const float4 vv4 = *(const float4*)(myr + (dyl * 15 + dx) * 36 + cq * 4);
            float wg = d[t];
            acc[cq*4+0] = fmaf(wg, vv4.x, acc[cq*4+0]);
            acc[cq*4+1] = fmaf(wg, vv4.y, acc[cq*4+1]);
            acc[cq*4+2] = fmaf(wg, vv4.z, acc[cq*4+2]);
            acc[cq*4+3] = fmaf(wg, vv4.w, acc[cq*4+3]);
        }
    }

    // combine offset quarters per channel (butterfly); lane q stores channels q*8..q*8+7
    float* op = att + (size_t)(bn * 32) * HWc + gq;
    #pragma unroll
    for (int c = 0; c < 32; ++c) {
        float t1 = acc[c] + __shfl_xor(acc[c], 1);
        float tot = t1 + __shfl_xor(t1, 2);
        if ((c >> 3) == qq) op[(size_t)c * HWc] = tot * inv;
    }
}

// ---------------------------------- launcher ------------------------------------------
extern "C" void kernel_launch(void* const* d_in, const int* in_sizes, int n_in,
                              void* d_out, int out_size, void* d_ws, size_t ws_size,
                              hipStream_t stream)
{
    const float* vid  = (const float*)d_in[0];
    const float* qdww = (const float*)d_in[1];
    const float* qdwb = (const float*)d_in[2];
    const float* qpww = (const float*)d_in[3];
    const float* qpwb = (const float*)d_in[4];
    const float* kdww = (const float*)d_in[5];
    const float* kdwb = (const float*)d_in[6];
    const float* kpww = (const float*)d_in[7];
    const float* kpwb = (const float*)d_in[8];
    const float* vdww = (const float*)d_in[9];
    const float* vdwb = (const float*)d_in[10];
    const float* vpww = (const float*)d_in[11];
    const float* vpwb = (const float*)d_in[12];
    const float* pjw  = (const float*)d_in[13];
    const float* pjb  = (const float*)d_in[14];

    float* ws = (float*)d_ws;
    const size_t SZ = (size_t)Bc * Cc * HWc;   // 16 MB each
    float* buf0 = ws;            // q-dw -> q -> att
    float* buf1 = ws + SZ;       // k-dw -> k
    float* buf2 = ws + 2 * SZ;   // v-dw -> v

    hipFuncSetAttribute((const void*)pw_kernel, hipFuncAttributeMaxDynamicSharedMemorySize, 68096);

    dw_kernel<<<dim3(HWc / 256, Bc * Cc, 3), 256, 0, stream>>>(
        vid, qdww, qdwb, kdww, kdwb, vdww, vdwb, buf0, buf1, buf2);

    const float scale = 0.17677669529663687f;
    pw_kernel<<<dim3((Bc * HWc) / 128, 1, 3), 256, 68096, stream>>>(
        buf0, buf1, buf2, qpww, kpww, vpww, qpwb, kpwb, vpwb, buf0, buf1, buf2, scale);

    attn_kernel<<<dim3(Wd / 8, Hd / 8, Bc * NHc), 256, 0, stream>>>(buf0, buf1, buf2, buf0);

    pw_kernel<<<dim3((Bc * HWc) / 128, 1, 1), 256, 68096, stream>>>(
        buf0, buf0, buf0, pjw, pjw, pjw, pjb, pjb, pjb, (float*)d_out, (float*)d_out, (float*)d_out, 1.f);
}

// Round 8
// 329.019 us; speedup vs baseline: 4.6658x; 1.4259x over previous
//
#include <hip/hip_runtime.h>

static constexpr int Wd  = 128;
static constexpr int Hd  = 128;
static constexpr int HWc = Wd * Hd;    // 16384
static constexpr int Cc  = 128;
static constexpr int NHc = 4;
static constexpr int Bc  = 2;

__device__ __forceinline__ int refl(int i, int L) {
    i = i < 0 ? -i : i;
    return i >= L ? 2 * (L - 1) - i : i;
}

// float -> sortable u32 (strictly increasing bijection), and inverse
__device__ __forceinline__ unsigned f2s(float f) {
    unsigned u = __float_as_uint(f);
    return u ^ (0x80000000u | (unsigned)((int)u >> 31));
}
__device__ __forceinline__ float s2f(unsigned s) {
    unsigned u = (s & 0x80000000u) ? (s ^ 0x80000000u) : ~s;
    return __uint_as_float(u);
}

// ---------------- Kernel A: depthwise 3x3 + bias + relu (zero padding) ----------------
__global__ __launch_bounds__(256) void dw_kernel(
    const float* __restrict__ vid,
    const float* __restrict__ wq, const float* __restrict__ bq,
    const float* __restrict__ wk, const float* __restrict__ bk,
    const float* __restrict__ wv, const float* __restrict__ bv,
    float* __restrict__ yq, float* __restrict__ yk, float* __restrict__ yv)
{
    int pix  = blockIdx.x * 256 + threadIdx.x;
    int bc   = blockIdx.y;           // b*C + c
    int conv = blockIdx.z;
    const float* wsel = conv == 0 ? wq : (conv == 1 ? wk : wv);
    const float* bsel = conv == 0 ? bq : (conv == 1 ? bk : bv);
    float* osel       = conv == 0 ? yq : (conv == 1 ? yk : yv);
    int c = bc & (Cc - 1);
    int y = pix >> 7, x = pix & (Wd - 1);
    const float* src = vid + (size_t)bc * HWc;
    const float* wp  = wsel + c * 9;
    float acc = 0.f;
    #pragma unroll
    for (int ky = 0; ky < 3; ++ky) {
        int iy = y + ky - 1;
        if (iy < 0 || iy >= Hd) continue;
        #pragma unroll
        for (int kx = 0; kx < 3; ++kx) {
            int ix = x + kx - 1;
            if (ix < 0 || ix >= Wd) continue;
            acc = fmaf(src[iy * Wd + ix], wp[ky * 3 + kx], acc);
        }
    }
    acc += bsel[c];
    osel[(size_t)bc * HWc + pix] = fmaxf(acc, 0.f);
}

// ---------------- Kernel B/D: pointwise GEMM, c-major in/out, in-place safe ----------
__global__ __launch_bounds__(256) void pw_kernel(
    const float* y0p, const float* y1p, const float* y2p,
    const float* __restrict__ w0,  const float* __restrict__ w1,  const float* __restrict__ w2,
    const float* __restrict__ b0,  const float* __restrict__ b1,  const float* __restrict__ b2,
    float* o0, float* o1, float* o2,
    float scale0)
{
    extern __shared__ float lds[];
    float* wl = lds;            // [64 cc][129]
    float* yl = lds + 8256;     // [64 cc][128 p]

    int z = blockIdx.z;
    const float* yin  = z == 0 ? y0p : (z == 1 ? y1p : y2p);
    const float* wmat = z == 0 ? w0  : (z == 1 ? w1  : w2);
    const float* bias = z == 0 ? b0  : (z == 1 ? b1  : b2);
    float* out        = z == 0 ? o0  : (z == 1 ? o1  : o2);
    float scale       = z == 0 ? scale0 : 1.f;

    int tid = threadIdx.x;
    int ot = tid & 15, pt = tid >> 4;
    int gp  = blockIdx.x * 128;
    int b   = gp >> 14;
    int pof = gp & (HWc - 1);
    const float* yb = yin + (size_t)b * Cc * HWc + pof;

    float acc[8][8];
    #pragma unroll
    for (int i = 0; i < 8; ++i)
        #pragma unroll
        for (int j = 0; j < 8; ++j) acc[i][j] = 0.f;

    for (int kh = 0; kh < 2; ++kh) {
        int c0 = kh * 64;
        for (int i = tid; i < 8192; i += 256) {
            int cc = i & 63, o = i >> 6;
            wl[cc * 129 + o] = wmat[o * 128 + c0 + cc];
        }
        for (int i = tid; i < 8192; i += 256) {
            int p = i & 127, cc = i >> 7;
            yl[cc * 128 + p] = yb[(size_t)(c0 + cc) * HWc + p];
        }
        __syncthreads();
        #pragma unroll 4
        for (int cc = 0; cc < 64; ++cc) {
            float wv[8], pv[8];
            #pragma unroll
            for (int oi = 0; oi < 8; ++oi) wv[oi] = wl[cc * 129 + oi * 16 + ot];
            #pragma unroll
            for (int pi = 0; pi < 8; ++pi) pv[pi] = yl[cc * 128 + pi * 16 + pt];
            #pragma unroll
            for (int oi = 0; oi < 8; ++oi)
                #pragma unroll
                for (int pi = 0; pi < 8; ++pi)
                    acc[oi][pi] = fmaf(wv[oi], pv[pi], acc[oi][pi]);
        }
        __syncthreads();
    }

    float bia[8];
    #pragma unroll
    for (int oi = 0; oi < 8; ++oi) bia[oi] = bias[oi * 16 + ot];

    #pragma unroll
    for (int oi = 0; oi < 8; ++oi)
        #pragma unroll
        for (int pi = 0; pi < 8; ++pi)
            lds[(pi * 16 + pt) * 133 + oi * 16 + ot] = (acc[oi][pi] + bia[oi]) * scale;
    __syncthreads();

    for (int i = tid; i < 16384; i += 256) {
        int p = i & 127, o = i >> 7;
        out[(size_t)b * Cc * HWc + (size_t)o * HWc + pof + p] = lds[p * 133 + o];
    }
}

// ---------------- Kernel C: neighborhood attention, quarter-lane split ----------------
// 8x8 pixel tile, 256 threads. Lane QUAD shares pixel pl = tid>>2; lane qq owns window
// offsets qq*16..qq*16+15 over ALL 32 channels.
// (256,2): VGPR cap 128 (empirical: cap=256/arg2). Round-7 natural alloc was 256 regs
// -> 2 waves/SIMD, latency-bound (VALUBusy 23%). This version reduces true peak
// pressure to ~90 (two-pass PV acc[16]; only s[16] live during ranking) so the 128 cap
// fits WITHOUT spill (watch WRITE_SIZE ~ 20 MB, not hundreds).
// Ranking on sortable-u32 keys: exact lax.top_k tie semantics with ONE uint compare
// per pair: beat <=> sp + plow > s_i  (plow in {0,1}).
__global__ __launch_bounds__(256, 2) void attn_kernel(
    const float* q, const float* kk, const float* vv, float* att)
{
    __shared__ float lds[225 * 36];  // [225 region pix][36] (144B pixel stride)
    int tid = threadIdx.x;
    int x0 = blockIdx.x * 8, y0 = blockIdx.y * 8;
    int bn = blockIdx.z;
    const float* kb = kk + (size_t)bn * 32 * HWc;
    const float* vb = vv + (size_t)bn * 32 * HWc;

    // ---- compute geometry
    int qq = tid & 3;              // offset quarter (rows dy = 2qq, 2qq+1)
    int pl = tid >> 2;             // pixel 0..63
    int px = pl & 7, py = pl >> 3;
    int gq = (y0 + py) * Wd + (x0 + px);
    float* myr = lds + ((py + 2 * qq) * 15 + px) * 36;

    // ================= stage K (225 pix x 8 quads = 1800 units) =================
    for (int u = tid; u < 1800; u += 256) {
        int pix = u >> 3, cb = u & 7;
        int ry = pix / 15, rx = pix - ry * 15;
        int go = refl(y0 - 4 + ry, Hd) * Wd + refl(x0 - 4 + rx, Wd);
        float4 v;
        v.x = kb[(size_t)(cb * 4 + 0) * HWc + go];
        v.y = kb[(size_t)(cb * 4 + 1) * HWc + go];
        v.z = kb[(size_t)(cb * 4 + 2) * HWc + go];
        v.w = kb[(size_t)(cb * 4 + 3) * HWc + go];
        *(float4*)(lds + pix * 36 + cb * 4) = v;
    }
    __syncthreads();

    // ================= QK: my 16 offsets x all 32 channels =================
    float d[16];
    #pragma unroll
    for (int i = 0; i < 16; ++i) d[i] = 0.f;
    {
        const float* qp = q + (size_t)(bn * 32) * HWc + gq;
        #pragma unroll
        for (int cq = 0; cq < 8; ++cq) {
            float4 q4;
            q4.x = qp[(size_t)(cq * 4 + 0) * HWc];
            q4.y = qp[(size_t)(cq * 4 + 1) * HWc];
            q4.z = qp[(size_t)(cq * 4 + 2) * HWc];
            q4.w = qp[(size_t)(cq * 4 + 3) * HWc];
            #pragma unroll
            for (int t = 0; t < 16; ++t) {
                int dyl = t >> 3, dx = t & 7;
                const float4 kv = *(const float4*)(myr + (dyl * 15 + dx) * 36 + cq * 4);
                d[t] = fmaf(q4.x, kv.x, fmaf(q4.y, kv.y, fmaf(q4.z, kv.z, fmaf(q4.w, kv.w, d[t]))));
            }
        }
    }
    // convert to sortable keys in place (d dies; s[16] is the only rank-phase state)
    unsigned s[16];
    #pragma unroll
    for (int i = 0; i < 16; ++i) s[i] = f2s(d[i]);
    __syncthreads();   // all QK reads done before V overwrites

    // ================= stage V (latency overlaps ranking below) =================
    for (int u = tid; u < 1800; u += 256) {
        int pix = u >> 3, cb = u & 7;
        int ry = pix / 15, rx = pix - ry * 15;
        int go = refl(y0 - 4 + ry, Hd) * Wd + refl(x0 - 4 + rx, Wd);
        float4 v;
        v.x = vb[(size_t)(cb * 4 + 0) * HWc + go];
        v.y = vb[(size_t)(cb * 4 + 1) * HWc + go];
        v.z = vb[(size_t)(cb * 4 + 2) * HWc + go];
        v.w = vb[(size_t)(cb * 4 + 3) * HWc + go];
        *(float4*)(lds + pix * 36 + cb * 4) = v;
    }

    // ================= cooperative top-16 ranking (integer keys) =================
    // rank(i) = #{j beating i}; j beats i iff s_j > s_i (j higher gidx) or s_j >= s_i
    // (j lower gidx). Selected iff rank < 16.
    unsigned rk[4];
    #pragma unroll
    for (int i = 0; i < 4; ++i) rk[i] = 0u;
    // within my 16 (consecutive global indices: i < j)
    #pragma unroll
    for (int i = 0; i < 15; ++i) {
        #pragma unroll
        for (int j = i + 1; j < 16; ++j) {
            bool jw = s[j] > s[i];
            rk[i >> 2] += jw ? (1u << (8 * (i & 3))) : 0u;
            rk[j >> 2] += jw ? 0u : (1u << (8 * (j & 3)));
        }
    }
    // cross-quad: partner qq^m has lower gidx iff (m==1 ? qq&1 : qq&2)
    #pragma unroll
    for (int m = 1; m <= 3; ++m) {
        unsigned plow = ((m == 1) ? (qq & 1) : ((qq >> 1) & 1)) ? 1u : 0u;
        #pragma unroll
        for (int j = 0; j < 16; ++j) {
            unsigned spa = __shfl_xor(s[j], m) + plow;   // beat <=> spa > s_i
            #pragma unroll
            for (int i = 0; i < 16; ++i)
                rk[i >> 2] += (spa > s[i]) ? (1u << (8 * (i & 3))) : 0u;
        }
    }

    // ================= softmax over the selected 16 =================
    unsigned smax = s[0];
    #pragma unroll
    for (int i = 1; i < 16; ++i) smax = max(smax, s[i]);
    smax = max(smax, (unsigned)__shfl_xor(smax, 1));
    smax = max(smax, (unsigned)__shfl_xor(smax, 2));
    float dmax = s2f(smax);
    float w[16];
    float sum = 0.f;
    #pragma unroll
    for (int i = 0; i < 16; ++i) {
        unsigned r = (rk[i >> 2] >> (8 * (i & 3))) & 255u;
        float di = s2f(s[i]);
        float e = (r < 16u) ? __expf(di - dmax) : 0.f;
        w[i] = e;
        sum += e;
    }
    sum += __shfl_xor(sum, 1);
    sum += __shfl_xor(sum, 2);
    float inv = 1.0f / sum;
    __syncthreads();   // V fully staged

    // ================= PV pass A: channels 0..15 =================
    float* op = att + (size_t)(bn * 32) * HWc + gq;
    {
        float acc[16];
        #pragma unroll
        for (int c = 0; c < 16; ++c) acc[c] = 0.f;
        #pragma unroll
        for (int cq = 0; cq < 4; ++cq) {
            #pragma unroll
            for (int t = 0; t < 16; ++t) {
                int dyl = t >> 3, dx = t & 7;
                const float4 vv4 = *(const float4*)(myr + (dyl * 15 + dx) * 36 + cq * 4);
                float wg = w[t];
                acc[cq*4+0] = fmaf(wg, vv4.x, acc[cq*4+0]);
                acc[cq*4+1] = fmaf(wg, vv4.y, acc[cq*4+1]);
                acc[cq*4+2] = fmaf(wg, vv4.z, acc[cq*4+2]);
                acc[cq*4+3] = fmaf(wg, vv4.w, acc[cq*4+3]);
            }
        }
        #pragma unroll
        for (int c = 0; c < 16; ++c) {
            float t1 = acc[c] + __shfl_xor(acc[c], 1);
            float tot = t1 + __shfl_xor(t1, 2);
            if ((c >> 3) == qq) op[(size_t)c * HWc] = tot * inv;
        }
    }
    // ================= PV pass B: channels 16..31 =================
    {
        float acc[16];
        #pragma unroll
        for (int c = 0; c < 16; ++c) acc[c] = 0.f;
        #pragma unroll
        for (int cq = 4; cq < 8; ++cq) {
            #pragma unroll
            for (int t = 0; t < 16; ++t) {
                int dyl = t >> 3, dx = t & 7;
                const float4 vv4 = *(const float4*)(myr + (dyl * 15 + dx) * 36 + cq * 4);
                float wg = w[t];
                int k = (cq - 4) * 4;
                acc[k+0] = fmaf(wg, vv4.x, acc[k+0]);
                acc[k+1] = fmaf(wg, vv4.y, acc[k+1]);
                acc[k+2] = fmaf(wg, vv4.z, acc[k+2]);
                acc[k+3] = fmaf(wg, vv4.w, acc[k+3]);
            }
        }
        #pragma unroll
        for (int k = 0; k < 16; ++k) {
            int c = 16 + k;
            float t1 = acc[k] + __shfl_xor(acc[k], 1);
            float tot = t1 + __shfl_xor(t1, 2);
            if ((c >> 3) == qq) op[(size_t)c * HWc] = tot * inv;
        }
    }
}

// ---------------------------------- launcher ------------------------------------------
extern "C" void kernel_launch(void* const* d_in, const int* in_sizes, int n_in,
                              void* d_out, int out_size, void* d_ws, size_t ws_size,
                              hipStream_t stream)
{
    const float* vid  = (const float*)d_in[0];
    const float* qdww = (const float*)d_in[1];
    const float* qdwb = (const float*)d_in[2];
    const float* qpww = (const float*)d_in[3];
    const float* qpwb = (const float*)d_in[4];
    const float* kdww = (const float*)d_in[5];
    const float* kdwb = (const float*)d_in[6];
    const float* kpww = (const float*)d_in[7];
    const float* kpwb = (const float*)d_in[8];
    const float* vdww = (const float*)d_in[9];
    const float* vdwb = (const float*)d_in[10];
    const float* vpww = (const float*)d_in[11];
    const float* vpwb = (const float*)d_in[12];
    const float* pjw  = (const float*)d_in[13];
    const float* pjb  = (const float*)d_in[14];

    float* ws = (float*)d_ws;
    const size_t SZ = (size_t)Bc * Cc * HWc;   // 16 MB each
    float* buf0 = ws;            // q-dw -> q -> att
    float* buf1 = ws + SZ;       // k-dw -> k
    float* buf2 = ws + 2 * SZ;   // v-dw -> v

    hipFuncSetAttribute((const void*)pw_kernel, hipFuncAttributeMaxDynamicSharedMemorySize, 68096);

    dw_kernel<<<dim3(HWc / 256, Bc * Cc, 3), 256, 0, stream>>>(
        vid, qdww, qdwb, kdww, kdwb, vdww, vdwb, buf0, buf1, buf2);

    const float scale = 0.17677669529663687f;
    pw_kernel<<<dim3((Bc * HWc) / 128, 1, 3), 256, 68096, stream>>>(
        buf0, buf1, buf2, qpww, kpww, vpww, qpwb, kpwb, vpwb, buf0, buf1, buf2, scale);

    attn_kernel<<<dim3(Wd / 8, Hd / 8, Bc * NHc), 256, 0, stream>>>(buf0, buf1, buf2, buf0);

    pw_kernel<<<dim3((Bc * HWc) / 128, 1, 1), 256, 68096, stream>>>(
        buf0, buf0, buf0, pjw, pjw, pjw, pjb, pjb, pjb, (float*)d_out, (float*)d_out, (float*)d_out, 1.f);
}

// Round 9
// 302.426 us; speedup vs baseline: 5.0761x; 1.0879x over previous
//
#include <hip/hip_runtime.h>

static constexpr int Wd  = 128;
static constexpr int Hd  = 128;
static constexpr int HWc = Wd * Hd;    // 16384
static constexpr int Cc  = 128;
static constexpr int NHc = 4;
static constexpr int Bc  = 2;

__device__ __forceinline__ int refl(int i, int L) {
    i = i < 0 ? -i : i;
    return i >= L ? 2 * (L - 1) - i : i;
}

// float -> sortable u32 (strictly increasing bijection), and inverse
__device__ __forceinline__ unsigned f2s(float f) {
    unsigned u = __float_as_uint(f);
    return u ^ (0x80000000u | (unsigned)((int)u >> 31));
}
__device__ __forceinline__ float s2f(unsigned s) {
    unsigned u = (s & 0x80000000u) ? (s ^ 0x80000000u) : ~s;
    return __uint_as_float(u);
}

// ---------------- Kernel A: depthwise 3x3 + bias + relu (zero padding) ----------------
__global__ __launch_bounds__(256) void dw_kernel(
    const float* __restrict__ vid,
    const float* __restrict__ wq, const float* __restrict__ bq,
    const float* __restrict__ wk, const float* __restrict__ bk,
    const float* __restrict__ wv, const float* __restrict__ bv,
    float* __restrict__ yq, float* __restrict__ yk, float* __restrict__ yv)
{
    int pix  = blockIdx.x * 256 + threadIdx.x;
    int bc   = blockIdx.y;           // b*C + c
    int conv = blockIdx.z;
    const float* wsel = conv == 0 ? wq : (conv == 1 ? wk : wv);
    const float* bsel = conv == 0 ? bq : (conv == 1 ? bk : bv);
    float* osel       = conv == 0 ? yq : (conv == 1 ? yk : yv);
    int c = bc & (Cc - 1);
    int y = pix >> 7, x = pix & (Wd - 1);
    const float* src = vid + (size_t)bc * HWc;
    const float* wp  = wsel + c * 9;
    float acc = 0.f;
    #pragma unroll
    for (int ky = 0; ky < 3; ++ky) {
        int iy = y + ky - 1;
        if (iy < 0 || iy >= Hd) continue;
        #pragma unroll
        for (int kx = 0; kx < 3; ++kx) {
            int ix = x + kx - 1;
            if (ix < 0 || ix >= Wd) continue;
            acc = fmaf(src[iy * Wd + ix], wp[ky * 3 + kx], acc);
        }
    }
    acc += bsel[c];
    osel[(size_t)bc * HWc + pix] = fmaxf(acc, 0.f);
}

// ---------------- Kernel B/D: pointwise GEMM, float4 micro-tile, direct stores -------
// out[o,p] = (sum_c w[o,c]*y[c,p] + b[o]) * scale, c-major in/out, in-place safe
// (all staging reads complete before the final barrier; stores after it).
// Thread (ot=tid&15, pt=tid>>4) owns o in {4ot+oi}+{0,64}, p in {4pt+pi}+{0,64}.
// Inner loop per cc: 4x ds_read_b128 + 64 fma. Epilogue: 16x global float4 stores.
__global__ __launch_bounds__(256) void pw_kernel(
    const float* y0p, const float* y1p, const float* y2p,
    const float* __restrict__ w0,  const float* __restrict__ w1,  const float* __restrict__ w2,
    const float* __restrict__ b0,  const float* __restrict__ b1,  const float* __restrict__ b2,
    float* o0, float* o1, float* o2,
    float scale0)
{
    extern __shared__ float lds[];
    float* wl = lds;            // [64 cc][132]  (aligned float4 reads, 2-way banks)
    float* yl = lds + 8448;     // [64 cc][128 p]

    int z = blockIdx.z;
    const float* yin  = z == 0 ? y0p : (z == 1 ? y1p : y2p);
    const float* wmat = z == 0 ? w0  : (z == 1 ? w1  : w2);
    const float* bias = z == 0 ? b0  : (z == 1 ? b1  : b2);
    float* out        = z == 0 ? o0  : (z == 1 ? o1  : o2);
    float scale       = z == 0 ? scale0 : 1.f;

    int tid = threadIdx.x;
    int ot = tid & 15, pt = tid >> 4;
    int gp  = blockIdx.x * 128;
    int b   = gp >> 14;
    int pof = gp & (HWc - 1);
    const float* yb = yin + (size_t)b * Cc * HWc + pof;

    float acc[2][2][4][4];   // [oh][ph][oi][pi]
    #pragma unroll
    for (int a = 0; a < 2; ++a)
        #pragma unroll
        for (int c = 0; c < 2; ++c)
            #pragma unroll
            for (int i = 0; i < 4; ++i)
                #pragma unroll
                for (int j = 0; j < 4; ++j) acc[a][c][i][j] = 0.f;

    for (int kh = 0; kh < 2; ++kh) {
        int c0 = kh * 64;
        for (int i = tid; i < 8192; i += 256) {
            int cc = i & 63, o = i >> 6;
            wl[cc * 132 + o] = wmat[o * 128 + c0 + cc];
        }
        for (int i = tid; i < 8192; i += 256) {
            int p = i & 127, cc = i >> 7;
            yl[cc * 128 + p] = yb[(size_t)(c0 + cc) * HWc + p];
        }
        __syncthreads();
        #pragma unroll 4
        for (int cc = 0; cc < 64; ++cc) {
            float4 wv[2], pv[2];
            wv[0] = *(const float4*)(wl + cc * 132 + 4 * ot);
            wv[1] = *(const float4*)(wl + cc * 132 + 64 + 4 * ot);
            pv[0] = *(const float4*)(yl + cc * 128 + 4 * pt);
            pv[1] = *(const float4*)(yl + cc * 128 + 64 + 4 * pt);
            #pragma unroll
            for (int oh = 0; oh < 2; ++oh) {
                const float wo[4] = {wv[oh].x, wv[oh].y, wv[oh].z, wv[oh].w};
                #pragma unroll
                for (int ph = 0; ph < 2; ++ph) {
                    const float pp[4] = {pv[ph].x, pv[ph].y, pv[ph].z, pv[ph].w};
                    #pragma unroll
                    for (int oi = 0; oi < 4; ++oi)
                        #pragma unroll
                        for (int pi = 0; pi < 4; ++pi)
                            acc[oh][ph][oi][pi] = fmaf(wo[oi], pp[pi], acc[oh][ph][oi][pi]);
                }
            }
        }
        __syncthreads();
    }

    float* ob = out + (size_t)b * Cc * HWc + pof;
    #pragma unroll
    for (int oh = 0; oh < 2; ++oh)
        #pragma unroll
        for (int oi = 0; oi < 4; ++oi) {
            int o = oh * 64 + 4 * ot + oi;
            float bo = bias[o];
            float* row = ob + (size_t)o * HWc;
            #pragma unroll
            for (int ph = 0; ph < 2; ++ph) {
                float4 v;
                v.x = (acc[oh][ph][oi][0] + bo) * scale;
                v.y = (acc[oh][ph][oi][1] + bo) * scale;
                v.z = (acc[oh][ph][oi][2] + bo) * scale;
                v.w = (acc[oh][ph][oi][3] + bo) * scale;
                *(float4*)(row + ph * 64 + 4 * pt) = v;
            }
        }
}

// ---------------- Kernel C: neighborhood attention, quarter-lane split ----------------
// 8x8 pixel tile, 256 threads. Lane QUAD shares pixel pl = tid>>2; lane qq owns window
// offsets qq*16..qq*16+15 over ALL 32 channels. VGPR cap 128 via (256,2); true peak
// pressure now ~50: weights overwrite s[] in place (no separate w[16]), staging loops
// kept rolled (#pragma unroll 1) so only 4 float4 loads are in flight (round-8 residual
// spill came from the unrolled stage loop holding 8 iterations of loads).
__global__ __launch_bounds__(256, 2) void attn_kernel(
    const float* q, const float* kk, const float* vv, float* att)
{
    __shared__ float lds[225 * 36];  // [225 region pix][36] (144B pixel stride)
    int tid = threadIdx.x;
    int x0 = blockIdx.x * 8, y0 = blockIdx.y * 8;
    int bn = blockIdx.z;
    const float* kb = kk + (size_t)bn * 32 * HWc;
    const float* vb = vv + (size_t)bn * 32 * HWc;

    // ---- compute geometry
    int qq = tid & 3;              // offset quarter (rows dy = 2qq, 2qq+1)
    int pl = tid >> 2;             // pixel 0..63
    int px = pl & 7, py = pl >> 3;
    int gq = (y0 + py) * Wd + (x0 + px);
    float* myr = lds + ((py + 2 * qq) * 15 + px) * 36;

    // ================= stage K (225 pix x 8 quads = 1800 units) =================
    #pragma unroll 1
    for (int u = tid; u < 1800; u += 256) {
        int pix = u >> 3, cb = u & 7;
        int ry = pix / 15, rx = pix - ry * 15;
        int go = refl(y0 - 4 + ry, Hd) * Wd + refl(x0 - 4 + rx, Wd);
        float4 v;
        v.x = kb[(size_t)(cb * 4 + 0) * HWc + go];
        v.y = kb[(size_t)(cb * 4 + 1) * HWc + go];
        v.z = kb[(size_t)(cb * 4 + 2) * HWc + go];
        v.w = kb[(size_t)(cb * 4 + 3) * HWc + go];
        *(float4*)(lds + pix * 36 + cb * 4) = v;
    }
    __syncthreads();

    // ================= QK: my 16 offsets x all 32 channels =================
    float d[16];
    #pragma unroll
    for (int i = 0; i < 16; ++i) d[i] = 0.f;
    {
        const float* qp = q + (size_t)(bn * 32) * HWc + gq;
        #pragma unroll
        for (int cq = 0; cq < 8; ++cq) {
            float4 q4;
            q4.x = qp[(size_t)(cq * 4 + 0) * HWc];
            q4.y = qp[(size_t)(cq * 4 + 1) * HWc];
            q4.z = qp[(size_t)(cq * 4 + 2) * HWc];
            q4.w = qp[(size_t)(cq * 4 + 3) * HWc];
            #pragma unroll
            for (int t = 0; t < 16; ++t) {
                int dyl = t >> 3, dx = t & 7;
                const float4 kv = *(const float4*)(myr + (dyl * 15 + dx) * 36 + cq * 4);
                d[t] = fmaf(q4.x, kv.x, fmaf(q4.y, kv.y, fmaf(q4.z, kv.z, fmaf(q4.w, kv.w, d[t]))));
            }
        }
    }
    // convert to sortable keys (d dies; s[16] is the only cross-phase state)
    unsigned s[16];
    #pragma unroll
    for (int i = 0; i < 16; ++i) s[i] = f2s(d[i]);
    __syncthreads();   // all QK reads done before V overwrites

    // ================= stage V (latency overlaps ranking below) =================
    #pragma unroll 1
    for (int u = tid; u < 1800; u += 256) {
        int pix = u >> 3, cb = u & 7;
        int ry = pix / 15, rx = pix - ry * 15;
        int go = refl(y0 - 4 + ry, Hd) * Wd + refl(x0 - 4 + rx, Wd);
        float4 v;
        v.x = vb[(size_t)(cb * 4 + 0) * HWc + go];
        v.y = vb[(size_t)(cb * 4 + 1) * HWc + go];
        v.z = vb[(size_t)(cb * 4 + 2) * HWc + go];
        v.w = vb[(size_t)(cb * 4 + 3) * HWc + go];
        *(float4*)(lds + pix * 36 + cb * 4) = v;
    }

    // ================= cooperative top-16 ranking (integer keys) =================
    // rank(i) = #{j beating i}; j beats i iff s_j > s_i (j higher gidx) or s_j >= s_i
    // (j lower gidx). Selected iff rank < 16.
    unsigned rk[4];
    #pragma unroll
    for (int i = 0; i < 4; ++i) rk[i] = 0u;
    #pragma unroll
    for (int i = 0; i < 15; ++i) {
        #pragma unroll
        for (int j = i + 1; j < 16; ++j) {
            bool jw = s[j] > s[i];
            rk[i >> 2] += jw ? (1u << (8 * (i & 3))) : 0u;
            rk[j >> 2] += jw ? 0u : (1u << (8 * (j & 3)));
        }
    }
    #pragma unroll
    for (int m = 1; m <= 3; ++m) {
        unsigned plow = ((m == 1) ? (qq & 1) : ((qq >> 1) & 1)) ? 1u : 0u;
        #pragma unroll
        for (int j = 0; j < 16; ++j) {
            unsigned spa = __shfl_xor(s[j], m) + plow;   // beat <=> spa > s_i
            #pragma unroll
            for (int i = 0; i < 16; ++i)
                rk[i >> 2] += (spa > s[i]) ? (1u << (8 * (i & 3))) : 0u;
        }
    }

    // ================= softmax over the selected 16 (weights overwrite s) ========
    unsigned smax = s[0];
    #pragma unroll
    for (int i = 1; i < 16; ++i) smax = max(smax, s[i]);
    smax = max(smax, (unsigned)__shfl_xor(smax, 1));
    smax = max(smax, (unsigned)__shfl_xor(smax, 2));
    float dmax = s2f(smax);
    float sum = 0.f;
    #pragma unroll
    for (int i = 0; i < 16; ++i) {
        unsigned r = (rk[i >> 2] >> (8 * (i & 3))) & 255u;
        float e = (r < 16u) ? __expf(s2f(s[i]) - dmax) : 0.f;
        s[i] = __float_as_uint(e);
        sum += e;
    }
    sum += __shfl_xor(sum, 1);
    sum += __shfl_xor(sum, 2);
    float inv = 1.0f / sum;
    __syncthreads();   // V fully staged

    // ================= PV pass A: channels 0..15 =================
    float* op = att + (size_t)(bn * 32) * HWc + gq;
    {
        float acc[16];
        #pragma unroll
        for (int c = 0; c < 16; ++c) acc[c] = 0.f;
        #pragma unroll
        for (int cq = 0; cq < 4; ++cq) {
            #pragma unroll
            for (int t = 0; t < 16; ++t) {
                int dyl = t >> 3, dx = t & 7;
                const float4 vv4 = *(const float4*)(myr + (dyl * 15 + dx) * 36 + cq * 4);
                float wg = __uint_as_float(s[t]);
                acc[cq*4+0] = fmaf(wg, vv4.x, acc[cq*4+0]);
                acc[cq*4+1] = fmaf(wg, vv4.y, acc[cq*4+1]);
                acc[cq*4+2] = fmaf(wg, vv4.z, acc[cq*4+2]);
                acc[cq*4+3] = fmaf(wg, vv4.w, acc[cq*4+3]);
            }
        }
        #pragma unroll
        for (int c = 0; c < 16; ++c) {
            float t1 = acc[c] + __shfl_xor(acc[c], 1);
            float tot = t1 + __shfl_xor(t1, 2);
            if ((c >> 3) == qq) op[(size_t)c * HWc] = tot * inv;
        }
    }
    // ================= PV pass B: channels 16..31 =================
    {
        float acc[16];
        #pragma unroll
        for (int c = 0; c < 16; ++c) acc[c] = 0.f;
        #pragma unroll
        for (int cq = 4; cq < 8; ++cq) {
            #pragma unroll
            for (int t = 0; t < 16; ++t) {
                int dyl = t >> 3, dx = t & 7;
                const float4 vv4 = *(const float4*)(myr + (dyl * 15 + dx) * 36 + cq * 4);
                float wg = __uint_as_float(s[t]);
                int k = (cq - 4) * 4;
                acc[k+0] = fmaf(wg, vv4.x, acc[k+0]);
                acc[k+1] = fmaf(wg, vv4.y, acc[k+1]);
                acc[k+2] = fmaf(wg, vv4.z, acc[k+2]);
                acc[k+3] = fmaf(wg, vv4.w, acc[k+3]);
            }
        }
        #pragma unroll
        for (int k = 0; k < 16; ++k) {
            int c = 16 + k;
            float t1 = acc[k] + __shfl_xor(acc[k], 1);
            float tot = t1 + __shfl_xor(t1, 2);
            if ((c >> 3) == qq) op[(size_t)c * HWc] = tot * inv;
        }
    }
}

// ---------------------------------- launcher ------------------------------------------
extern "C" void kernel_launch(void* const* d_in, const int* in_sizes, int n_in,
                              void* d_out, int out_size, void* d_ws, size_t ws_size,
                              hipStream_t stream)
{
    const float* vid  = (const float*)d_in[0];
    const float* qdww = (const float*)d_in[1];
    const float* qdwb = (const float*)d_in[2];
    const float* qpww = (const float*)d_in[3];
    const float* qpwb = (const float*)d_in[4];
    const float* kdww = (const float*)d_in[5];
    const float* kdwb = (const float*)d_in[6];
    const float* kpww = (const float*)d_in[7];
    const float* kpwb = (const float*)d_in[8];
    const float* vdww = (const float*)d_in[9];
    const float* vdwb = (const float*)d_in[10];
    const float* vpww = (const float*)d_in[11];
    const float* vpwb = (const float*)d_in[12];
    const float* pjw  = (const float*)d_in[13];
    const float* pjb  = (const float*)d_in[14];

    float* ws = (float*)d_ws;
    const size_t SZ = (size_t)Bc * Cc * HWc;   // 16 MB each
    float* buf0 = ws;            // q-dw -> q -> att
    float* buf1 = ws + SZ;       // k-dw -> k
    float* buf2 = ws + 2 * SZ;   // v-dw -> v

    hipFuncSetAttribute((const void*)pw_kernel, hipFuncAttributeMaxDynamicSharedMemorySize, 66560);

    dw_kernel<<<dim3(HWc / 256, Bc * Cc, 3), 256, 0, stream>>>(
        vid, qdww, qdwb, kdww, kdwb, vdww, vdwb, buf0, buf1, buf2);

    const float scale = 0.17677669529663687f;
    pw_kernel<<<dim3((Bc * HWc) / 128, 1, 3), 256, 66560, stream>>>(
        buf0, buf1, buf2, qpww, kpww, vpww, qpwb, kpwb, vpwb, buf0, buf1, buf2, scale);

    attn_kernel<<<dim3(Wd / 8, Hd / 8, Bc * NHc), 256, 0, stream>>>(buf0, buf1, buf2, buf0);

    pw_kernel<<<dim3((Bc * HWc) / 128, 1, 1), 256, 66560, stream>>>(
        buf0, buf0, buf0, pjw, pjw, pjw, pjb, pjb, pjb, (float*)d_out, (float*)d_out, (float*)d_out, 1.f);
}

// Round 10
// 300.093 us; speedup vs baseline: 5.1156x; 1.0078x over previous
//
#include <hip/hip_runtime.h>
#include <hip/hip_fp16.h>

static constexpr int Wd  = 128;
static constexpr int Hd  = 128;
static constexpr int HWc = Wd * Hd;    // 16384
static constexpr int Cc  = 128;
static constexpr int NHc = 4;
static constexpr int Bc  = 2;

__device__ __forceinline__ int refl(int i, int L) {
    i = i < 0 ? -i : i;
    return i >= L ? 2 * (L - 1) - i : i;
}

// float -> sortable u32 (strictly increasing bijection), and inverse
__device__ __forceinline__ unsigned f2s(float f) {
    unsigned u = __float_as_uint(f);
    return u ^ (0x80000000u | (unsigned)((int)u >> 31));
}
__device__ __forceinline__ float s2f(unsigned s) {
    unsigned u = (s & 0x80000000u) ? (s ^ 0x80000000u) : ~s;
    return __uint_as_float(u);
}

// ---------------- Kernel A: depthwise 3x3 + bias + relu (zero padding) ----------------
__global__ __launch_bounds__(256) void dw_kernel(
    const float* __restrict__ vid,
    const float* __restrict__ wq, const float* __restrict__ bq,
    const float* __restrict__ wk, const float* __restrict__ bk,
    const float* __restrict__ wv, const float* __restrict__ bv,
    float* __restrict__ yq, float* __restrict__ yk, float* __restrict__ yv)
{
    int pix  = blockIdx.x * 256 + threadIdx.x;
    int bc   = blockIdx.y;           // b*C + c
    int conv = blockIdx.z;
    const float* wsel = conv == 0 ? wq : (conv == 1 ? wk : wv);
    const float* bsel = conv == 0 ? bq : (conv == 1 ? bk : bv);
    float* osel       = conv == 0 ? yq : (conv == 1 ? yk : yv);
    int c = bc & (Cc - 1);
    int y = pix >> 7, x = pix & (Wd - 1);
    const float* src = vid + bc * HWc;
    const float* wp  = wsel + c * 9;
    float acc = 0.f;
    #pragma unroll
    for (int ky = 0; ky < 3; ++ky) {
        int iy = y + ky - 1;
        if (iy < 0 || iy >= Hd) continue;
        #pragma unroll
        for (int kx = 0; kx < 3; ++kx) {
            int ix = x + kx - 1;
            if (ix < 0 || ix >= Wd) continue;
            acc = fmaf(src[iy * Wd + ix], wp[ky * 3 + kx], acc);
        }
    }
    acc += bsel[c];
    osel[bc * HWc + pix] = fmaxf(acc, 0.f);
}

// ---------------- Kernel B/D: pointwise GEMM, float4 micro-tile, direct stores -------
__global__ __launch_bounds__(256) void pw_kernel(
    const float* y0p, const float* y1p, const float* y2p,
    const float* __restrict__ w0,  const float* __restrict__ w1,  const float* __restrict__ w2,
    const float* __restrict__ b0,  const float* __restrict__ b1,  const float* __restrict__ b2,
    float* o0, float* o1, float* o2,
    float scale0)
{
    extern __shared__ float lds[];
    float* wl = lds;            // [64 cc][132]
    float* yl = lds + 8448;     // [64 cc][128 p]

    int z = blockIdx.z;
    const float* yin  = z == 0 ? y0p : (z == 1 ? y1p : y2p);
    const float* wmat = z == 0 ? w0  : (z == 1 ? w1  : w2);
    const float* bias = z == 0 ? b0  : (z == 1 ? b1  : b2);
    float* out        = z == 0 ? o0  : (z == 1 ? o1  : o2);
    float scale       = z == 0 ? scale0 : 1.f;

    int tid = threadIdx.x;
    int ot = tid & 15, pt = tid >> 4;
    int gp  = blockIdx.x * 128;
    int b   = gp >> 14;
    int pof = gp & (HWc - 1);
    const float* yb = yin + b * Cc * HWc + pof;

    float acc[2][2][4][4];
    #pragma unroll
    for (int a = 0; a < 2; ++a)
        #pragma unroll
        for (int c = 0; c < 2; ++c)
            #pragma unroll
            for (int i = 0; i < 4; ++i)
                #pragma unroll
                for (int j = 0; j < 4; ++j) acc[a][c][i][j] = 0.f;

    for (int kh = 0; kh < 2; ++kh) {
        int c0 = kh * 64;
        for (int i = tid; i < 8192; i += 256) {
            int cc = i & 63, o = i >> 6;
            wl[cc * 132 + o] = wmat[o * 128 + c0 + cc];
        }
        for (int i = tid; i < 8192; i += 256) {
            int p = i & 127, cc = i >> 7;
            yl[cc * 128 + p] = yb[(c0 + cc) * HWc + p];
        }
        __syncthreads();
        #pragma unroll 4
        for (int cc = 0; cc < 64; ++cc) {
            float4 wv[2], pv[2];
            wv[0] = *(const float4*)(wl + cc * 132 + 4 * ot);
            wv[1] = *(const float4*)(wl + cc * 132 + 64 + 4 * ot);
            pv[0] = *(const float4*)(yl + cc * 128 + 4 * pt);
            pv[1] = *(const float4*)(yl + cc * 128 + 64 + 4 * pt);
            #pragma unroll
            for (int oh = 0; oh < 2; ++oh) {
                const float wo[4] = {wv[oh].x, wv[oh].y, wv[oh].z, wv[oh].w};
                #pragma unroll
                for (int ph = 0; ph < 2; ++ph) {
                    const float pp[4] = {pv[ph].x, pv[ph].y, pv[ph].z, pv[ph].w};
                    #pragma unroll
                    for (int oi = 0; oi < 4; ++oi)
                        #pragma unroll
                        for (int pi = 0; pi < 4; ++pi)
                            acc[oh][ph][oi][pi] = fmaf(wo[oi], pp[pi], acc[oh][ph][oi][pi]);
                }
            }
        }
        __syncthreads();
    }

    float* ob = out + b * Cc * HWc + pof;
    #pragma unroll
    for (int oh = 0; oh < 2; ++oh)
        #pragma unroll
        for (int oi = 0; oi < 4; ++oi) {
            int o = oh * 64 + 4 * ot + oi;
            float bo = bias[o];
            float* row = ob + o * HWc;
            #pragma unroll
            for (int ph = 0; ph < 2; ++ph) {
                float4 v;
                v.x = (acc[oh][ph][oi][0] + bo) * scale;
                v.y = (acc[oh][ph][oi][1] + bo) * scale;
                v.z = (acc[oh][ph][oi][2] + bo) * scale;
                v.w = (acc[oh][ph][oi][3] + bo) * scale;
                *(float4*)(row + ph * 64 + 4 * pt) = v;
            }
        }
}

// ---------------- Kernel C1: QK + top-16 rank + softmax -> packed fp16 weights --------
// 8x8 tile, 256 threads; quad shares pixel, lane qq owns offsets qq*16..qq*16+15.
// Writes normalized weights as 32 u32 slots/pixel (fp16 pairs) IN PLACE over q's
// buffer (exact footprint: 32 floats/pixel). Safe: quad q-reads precede w-stores in
// wave lockstep; blocks touch only their own pixel columns. q/wout NOT __restrict__
// (same buffer). Split-kernel rationale: round 8/9's monolithic kernel filled the
// 128-VGPR cap and spilled ~90 MB/side; each split kernel's true live state (~25-60)
// sits far below the cap.
__global__ __launch_bounds__(256, 2) void qk_kernel(
    const float* q, const float* __restrict__ kk, unsigned* wout)
{
    __shared__ float lds[225 * 36];
    __shared__ int go_l[225];
    int tid = threadIdx.x;
    int x0 = blockIdx.x * 8, y0 = blockIdx.y * 8;
    int bn = blockIdx.z;
    const float* kb = kk + bn * 32 * HWc;

    if (tid < 225) {
        int ry = tid / 15, rx = tid - ry * 15;
        go_l[tid] = refl(y0 - 4 + ry, Hd) * Wd + refl(x0 - 4 + rx, Wd);
    }
    __syncthreads();

    // ---- stage K: cb = tid&7 fixed per thread; 4 scalar loads per unit
    {
        int cb = tid & 7;
        const float* kc = kb + cb * 4 * HWc;
        for (int u = tid; u < 1800; u += 256) {
            int pix = u >> 3;
            int go = go_l[pix];
            float4 v;
            v.x = kc[go];
            v.y = kc[HWc + go];
            v.z = kc[2 * HWc + go];
            v.w = kc[3 * HWc + go];
            *(float4*)(lds + pix * 36 + cb * 4) = v;
        }
    }
    __syncthreads();

    int qq = tid & 3;
    int pl = tid >> 2;
    int px = pl & 7, py = pl >> 3;
    int gq = (y0 + py) * Wd + (x0 + px);
    const float* myr = lds + ((py + 2 * qq) * 15 + px) * 36;

    // ---- QK: my 16 offsets x all 32 channels
    float d[16];
    #pragma unroll
    for (int i = 0; i < 16; ++i) d[i] = 0.f;
    {
        const float* qp = q + bn * 32 * HWc + gq;
        #pragma unroll
        for (int cq = 0; cq < 8; ++cq) {
            float4 q4;
            q4.x = qp[(cq * 4 + 0) * HWc];
            q4.y = qp[(cq * 4 + 1) * HWc];
            q4.z = qp[(cq * 4 + 2) * HWc];
            q4.w = qp[(cq * 4 + 3) * HWc];
            #pragma unroll
            for (int t = 0; t < 16; ++t) {
                int dyl = t >> 3, dx = t & 7;
                const float4 kv = *(const float4*)(myr + (dyl * 15 + dx) * 36 + cq * 4);
                d[t] = fmaf(q4.x, kv.x, fmaf(q4.y, kv.y, fmaf(q4.z, kv.z, fmaf(q4.w, kv.w, d[t]))));
            }
        }
    }
    unsigned s[16];
    #pragma unroll
    for (int i = 0; i < 16; ++i) s[i] = f2s(d[i]);

    // ---- cooperative top-16 ranking (integer keys; exact lax.top_k ties)
    unsigned rk[4];
    #pragma unroll
    for (int i = 0; i < 4; ++i) rk[i] = 0u;
    #pragma unroll
    for (int i = 0; i < 15; ++i) {
        #pragma unroll
        for (int j = i + 1; j < 16; ++j) {
            bool jw = s[j] > s[i];
            rk[i >> 2] += jw ? (1u << (8 * (i & 3))) : 0u;
            rk[j >> 2] += jw ? 0u : (1u << (8 * (j & 3)));
        }
    }
    #pragma unroll
    for (int m = 1; m <= 3; ++m) {
        unsigned plow = ((m == 1) ? (qq & 1) : ((qq >> 1) & 1)) ? 1u : 0u;
        #pragma unroll
        for (int j = 0; j < 16; ++j) {
            unsigned spa = __shfl_xor(s[j], m) + plow;   // beat <=> spa > s_i
            #pragma unroll
            for (int i = 0; i < 16; ++i)
                rk[i >> 2] += (spa > s[i]) ? (1u << (8 * (i & 3))) : 0u;
        }
    }

    // ---- softmax over the selected 16, normalized
    unsigned smax = s[0];
    #pragma unroll
    for (int i = 1; i < 16; ++i) smax = max(smax, s[i]);
    smax = max(smax, (unsigned)__shfl_xor(smax, 1));
    smax = max(smax, (unsigned)__shfl_xor(smax, 2));
    float dmax = s2f(smax);
    float w[16];
    float sum = 0.f;
    #pragma unroll
    for (int i = 0; i < 16; ++i) {
        unsigned r = (rk[i >> 2] >> (8 * (i & 3))) & 255u;
        float e = (r < 16u) ? __expf(s2f(s[i]) - dmax) : 0.f;
        w[i] = e;
        sum += e;
    }
    sum += __shfl_xor(sum, 1);
    sum += __shfl_xor(sum, 2);
    float inv = 1.0f / sum;

    // ---- pack normalized weights to fp16 pairs; store into q's footprint
    unsigned* wp = wout + (bn * 32 + qq * 8) * HWc + gq;
    #pragma unroll
    for (int k = 0; k < 8; ++k) {
        unsigned lo = __half_as_ushort(__float2half(w[2 * k] * inv));
        unsigned hi = __half_as_ushort(__float2half(w[2 * k + 1] * inv));
        wp[k * HWc] = lo | (hi << 16);
    }
}

// ---------------- Kernel C2: PV gather with precomputed weights -----------------------
// Reads packed fp16 weights (buf0) + V (buf2), writes att c-major into buf1 (dead k).
__global__ __launch_bounds__(256, 2) void pv_kernel(
    const unsigned* __restrict__ win, const float* __restrict__ vv,
    float* __restrict__ att)
{
    __shared__ float lds[225 * 36];
    __shared__ int go_l[225];
    int tid = threadIdx.x;
    int x0 = blockIdx.x * 8, y0 = blockIdx.y * 8;
    int bn = blockIdx.z;
    const float* vb = vv + bn * 32 * HWc;

    if (tid < 225) {
        int ry = tid / 15, rx = tid - ry * 15;
        go_l[tid] = refl(y0 - 4 + ry, Hd) * Wd + refl(x0 - 4 + rx, Wd);
    }
    __syncthreads();

    int qq = tid & 3;
    int pl = tid >> 2;
    int px = pl & 7, py = pl >> 3;
    int gq = (y0 + py) * Wd + (x0 + px);
    const float* myr = lds + ((py + 2 * qq) * 15 + px) * 36;

    // ---- issue weight loads (8 u32), then stage V (loads overlap)
    unsigned wr[8];
    {
        const unsigned* wp = win + (bn * 32 + qq * 8) * HWc + gq;
        #pragma unroll
        for (int k = 0; k < 8; ++k) wr[k] = wp[k * HWc];
    }
    {
        int cb = tid & 7;
        const float* vc = vb + cb * 4 * HWc;
        for (int u = tid; u < 1800; u += 256) {
            int pix = u >> 3;
            int go = go_l[pix];
            float4 v;
            v.x = vc[go];
            v.y = vc[HWc + go];
            v.z = vc[2 * HWc + go];
            v.w = vc[3 * HWc + go];
            *(float4*)(lds + pix * 36 + cb * 4) = v;
        }
    }
    float w[16];
    #pragma unroll
    for (int k = 0; k < 8; ++k) {
        w[2 * k]     = __half2float(__ushort_as_half((unsigned short)(wr[k] & 0xffffu)));
        w[2 * k + 1] = __half2float(__ushort_as_half((unsigned short)(wr[k] >> 16)));
    }
    __syncthreads();

    float* op = att + bn * 32 * HWc + gq;
    // ---- PV pass A: channels 0..15
    {
        float acc[16];
        #pragma unroll
        for (int c = 0; c < 16; ++c) acc[c] = 0.f;
        #pragma unroll
        for (int cq = 0; cq < 4; ++cq) {
            #pragma unroll
            for (int t = 0; t < 16; ++t) {
                int dyl = t >> 3, dx = t & 7;
                const float4 vv4 = *(const float4*)(myr + (dyl * 15 + dx) * 36 + cq * 4);
                float wg = w[t];
                acc[cq*4+0] = fmaf(wg, vv4.x, acc[cq*4+0]);
                acc[cq*4+1] = fmaf(wg, vv4.y, acc[cq*4+1]);
                acc[cq*4+2] = fmaf(wg, vv4.z, acc[cq*4+2]);
                acc[cq*4+3] = fmaf(wg, vv4.w, acc[cq*4+3]);
            }
        }
        #pragma unroll
        for (int c = 0; c < 16; ++c) {
            float t1 = acc[c] + __shfl_xor(acc[c], 1);
            float tot = t1 + __shfl_xor(t1, 2);
            if ((c >> 3) == qq) op[c * HWc] = tot;
        }
    }
    // ---- PV pass B: channels 16..31
    {
        float acc[16];
        #pragma unroll
        for (int c = 0; c < 16; ++c) acc[c] = 0.f;
        #pragma unroll
        for (int cq = 4; cq < 8; ++cq) {
            #pragma unroll
            for (int t = 0; t < 16; ++t) {
                int dyl = t >> 3, dx = t & 7;
                const float4 vv4 = *(const float4*)(myr + (dyl * 15 + dx) * 36 + cq * 4);
                float wg = w[t];
                int k = (cq - 4) * 4;
                acc[k+0] = fmaf(wg, vv4.x, acc[k+0]);
                acc[k+1] = fmaf(wg, vv4.y, acc[k+1]);
                acc[k+2] = fmaf(wg, vv4.z, acc[k+2]);
                acc[k+3] = fmaf(wg, vv4.w, acc[k+3]);
            }
        }
        #pragma unroll
        for (int k = 0; k < 16; ++k) {
            int c = 16 + k;
            float t1 = acc[k] + __shfl_xor(acc[k], 1);
            float tot = t1 + __shfl_xor(t1, 2);
            if ((c >> 3) == qq) op[c * HWc] = tot;
        }
    }
}

// ---------------------------------- launcher ------------------------------------------
extern "C" void kernel_launch(void* const* d_in, const int* in_sizes, int n_in,
                              void* d_out, int out_size, void* d_ws, size_t ws_size,
                              hipStream_t stream)
{
    const float* vid  = (const float*)d_in[0];
    const float* qdww = (const float*)d_in[1];
    const float* qdwb = (const float*)d_in[2];
    const float* qpww = (const float*)d_in[3];
    const float* qpwb = (const float*)d_in[4];
    const float* kdww = (const float*)d_in[5];
    const float* kdwb = (const float*)d_in[6];
    const float* kpww = (const float*)d_in[7];
    const float* kpwb = (const float*)d_in[8];
    const float* vdww = (const float*)d_in[9];
    const float* vdwb = (const float*)d_in[10];
    const float* vpww = (const float*)d_in[11];
    const float* vpwb = (const float*)d_in[12];
    const float* pjw  = (const float*)d_in[13];
    const float* pjb  = (const float*)d_in[14];

    float* ws = (float*)d_ws;
    const size_t SZ = (size_t)Bc * Cc * HWc;   // 16 MB each; total ws use 48 MB
    float* buf0 = ws;            // q-dw -> q -> packed fp16 weights
    float* buf1 = ws + SZ;       // k-dw -> k -> att
    float* buf2 = ws + 2 * SZ;   // v-dw -> v

    hipFuncSetAttribute((const void*)pw_kernel, hipFuncAttributeMaxDynamicSharedMemorySize, 66560);

    dw_kernel<<<dim3(HWc / 256, Bc * Cc, 3), 256, 0, stream>>>(
        vid, qdww, qdwb, kdww, kdwb, vdww, vdwb, buf0, buf1, buf2);

    const float scale = 0.17677669529663687f;
    pw_kernel<<<dim3((Bc * HWc) / 128, 1, 3), 256, 66560, stream>>>(
        buf0, buf1, buf2, qpww, kpww, vpww, qpwb, kpwb, vpwb, buf0, buf1, buf2, scale);

    qk_kernel<<<dim3(Wd / 8, Hd / 8, Bc * NHc), 256, 0, stream>>>(
        buf0, buf1, (unsigned*)buf0);

    pv_kernel<<<dim3(Wd / 8, Hd / 8, Bc * NHc), 256, 0, stream>>>(
        (const unsigned*)buf0, buf2, buf1);

    pw_kernel<<<dim3((Bc * HWc) / 128, 1, 1), 256, 66560, stream>>>(
        buf1, buf1, buf1, pjw, pjw, pjw, pjb, pjb, pjb, (float*)d_out, (float*)d_out, (float*)d_out, 1.f);
}

// Round 14
// 243.421 us; speedup vs baseline: 6.3065x; 1.2328x over previous
//
#include <hip/hip_runtime.h>
#include <hip/hip_fp16.h>

static constexpr int Wd  = 128;
static constexpr int Hd  = 128;
static constexpr int HWc = Wd * Hd;    // 16384
static constexpr int Cc  = 128;
static constexpr int NHc = 4;
static constexpr int Bc  = 2;

__device__ __forceinline__ int refl(int i, int L) {
    i = i < 0 ? -i : i;
    return i >= L ? 2 * (L - 1) - i : i;
}

// float -> sortable u32 (strictly increasing bijection), and inverse
__device__ __forceinline__ unsigned f2s(float f) {
    unsigned u = __float_as_uint(f);
    return u ^ (0x80000000u | (unsigned)((int)u >> 31));
}
__device__ __forceinline__ float s2f(unsigned s) {
    unsigned u = (s & 0x80000000u) ? (s ^ 0x80000000u) : ~s;
    return __uint_as_float(u);
}

// ---------------- Kernel A: depthwise 3x3 + bias + relu (zero padding) ----------------
__global__ __launch_bounds__(256) void dw_kernel(
    const float* __restrict__ vid,
    const float* __restrict__ wq, const float* __restrict__ bq,
    const float* __restrict__ wk, const float* __restrict__ bk,
    const float* __restrict__ wv, const float* __restrict__ bv,
    float* __restrict__ yq, float* __restrict__ yk, float* __restrict__ yv)
{
    int pix  = blockIdx.x * 256 + threadIdx.x;
    int bc   = blockIdx.y;           // b*C + c
    int conv = blockIdx.z;
    const float* wsel = conv == 0 ? wq : (conv == 1 ? wk : wv);
    const float* bsel = conv == 0 ? bq : (conv == 1 ? bk : bv);
    float* osel       = conv == 0 ? yq : (conv == 1 ? yk : yv);
    int c = bc & (Cc - 1);
    int y = pix >> 7, x = pix & (Wd - 1);
    const float* src = vid + bc * HWc;
    const float* wp  = wsel + c * 9;
    float acc = 0.f;
    #pragma unroll
    for (int ky = 0; ky < 3; ++ky) {
        int iy = y + ky - 1;
        if (iy < 0 || iy >= Hd) continue;
        #pragma unroll
        for (int kx = 0; kx < 3; ++kx) {
            int ix = x + kx - 1;
            if (ix < 0 || ix >= Wd) continue;
            acc = fmaf(src[iy * Wd + ix], wp[ky * 3 + kx], acc);
        }
    }
    acc += bsel[c];
    osel[bc * HWc + pix] = fmaxf(acc, 0.f);
}

// ---------------- Kernel B/D: pointwise GEMM, float4 micro-tile, direct stores -------
__global__ __launch_bounds__(256) void pw_kernel(
    const float* y0p, const float* y1p, const float* y2p,
    const float* __restrict__ w0,  const float* __restrict__ w1,  const float* __restrict__ w2,
    const float* __restrict__ b0,  const float* __restrict__ b1,  const float* __restrict__ b2,
    float* o0, float* o1, float* o2,
    float scale0)
{
    extern __shared__ float lds[];
    float* wl = lds;            // [64 cc][132]
    float* yl = lds + 8448;     // [64 cc][128 p]

    int z = blockIdx.z;
    const float* yin  = z == 0 ? y0p : (z == 1 ? y1p : y2p);
    const float* wmat = z == 0 ? w0  : (z == 1 ? w1  : w2);
    const float* bias = z == 0 ? b0  : (z == 1 ? b1  : b2);
    float* out        = z == 0 ? o0  : (z == 1 ? o1  : o2);
    float scale       = z == 0 ? scale0 : 1.f;

    int tid = threadIdx.x;
    int ot = tid & 15, pt = tid >> 4;
    int gp  = blockIdx.x * 128;
    int b   = gp >> 14;
    int pof = gp & (HWc - 1);
    const float* yb = yin + b * Cc * HWc + pof;

    float acc[2][2][4][4];
    #pragma unroll
    for (int a = 0; a < 2; ++a)
        #pragma unroll
        for (int c = 0; c < 2; ++c)
            #pragma unroll
            for (int i = 0; i < 4; ++i)
                #pragma unroll
                for (int j = 0; j < 4; ++j) acc[a][c][i][j] = 0.f;

    for (int kh = 0; kh < 2; ++kh) {
        int c0 = kh * 64;
        for (int i = tid; i < 8192; i += 256) {
            int cc = i & 63, o = i >> 6;
            wl[cc * 132 + o] = wmat[o * 128 + c0 + cc];
        }
        for (int i = tid; i < 8192; i += 256) {
            int p = i & 127, cc = i >> 7;
            yl[cc * 128 + p] = yb[(c0 + cc) * HWc + p];
        }
        __syncthreads();
        #pragma unroll 4
        for (int cc = 0; cc < 64; ++cc) {
            float4 wv[2], pv[2];
            wv[0] = *(const float4*)(wl + cc * 132 + 4 * ot);
            wv[1] = *(const float4*)(wl + cc * 132 + 64 + 4 * ot);
            pv[0] = *(const float4*)(yl + cc * 128 + 4 * pt);
            pv[1] = *(const float4*)(yl + cc * 128 + 64 + 4 * pt);
            #pragma unroll
            for (int oh = 0; oh < 2; ++oh) {
                const float wo[4] = {wv[oh].x, wv[oh].y, wv[oh].z, wv[oh].w};
                #pragma unroll
                for (int ph = 0; ph < 2; ++ph) {
                    const float pp[4] = {pv[ph].x, pv[ph].y, pv[ph].z, pv[ph].w};
                    #pragma unroll
                    for (int oi = 0; oi < 4; ++oi)
                        #pragma unroll
                        for (int pi = 0; pi < 4; ++pi)
                            acc[oh][ph][oi][pi] = fmaf(wo[oi], pp[pi], acc[oh][ph][oi][pi]);
                }
            }
        }
        __syncthreads();
    }

    float* ob = out + b * Cc * HWc + pof;
    #pragma unroll
    for (int oh = 0; oh < 2; ++oh)
        #pragma unroll
        for (int oi = 0; oi < 4; ++oi) {
            int o = oh * 64 + 4 * ot + oi;
            float bo = bias[o];
            float* row = ob + o * HWc;
            #pragma unroll
            for (int ph = 0; ph < 2; ++ph) {
                float4 v;
                v.x = (acc[oh][ph][oi][0] + bo) * scale;
                v.y = (acc[oh][ph][oi][1] + bo) * scale;
                v.z = (acc[oh][ph][oi][2] + bo) * scale;
                v.w = (acc[oh][ph][oi][3] + bo) * scale;
                *(float4*)(row + ph * 64 + 4 * pt) = v;
            }
        }
}

// ---------------- Kernel C1: QK + top-16 rank + softmax -> 16 scattered entries -------
// 8x4 pixel tile, 256 threads: 8 lanes share pixel pl=tid>>3; lane qq=tid&7 owns
// offsets qq*8..qq*8+7 (window row dy=qq) over all 32 channels. Region 15x11=165 pix,
// LDS 24 KB -> 6 blocks/CU. Ranks 0..63 are a permutation, so the 16 selected
// (rank<16) entries scatter uniquely: wout plane bn*32+r at pixel gq, value
// (fp16(weight)<<16)|t. Written over q's own 32-plane footprint: same-bn blocks own
// disjoint pixels, cross-bn plane sets disjoint -> race-free.
__global__ __launch_bounds__(256, 2) void qk_kernel(
    const float* q, const float* __restrict__ kk, unsigned* wout)
{
    __shared__ float lds[165 * 36];
    __shared__ int go_l[165];
    int tid = threadIdx.x;
    int x0 = blockIdx.x * 8, y0 = blockIdx.y * 4;
    int bn = blockIdx.z;
    const float* kb = kk + bn * 32 * HWc;

    if (tid < 165) {
        int ry = tid / 15, rx = tid - ry * 15;
        go_l[tid] = refl(y0 - 4 + ry, Hd) * Wd + refl(x0 - 4 + rx, Wd);
    }
    __syncthreads();

    // ---- stage K (165 pix x 8 quads = 1320 units); cb = tid&7 fixed
    {
        int cb = tid & 7;
        const float* kc = kb + cb * 4 * HWc;
        for (int u = tid; u < 1320; u += 256) {
            int pix = u >> 3;
            int go = go_l[pix];
            float4 v;
            v.x = kc[go];
            v.y = kc[HWc + go];
            v.z = kc[2 * HWc + go];
            v.w = kc[3 * HWc + go];
            *(float4*)(lds + pix * 36 + cb * 4) = v;
        }
    }
    __syncthreads();

    int qq = tid & 7;              // my window row (dy = qq), offsets qq*8..qq*8+7
    int pl = tid >> 3;             // pixel 0..31
    int px = pl & 7, py = pl >> 3;
    int gq = (y0 + py) * Wd + (x0 + px);
    const float* myr = lds + ((py + qq) * 15 + px) * 36;

    // ---- QK: my 8 offsets x all 32 channels
    float d[8];
    #pragma unroll
    for (int i = 0; i < 8; ++i) d[i] = 0.f;
    {
        const float* qp = q + bn * 32 * HWc + gq;
        #pragma unroll
        for (int cq = 0; cq < 8; ++cq) {
            float4 q4;
            q4.x = qp[(cq * 4 + 0) * HWc];
            q4.y = qp[(cq * 4 + 1) * HWc];
            q4.z = qp[(cq * 4 + 2) * HWc];
            q4.w = qp[(cq * 4 + 3) * HWc];
            #pragma unroll
            for (int j = 0; j < 8; ++j) {
                const float4 kv = *(const float4*)(myr + j * 36 + cq * 4);
                d[j] = fmaf(q4.x, kv.x, fmaf(q4.y, kv.y, fmaf(q4.z, kv.z, fmaf(q4.w, kv.w, d[j]))));
            }
        }
    }
    unsigned s[8];
    #pragma unroll
    for (int i = 0; i < 8; ++i) s[i] = f2s(d[i]);

    // ---- cooperative top-16 ranking (integer keys; exact lax.top_k ties)
    unsigned rk[2];
    rk[0] = rk[1] = 0u;
    #pragma unroll
    for (int i = 0; i < 7; ++i) {
        #pragma unroll
        for (int j = i + 1; j < 8; ++j) {
            bool jw = s[j] > s[i];
            rk[i >> 2] += jw ? (1u << (8 * (i & 3))) : 0u;
            rk[j >> 2] += jw ? 0u : (1u << (8 * (j & 3)));
        }
    }
    #pragma unroll
    for (int m = 1; m <= 7; ++m) {
        // partner qq^m has lower global indices iff qq's msb(m) bit is 1
        unsigned plow = ((m >= 4) ? (qq >> 2) : (m >= 2) ? (qq >> 1) : qq) & 1;
        #pragma unroll
        for (int j = 0; j < 8; ++j) {
            unsigned spa = __shfl_xor(s[j], m) + plow;   // beat <=> spa > s_i
            #pragma unroll
            for (int i = 0; i < 8; ++i)
                rk[i >> 2] += (spa > s[i]) ? (1u << (8 * (i & 3))) : 0u;
        }
    }

    // ---- softmax over the selected 16 (8-lane butterfly)
    unsigned smax = s[0];
    #pragma unroll
    for (int i = 1; i < 8; ++i) smax = max(smax, s[i]);
    smax = max(smax, (unsigned)__shfl_xor(smax, 1));
    smax = max(smax, (unsigned)__shfl_xor(smax, 2));
    smax = max(smax, (unsigned)__shfl_xor(smax, 4));
    float dmax = s2f(smax);
    float w[8];
    float sum = 0.f;
    #pragma unroll
    for (int i = 0; i < 8; ++i) {
        unsigned r = (rk[i >> 2] >> (8 * (i & 3))) & 255u;
        float e = (r < 16u) ? __expf(s2f(s[i]) - dmax) : 0.f;
        w[i] = e;
        sum += e;
    }
    sum += __shfl_xor(sum, 1);
    sum += __shfl_xor(sum, 2);
    sum += __shfl_xor(sum, 4);
    float inv = 1.0f / sum;

    // ---- scatter the 16 selected entries by rank (unique slots 0..15)
    unsigned* wp = wout + bn * 32 * HWc + gq;
    #pragma unroll
    for (int i = 0; i < 8; ++i) {
        unsigned r = (rk[i >> 2] >> (8 * (i & 3))) & 255u;
        if (r < 16u) {
            unsigned hb = __half_as_ushort(__float2half(w[i] * inv));
            wp[r * HWc] = (hb << 16) | (unsigned)(qq * 8 + i);
        }
    }
}

// ---------------- Kernel C2: PV gather over the 16 selected entries -------------------
// Same 8x4 geometry. Lane qq owns channel quad qq*4..qq*4+3; iterates all 16 entries:
// 16 ds_read_b128 + 64 fma, no cross-lane combine. Writes att into buf1 (dead k).
__global__ __launch_bounds__(256, 2) void pv_kernel(
    const unsigned* __restrict__ win, const float* __restrict__ vv,
    float* __restrict__ att)
{
    __shared__ float lds[165 * 36];
    __shared__ int go_l[165];
    int tid = threadIdx.x;
    int x0 = blockIdx.x * 8, y0 = blockIdx.y * 4;
    int bn = blockIdx.z;
    const float* vb = vv + bn * 32 * HWc;

    if (tid < 165) {
        int ry = tid / 15, rx = tid - ry * 15;
        go_l[tid] = refl(y0 - 4 + ry, Hd) * Wd + refl(x0 - 4 + rx, Wd);
    }
    __syncthreads();

    int qq = tid & 7;
    int pl = tid >> 3;
    int px = pl & 7, py = pl >> 3;
    int gq = (y0 + py) * Wd + (x0 + px);

    // ---- issue entry loads early (same addr across the 8-lane group -> broadcast)
    unsigned ent[16];
    {
        const unsigned* wp = win + bn * 32 * HWc + gq;
        #pragma unroll
        for (int e = 0; e < 16; ++e) ent[e] = wp[e * HWc];
    }

    // ---- stage V
    {
        int cb = tid & 7;
        const float* vc = vb + cb * 4 * HWc;
        for (int u = tid; u < 1320; u += 256) {
            int pix = u >> 3;
            int go = go_l[pix];
            float4 v;
            v.x = vc[go];
            v.y = vc[HWc + go];
            v.z = vc[2 * HWc + go];
            v.w = vc[3 * HWc + go];
            *(float4*)(lds + pix * 36 + cb * 4) = v;
        }
    }
    __syncthreads();

    // ---- PV: my channel quad over the 16 selected offsets
    float a0 = 0.f, a1 = 0.f, a2 = 0.f, a3 = 0.f;
    const float* base = lds + (py * 15 + px) * 36 + qq * 4;
    #pragma unroll
    for (int e = 0; e < 16; ++e) {
        unsigned en = ent[e];
        int t = en & 63;
        int dy = t >> 3, dx = t & 7;
        float wg = __half2float(__ushort_as_half((unsigned short)(en >> 16)));
        const float4 v4 = *(const float4*)(base + (dy * 15 + dx) * 36);
        a0 = fmaf(wg, v4.x, a0);
        a1 = fmaf(wg, v4.y, a1);
        a2 = fmaf(wg, v4.z, a2);
        a3 = fmaf(wg, v4.w, a3);
    }

    float* op = att + (bn * 32 + qq * 4) * HWc + gq;
    op[0]       = a0;
    op[HWc]     = a1;
    op[2 * HWc] = a2;
    op[3 * HWc] = a3;
}

// ---------------------------------- launcher ------------------------------------------
extern "C" void kernel_launch(void* const* d_in, const int* in_sizes, int n_in,
                              void* d_out, int out_size, void* d_ws, size_t ws_size,
                              hipStream_t stream)
{
    const float* vid  = (const float*)d_in[0];
    const float* qdww = (const float*)d_in[1];
    const float* qdwb = (const float*)d_in[2];
    const float* qpww = (const float*)d_in[3];
    const float* qpwb = (const float*)d_in[4];
    const float* kdww = (const float*)d_in[5];
    const float* kdwb = (const float*)d_in[6];
    const float* kpww = (const float*)d_in[7];
    const float* kpwb = (const float*)d_in[8];
    const float* vdww = (const float*)d_in[9];
    const float* vdwb = (const float*)d_in[10];
    const float* vpww = (const float*)d_in[11];
    const float* vpwb = (const float*)d_in[12];
    const float* pjw  = (const float*)d_in[13];
    const float* pjb  = (const float*)d_in[14];

    float* ws = (float*)d_ws;
    const size_t SZ = (size_t)Bc * Cc * HWc;   // 16 MB each; total ws use 48 MB
    float* buf0 = ws;            // q-dw -> q -> selected (offset,weight) entries
    float* buf1 = ws + SZ;       // k-dw -> k -> att
    float* buf2 = ws + 2 * SZ;   // v-dw -> v

    hipFuncSetAttribute((const void*)pw_kernel, hipFuncAttributeMaxDynamicSharedMemorySize, 66560);

    dw_kernel<<<dim3(HWc / 256, Bc * Cc, 3), 256, 0, stream>>>(
        vid, qdww, qdwb, kdww, kdwb, vdww, vdwb, buf0, buf1, buf2);

    const float scale = 0.17677669529663687f;
    pw_kernel<<<dim3((Bc * HWc) / 128, 1, 3), 256, 66560, stream>>>(
        buf0, buf1, buf2, qpww, kpww, vpww, qpwb, kpwb, vpwb, buf0, buf1, buf2, scale);

    qk_kernel<<<dim3(Wd / 8, Hd / 4, Bc * NHc), 256, 0, stream>>>(
        buf0, buf1, (unsigned*)buf0);

    pv_kernel<<<dim3(Wd / 8, Hd / 4, Bc * NHc), 256, 0, stream>>>(
        (const unsigned*)buf0, buf2, buf1);

    pw_kernel<<<dim3((Bc * HWc) / 128, 1, 1), 256, 66560, stream>>>(
        buf1, buf1, buf1, pjw, pjw, pjw, pjb, pjb, pjb, (float*)d_out, (float*)d_out, (float*)d_out, 1.f);
}

// Round 15
// 238.084 us; speedup vs baseline: 6.4479x; 1.0224x over previous
//
#include <hip/hip_runtime.h>
#include <hip/hip_fp16.h>

static constexpr int Wd  = 128;
static constexpr int Hd  = 128;
static constexpr int HWc = Wd * Hd;    // 16384
static constexpr int Cc  = 128;
static constexpr int NHc = 4;
static constexpr int Bc  = 2;

__device__ __forceinline__ int refl(int i, int L) {
    i = i < 0 ? -i : i;
    return i >= L ? 2 * (L - 1) - i : i;
}

// float -> sortable u32 (strictly increasing bijection), and inverse
__device__ __forceinline__ unsigned f2s(float f) {
    unsigned u = __float_as_uint(f);
    return u ^ (0x80000000u | (unsigned)((int)u >> 31));
}
__device__ __forceinline__ float s2f(unsigned s) {
    unsigned u = (s & 0x80000000u) ? (s ^ 0x80000000u) : ~s;
    return __uint_as_float(u);
}

// ---------------- Kernel A: depthwise 3x3 + bias + relu (zero padding) ----------------
__global__ __launch_bounds__(256) void dw_kernel(
    const float* __restrict__ vid,
    const float* __restrict__ wq, const float* __restrict__ bq,
    const float* __restrict__ wk, const float* __restrict__ bk,
    const float* __restrict__ wv, const float* __restrict__ bv,
    float* __restrict__ yq, float* __restrict__ yk, float* __restrict__ yv)
{
    int pix  = blockIdx.x * 256 + threadIdx.x;
    int bc   = blockIdx.y;           // b*C + c
    int conv = blockIdx.z;
    const float* wsel = conv == 0 ? wq : (conv == 1 ? wk : wv);
    const float* bsel = conv == 0 ? bq : (conv == 1 ? bk : bv);
    float* osel       = conv == 0 ? yq : (conv == 1 ? yk : yv);
    int c = bc & (Cc - 1);
    int y = pix >> 7, x = pix & (Wd - 1);
    const float* src = vid + bc * HWc;
    const float* wp  = wsel + c * 9;
    float acc = 0.f;
    #pragma unroll
    for (int ky = 0; ky < 3; ++ky) {
        int iy = y + ky - 1;
        if (iy < 0 || iy >= Hd) continue;
        #pragma unroll
        for (int kx = 0; kx < 3; ++kx) {
            int ix = x + kx - 1;
            if (ix < 0 || ix >= Wd) continue;
            acc = fmaf(src[iy * Wd + ix], wp[ky * 3 + kx], acc);
        }
    }
    acc += bsel[c];
    osel[bc * HWc + pix] = fmaxf(acc, 0.f);
}

// ---------------- Kernel B/D: pointwise GEMM, float4 micro-tile, direct stores -------
__global__ __launch_bounds__(256) void pw_kernel(
    const float* y0p, const float* y1p, const float* y2p,
    const float* __restrict__ w0,  const float* __restrict__ w1,  const float* __restrict__ w2,
    const float* __restrict__ b0,  const float* __restrict__ b1,  const float* __restrict__ b2,
    float* o0, float* o1, float* o2,
    float scale0)
{
    extern __shared__ float lds[];
    float* wl = lds;            // [64 cc][132]
    float* yl = lds + 8448;     // [64 cc][128 p]

    int z = blockIdx.z;
    const float* yin  = z == 0 ? y0p : (z == 1 ? y1p : y2p);
    const float* wmat = z == 0 ? w0  : (z == 1 ? w1  : w2);
    const float* bias = z == 0 ? b0  : (z == 1 ? b1  : b2);
    float* out        = z == 0 ? o0  : (z == 1 ? o1  : o2);
    float scale       = z == 0 ? scale0 : 1.f;

    int tid = threadIdx.x;
    int ot = tid & 15, pt = tid >> 4;
    int gp  = blockIdx.x * 128;
    int b   = gp >> 14;
    int pof = gp & (HWc - 1);
    const float* yb = yin + b * Cc * HWc + pof;

    float acc[2][2][4][4];
    #pragma unroll
    for (int a = 0; a < 2; ++a)
        #pragma unroll
        for (int c = 0; c < 2; ++c)
            #pragma unroll
            for (int i = 0; i < 4; ++i)
                #pragma unroll
                for (int j = 0; j < 4; ++j) acc[a][c][i][j] = 0.f;

    for (int kh = 0; kh < 2; ++kh) {
        int c0 = kh * 64;
        for (int i = tid; i < 8192; i += 256) {
            int cc = i & 63, o = i >> 6;
            wl[cc * 132 + o] = wmat[o * 128 + c0 + cc];
        }
        for (int i = tid; i < 8192; i += 256) {
            int p = i & 127, cc = i >> 7;
            yl[cc * 128 + p] = yb[(c0 + cc) * HWc + p];
        }
        __syncthreads();
        #pragma unroll 4
        for (int cc = 0; cc < 64; ++cc) {
            float4 wv[2], pv[2];
            wv[0] = *(const float4*)(wl + cc * 132 + 4 * ot);
            wv[1] = *(const float4*)(wl + cc * 132 + 64 + 4 * ot);
            pv[0] = *(const float4*)(yl + cc * 128 + 4 * pt);
            pv[1] = *(const float4*)(yl + cc * 128 + 64 + 4 * pt);
            #pragma unroll
            for (int oh = 0; oh < 2; ++oh) {
                const float wo[4] = {wv[oh].x, wv[oh].y, wv[oh].z, wv[oh].w};
                #pragma unroll
                for (int ph = 0; ph < 2; ++ph) {
                    const float pp[4] = {pv[ph].x, pv[ph].y, pv[ph].z, pv[ph].w};
                    #pragma unroll
                    for (int oi = 0; oi < 4; ++oi)
                        #pragma unroll
                        for (int pi = 0; pi < 4; ++pi)
                            acc[oh][ph][oi][pi] = fmaf(wo[oi], pp[pi], acc[oh][ph][oi][pi]);
                }
            }
        }
        __syncthreads();
    }

    float* ob = out + b * Cc * HWc + pof;
    #pragma unroll
    for (int oh = 0; oh < 2; ++oh)
        #pragma unroll
        for (int oi = 0; oi < 4; ++oi) {
            int o = oh * 64 + 4 * ot + oi;
            float bo = bias[o];
            float* row = ob + o * HWc;
            #pragma unroll
            for (int ph = 0; ph < 2; ++ph) {
                float4 v;
                v.x = (acc[oh][ph][oi][0] + bo) * scale;
                v.y = (acc[oh][ph][oi][1] + bo) * scale;
                v.z = (acc[oh][ph][oi][2] + bo) * scale;
                v.w = (acc[oh][ph][oi][3] + bo) * scale;
                *(float4*)(row + ph * 64 + 4 * pt) = v;
            }
        }
}

// ---------------- Kernel C: fused neighborhood attention ------------------------------
// 8x4 pixel tile, 256 threads: 8 lanes share pixel pl=tid>>3. Phase 1 (QK/rank): lane
// qq=tid&7 owns offsets qq*8..qq*8+7 (window row dy=qq). Phase 2 (PV): lane qq owns
// channel quad qq*4..qq*4+3. Selected entries pass through a 2KB LDS array (ranks are
// a permutation of 0..63 -> 16 unique slots; scatter/read within the same 8 lanes).
// Fusion rationale: round-14 split proved each phase needs <=50 VGPR, so fused peak
// stays under the (256,2)=128 cap with no spill (watch WRITE_SIZE ~= 16.5 MB), while
// killing the 16 MB entry round-trip + one launch. Ranking uses 8 independent byte
// counters: rkc[i] += (a > b) compiles to v_cmp + v_addc (2 ops/pair).
// Region 15x11 x 32ch stride 36 (23.8KB) + go (0.7K) + entries (2K) = 25.9KB -> 6 blk/CU.
__global__ __launch_bounds__(256, 2) void attn_kernel(
    const float* __restrict__ q, const float* __restrict__ kk,
    const float* __restrict__ vv, float* __restrict__ att)
{
    __shared__ float reg_l[165 * 36];
    __shared__ int go_l[165];
    __shared__ unsigned ent_l[32 * 16];
    int tid = threadIdx.x;
    int x0 = blockIdx.x * 8, y0 = blockIdx.y * 4;
    int bn = blockIdx.z;
    const float* kb = kk + bn * 32 * HWc;
    const float* vb = vv + bn * 32 * HWc;

    if (tid < 165) {
        int ry = tid / 15, rx = tid - ry * 15;
        go_l[tid] = refl(y0 - 4 + ry, Hd) * Wd + refl(x0 - 4 + rx, Wd);
    }
    __syncthreads();

    int qq = tid & 7;
    int pl = tid >> 3;             // pixel 0..31
    int px = pl & 7, py = pl >> 3;
    int gq = (y0 + py) * Wd + (x0 + px);

    // ================= stage K (165 pix x 8 quads = 1320 units) =================
    {
        int cb = tid & 7;
        const float* kc = kb + cb * 4 * HWc;
        for (int u = tid; u < 1320; u += 256) {
            int pix = u >> 3;
            int go = go_l[pix];
            float4 v;
            v.x = kc[go];
            v.y = kc[HWc + go];
            v.z = kc[2 * HWc + go];
            v.w = kc[3 * HWc + go];
            *(float4*)(reg_l + pix * 36 + cb * 4) = v;
        }
    }
    __syncthreads();

    // ================= QK: my 8 offsets (row dy=qq) x all 32 channels ============
    float d[8];
    #pragma unroll
    for (int i = 0; i < 8; ++i) d[i] = 0.f;
    {
        const float* myr = reg_l + ((py + qq) * 15 + px) * 36;
        const float* qp = q + bn * 32 * HWc + gq;
        #pragma unroll
        for (int cq = 0; cq < 8; ++cq) {
            float4 q4;
            q4.x = qp[(cq * 4 + 0) * HWc];
            q4.y = qp[(cq * 4 + 1) * HWc];
            q4.z = qp[(cq * 4 + 2) * HWc];
            q4.w = qp[(cq * 4 + 3) * HWc];
            #pragma unroll
            for (int j = 0; j < 8; ++j) {
                const float4 kv = *(const float4*)(myr + j * 36 + cq * 4);
                d[j] = fmaf(q4.x, kv.x, fmaf(q4.y, kv.y, fmaf(q4.z, kv.z, fmaf(q4.w, kv.w, d[j]))));
            }
        }
    }
    unsigned s[8];
    #pragma unroll
    for (int i = 0; i < 8; ++i) s[i] = f2s(d[i]);
    __syncthreads();   // all QK reads of the K region complete

    // ================= stage V (overwrites region; latency overlaps ranking) =====
    {
        int cb = tid & 7;
        const float* vc = vb + cb * 4 * HWc;
        for (int u = tid; u < 1320; u += 256) {
            int pix = u >> 3;
            int go = go_l[pix];
            float4 v;
            v.x = vc[go];
            v.y = vc[HWc + go];
            v.z = vc[2 * HWc + go];
            v.w = vc[3 * HWc + go];
            *(float4*)(reg_l + pix * 36 + cb * 4) = v;
        }
    }

    // ================= cooperative top-16 ranking (byte counters) ================
    // rank(i) = #{j beating i}; j beats i iff s_j > s_i (j higher gidx) or
    // s_j >= s_i (j lower gidx). Exact lax.top_k tie semantics.
    unsigned rkc[8];
    #pragma unroll
    for (int i = 0; i < 8; ++i) rkc[i] = 0u;
    #pragma unroll
    for (int i = 0; i < 7; ++i) {
        #pragma unroll
        for (int j = i + 1; j < 8; ++j) {
            rkc[i] += (unsigned)(s[j] > s[i]);   // j (higher idx) beats i on strict >
            rkc[j] += (unsigned)(s[i] >= s[j]);  // i (lower idx) beats j on >=
        }
    }
    #pragma unroll
    for (int m = 1; m <= 7; ++m) {
        // partner qq^m has lower global indices iff qq's msb(m) bit is 1
        unsigned plow = ((m >= 4) ? (qq >> 2) : (m >= 2) ? (qq >> 1) : qq) & 1;
        #pragma unroll
        for (int j = 0; j < 8; ++j) {
            unsigned spa = __shfl_xor(s[j], m) + plow;   // beat <=> spa > s_i
            #pragma unroll
            for (int i = 0; i < 8; ++i)
                rkc[i] += (unsigned)(spa > s[i]);
        }
    }

    // ================= softmax over the selected 16 (8-lane butterfly) ===========
    unsigned smax = s[0];
    #pragma unroll
    for (int i = 1; i < 8; ++i) smax = max(smax, s[i]);
    smax = max(smax, (unsigned)__shfl_xor(smax, 1));
    smax = max(smax, (unsigned)__shfl_xor(smax, 2));
    smax = max(smax, (unsigned)__shfl_xor(smax, 4));
    float dmax = s2f(smax);
    float w[8];
    float sum = 0.f;
    #pragma unroll
    for (int i = 0; i < 8; ++i) {
        float e = (rkc[i] < 16u) ? __expf(s2f(s[i]) - dmax) : 0.f;
        w[i] = e;
        sum += e;
    }
    sum += __shfl_xor(sum, 1);
    sum += __shfl_xor(sum, 2);
    sum += __shfl_xor(sum, 4);
    float inv = 1.0f / sum;

    // ---- scatter selected (weight fp16, offset) entries to LDS by rank
    #pragma unroll
    for (int i = 0; i < 8; ++i) {
        if (rkc[i] < 16u) {
            unsigned hb = __half_as_ushort(__float2half(w[i]));
            ent_l[pl * 16 + rkc[i]] = (hb << 16) | (unsigned)(qq * 8 + i);
        }
    }
    __syncthreads();   // V staged + entries visible

    // ================= PV: my channel quad over the 16 selected offsets ==========
    uint4 ea = *(const uint4*)(ent_l + pl * 16);
    uint4 eb = *(const uint4*)(ent_l + pl * 16 + 4);
    uint4 ec = *(const uint4*)(ent_l + pl * 16 + 8);
    uint4 ed = *(const uint4*)(ent_l + pl * 16 + 12);
    unsigned ent[16] = {ea.x, ea.y, ea.z, ea.w, eb.x, eb.y, eb.z, eb.w,
                        ec.x, ec.y, ec.z, ec.w, ed.x, ed.y, ed.z, ed.w};
    float a0 = 0.f, a1 = 0.f, a2 = 0.f, a3 = 0.f;
    const float* base = reg_l + (py * 15 + px) * 36 + qq * 4;
    #pragma unroll
    for (int e = 0; e < 16; ++e) {
        unsigned en = ent[e];
        int t = en & 63;
        int dy = t >> 3, dx = t & 7;
        float wg = __half2float(__ushort_as_half((unsigned short)(en >> 16)));
        const float4 v4 = *(const float4*)(base + (dy * 15 + dx) * 36);
        a0 = fmaf(wg, v4.x, a0);
        a1 = fmaf(wg, v4.y, a1);
        a2 = fmaf(wg, v4.z, a2);
        a3 = fmaf(wg, v4.w, a3);
    }

    float* op = att + (bn * 32 + qq * 4) * HWc + gq;
    op[0]       = a0 * inv;
    op[HWc]     = a1 * inv;
    op[2 * HWc] = a2 * inv;
    op[3 * HWc] = a3 * inv;
}

// ---------------------------------- launcher ------------------------------------------
extern "C" void kernel_launch(void* const* d_in, const int* in_sizes, int n_in,
                              void* d_out, int out_size, void* d_ws, size_t ws_size,
                              hipStream_t stream)
{
    const float* vid  = (const float*)d_in[0];
    const float* qdww = (const float*)d_in[1];
    const float* qdwb = (const float*)d_in[2];
    const float* qpww = (const float*)d_in[3];
    const float* qpwb = (const float*)d_in[4];
    const float* kdww = (const float*)d_in[5];
    const float* kdwb = (const float*)d_in[6];
    const float* kpww = (const float*)d_in[7];
    const float* kpwb = (const float*)d_in[8];
    const float* vdww = (const float*)d_in[9];
    const float* vdwb = (const float*)d_in[10];
    const float* vpww = (const float*)d_in[11];
    const float* vpwb = (const float*)d_in[12];
    const float* pjw  = (const float*)d_in[13];
    const float* pjb  = (const float*)d_in[14];

    float* ws = (float*)d_ws;
    const size_t SZ = (size_t)Bc * Cc * HWc;   // 16 MB each; total ws use 48 MB
    float* buf0 = ws;            // q-dw -> q
    float* buf1 = ws + SZ;       // k-dw -> k -> att
    float* buf2 = ws + 2 * SZ;   // v-dw -> v

    hipFuncSetAttribute((const void*)pw_kernel, hipFuncAttributeMaxDynamicSharedMemorySize, 66560);

    dw_kernel<<<dim3(HWc / 256, Bc * Cc, 3), 256, 0, stream>>>(
        vid, qdww, qdwb, kdww, kdwb, vdww, vdwb, buf0, buf1, buf2);

    const float scale = 0.17677669529663687f;
    pw_kernel<<<dim3((Bc * HWc) / 128, 1, 3), 256, 66560, stream>>>(
        buf0, buf1, buf2, qpww, kpww, vpww, qpwb, kpwb, vpwb, buf0, buf1, buf2, scale);

    attn_kernel<<<dim3(Wd / 8, Hd / 4, Bc * NHc), 256, 0, stream>>>(
        buf0, buf1, buf2, buf1);

    pw_kernel<<<dim3((Bc * HWc) / 128, 1, 1), 256, 66560, stream>>>(
        buf1, buf1, buf1, pjw, pjw, pjw, pjb, pjb, pjb, (float*)d_out, (float*)d_out, (float*)d_out, 1.f);
}

// Round 16
// 195.783 us; speedup vs baseline: 7.8410x; 1.2161x over previous
//
#include <hip/hip_runtime.h>
#include <hip/hip_fp16.h>

static constexpr int Wd  = 128;
static constexpr int Hd  = 128;
static constexpr int HWc = Wd * Hd;    // 16384
static constexpr int Cc  = 128;
static constexpr int NHc = 4;
static constexpr int Bc  = 2;

__device__ __forceinline__ int refl(int i, int L) {
    i = i < 0 ? -i : i;
    return i >= L ? 2 * (L - 1) - i : i;
}

// float -> sortable u32 (strictly increasing bijection), and inverse
__device__ __forceinline__ unsigned f2s(float f) {
    unsigned u = __float_as_uint(f);
    return u ^ (0x80000000u | (unsigned)((int)u >> 31));
}
__device__ __forceinline__ float s2f(unsigned s) {
    unsigned u = (s & 0x80000000u) ? (s ^ 0x80000000u) : ~s;
    return __uint_as_float(u);
}

// ---------------- Kernel A: fused depthwise 3x3 (q,k,v) + bias + relu ----------------
// One pass: load the 9-neighborhood once, apply all three weight sets (27 fma).
// Weights/bias are block-uniform (c = bc&127) -> scalar loads.
__global__ __launch_bounds__(256) void dw3_kernel(
    const float* __restrict__ vid,
    const float* __restrict__ wq, const float* __restrict__ bq,
    const float* __restrict__ wk, const float* __restrict__ bk,
    const float* __restrict__ wv, const float* __restrict__ bv,
    float* __restrict__ yq, float* __restrict__ yk, float* __restrict__ yv)
{
    int pix = blockIdx.x * 256 + threadIdx.x;
    int bc  = blockIdx.y;            // b*C + c
    int c   = bc & (Cc - 1);
    int y = pix >> 7, x = pix & (Wd - 1);
    const float* src = vid + bc * HWc;
    const float* wpq = wq + c * 9;
    const float* wpk = wk + c * 9;
    const float* wpv = wv + c * 9;
    float aq = 0.f, ak = 0.f, av = 0.f;
    #pragma unroll
    for (int ky = 0; ky < 3; ++ky) {
        int iy = y + ky - 1;
        if (iy < 0 || iy >= Hd) continue;
        #pragma unroll
        for (int kx = 0; kx < 3; ++kx) {
            int ix = x + kx - 1;
            if (ix < 0 || ix >= Wd) continue;
            float v = src[iy * Wd + ix];
            int k = ky * 3 + kx;
            aq = fmaf(v, wpq[k], aq);
            ak = fmaf(v, wpk[k], ak);
            av = fmaf(v, wpv[k], av);
        }
    }
    int o = bc * HWc + pix;
    yq[o] = fmaxf(aq + bq[c], 0.f);
    yk[o] = fmaxf(ak + bk[c], 0.f);
    yv[o] = fmaxf(av + bv[c], 0.f);
}

// ---------------- Kernel B/D: pointwise GEMM, float4 micro-tile, direct stores -------
__global__ __launch_bounds__(256) void pw_kernel(
    const float* y0p, const float* y1p, const float* y2p,
    const float* __restrict__ w0,  const float* __restrict__ w1,  const float* __restrict__ w2,
    const float* __restrict__ b0,  const float* __restrict__ b1,  const float* __restrict__ b2,
    float* o0, float* o1, float* o2,
    float scale0)
{
    extern __shared__ float lds[];
    float* wl = lds;            // [64 cc][132]
    float* yl = lds + 8448;     // [64 cc][128 p]

    int z = blockIdx.z;
    const float* yin  = z == 0 ? y0p : (z == 1 ? y1p : y2p);
    const float* wmat = z == 0 ? w0  : (z == 1 ? w1  : w2);
    const float* bias = z == 0 ? b0  : (z == 1 ? b1  : b2);
    float* out        = z == 0 ? o0  : (z == 1 ? o1  : o2);
    float scale       = z == 0 ? scale0 : 1.f;

    int tid = threadIdx.x;
    int ot = tid & 15, pt = tid >> 4;
    int gp  = blockIdx.x * 128;
    int b   = gp >> 14;
    int pof = gp & (HWc - 1);
    const float* yb = yin + b * Cc * HWc + pof;

    float acc[2][2][4][4];
    #pragma unroll
    for (int a = 0; a < 2; ++a)
        #pragma unroll
        for (int c = 0; c < 2; ++c)
            #pragma unroll
            for (int i = 0; i < 4; ++i)
                #pragma unroll
                for (int j = 0; j < 4; ++j) acc[a][c][i][j] = 0.f;

    for (int kh = 0; kh < 2; ++kh) {
        int c0 = kh * 64;
        for (int i = tid; i < 8192; i += 256) {
            int cc = i & 63, o = i >> 6;
            wl[cc * 132 + o] = wmat[o * 128 + c0 + cc];
        }
        for (int i = tid; i < 8192; i += 256) {
            int p = i & 127, cc = i >> 7;
            yl[cc * 128 + p] = yb[(c0 + cc) * HWc + p];
        }
        __syncthreads();
        #pragma unroll 4
        for (int cc = 0; cc < 64; ++cc) {
            float4 wv[2], pv[2];
            wv[0] = *(const float4*)(wl + cc * 132 + 4 * ot);
            wv[1] = *(const float4*)(wl + cc * 132 + 64 + 4 * ot);
            pv[0] = *(const float4*)(yl + cc * 128 + 4 * pt);
            pv[1] = *(const float4*)(yl + cc * 128 + 64 + 4 * pt);
            #pragma unroll
            for (int oh = 0; oh < 2; ++oh) {
                const float wo[4] = {wv[oh].x, wv[oh].y, wv[oh].z, wv[oh].w};
                #pragma unroll
                for (int ph = 0; ph < 2; ++ph) {
                    const float pp[4] = {pv[ph].x, pv[ph].y, pv[ph].z, pv[ph].w};
                    #pragma unroll
                    for (int oi = 0; oi < 4; ++oi)
                        #pragma unroll
                        for (int pi = 0; pi < 4; ++pi)
                            acc[oh][ph][oi][pi] = fmaf(wo[oi], pp[pi], acc[oh][ph][oi][pi]);
                }
            }
        }
        __syncthreads();
    }

    float* ob = out + b * Cc * HWc + pof;
    #pragma unroll
    for (int oh = 0; oh < 2; ++oh)
        #pragma unroll
        for (int oi = 0; oi < 4; ++oi) {
            int o = oh * 64 + 4 * ot + oi;
            float bo = bias[o];
            float* row = ob + o * HWc;
            #pragma unroll
            for (int ph = 0; ph < 2; ++ph) {
                float4 v;
                v.x = (acc[oh][ph][oi][0] + bo) * scale;
                v.y = (acc[oh][ph][oi][1] + bo) * scale;
                v.z = (acc[oh][ph][oi][2] + bo) * scale;
                v.w = (acc[oh][ph][oi][3] + bo) * scale;
                *(float4*)(row + ph * 64 + 4 * pt) = v;
            }
        }
}

// ---------------- Kernel C: fused neighborhood attention, XCD-head affinity -----------
// 1-D grid 4096; decode bn = bid&7 so round-robin block->XCD dispatch pins each XCD to
// ONE head: its k+v+q working set (~6 MB) ~fits the per-XCD 4 MB L2 (vs 48 MB shared
// before -> 123 MB HBM refetch). 8x4 pixel tile, 256 threads, 8 lanes/pixel.
// q staged once in LDS (pad-36: broadcast + conflict-free reads) instead of 8x
// redundant global loads. att written over q's buffer: every access (q stage read,
// att write) touches only the block's OWN 32 pixels -> race-free in-place.
__global__ __launch_bounds__(256, 2) void attn_kernel(
    const float* q, const float* __restrict__ kk,
    const float* __restrict__ vv, float* att)
{
    __shared__ float reg_l[165 * 36];      // K then V region [165 pix][36]
    __shared__ float q_l[32 * 36];         // q [32 pix][36] (only [0..31] used per pix)
    __shared__ int go_l[165];
    __shared__ unsigned ent_l[32 * 16];
    int tid = threadIdx.x;
    int bid = blockIdx.x;
    int bn = bid & 7;                      // head-on-XCD affinity
    int t  = bid >> 3;
    int x0 = (t & 15) * 8, y0 = (t >> 4) * 4;
    const float* kb = kk + bn * 32 * HWc;
    const float* vb = vv + bn * 32 * HWc;

    if (tid < 165) {
        int ry = tid / 15, rx = tid - ry * 15;
        go_l[tid] = refl(y0 - 4 + ry, Hd) * Wd + refl(x0 - 4 + rx, Wd);
    }
    __syncthreads();

    int qq = tid & 7;
    int pl = tid >> 3;             // pixel 0..31
    int px = pl & 7, py = pl >> 3;
    int gq = (y0 + py) * Wd + (x0 + px);

    // ================= stage K (1320 float4 units) + q (1024 floats) =============
    {
        int cb = tid & 7;
        const float* kc = kb + cb * 4 * HWc;
        for (int u = tid; u < 1320; u += 256) {
            int pix = u >> 3;
            int go = go_l[pix];
            float4 v;
            v.x = kc[go];
            v.y = kc[HWc + go];
            v.z = kc[2 * HWc + go];
            v.w = kc[3 * HWc + go];
            *(float4*)(reg_l + pix * 36 + cb * 4) = v;
        }
        const float* qb = q + bn * 32 * HWc;
        #pragma unroll
        for (int u = tid; u < 1024; u += 256) {
            int c = u >> 5, pix = u & 31;
            q_l[pix * 36 + c] = qb[c * HWc + (y0 + (pix >> 3)) * Wd + x0 + (pix & 7)];
        }
    }
    __syncthreads();

    // ================= QK: my 8 offsets (row dy=qq) x all 32 channels ============
    float d[8];
    #pragma unroll
    for (int i = 0; i < 8; ++i) d[i] = 0.f;
    {
        const float* myr = reg_l + ((py + qq) * 15 + px) * 36;
        const float* myq = q_l + pl * 36;
        #pragma unroll
        for (int cq = 0; cq < 8; ++cq) {
            const float4 q4 = *(const float4*)(myq + cq * 4);
            #pragma unroll
            for (int j = 0; j < 8; ++j) {
                const float4 kv = *(const float4*)(myr + j * 36 + cq * 4);
                d[j] = fmaf(q4.x, kv.x, fmaf(q4.y, kv.y, fmaf(q4.z, kv.z, fmaf(q4.w, kv.w, d[j]))));
            }
        }
    }
    unsigned s[8];
    #pragma unroll
    for (int i = 0; i < 8; ++i) s[i] = f2s(d[i]);
    __syncthreads();   // all QK reads of the K region complete

    // ================= stage V (overwrites region; latency overlaps ranking) =====
    {
        int cb = tid & 7;
        const float* vc = vb + cb * 4 * HWc;
        for (int u = tid; u < 1320; u += 256) {
            int pix = u >> 3;
            int go = go_l[pix];
            float4 v;
            v.x = vc[go];
            v.y = vc[HWc + go];
            v.z = vc[2 * HWc + go];
            v.w = vc[3 * HWc + go];
            *(float4*)(reg_l + pix * 36 + cb * 4) = v;
        }
    }

    // ================= cooperative top-16 ranking (byte counters) ================
    unsigned rkc[8];
    #pragma unroll
    for (int i = 0; i < 8; ++i) rkc[i] = 0u;
    #pragma unroll
    for (int i = 0; i < 7; ++i) {
        #pragma unroll
        for (int j = i + 1; j < 8; ++j) {
            rkc[i] += (unsigned)(s[j] > s[i]);   // j (higher idx) beats i on strict >
            rkc[j] += (unsigned)(s[i] >= s[j]);  // i (lower idx) beats j on >=
        }
    }
    #pragma unroll
    for (int m = 1; m <= 7; ++m) {
        unsigned plow = ((m >= 4) ? (qq >> 2) : (m >= 2) ? (qq >> 1) : qq) & 1;
        #pragma unroll
        for (int j = 0; j < 8; ++j) {
            unsigned spa = __shfl_xor(s[j], m) + plow;   // beat <=> spa > s_i
            #pragma unroll
            for (int i = 0; i < 8; ++i)
                rkc[i] += (unsigned)(spa > s[i]);
        }
    }

    // ================= softmax over the selected 16 (8-lane butterfly) ===========
    unsigned smax = s[0];
    #pragma unroll
    for (int i = 1; i < 8; ++i) smax = max(smax, s[i]);
    smax = max(smax, (unsigned)__shfl_xor(smax, 1));
    smax = max(smax, (unsigned)__shfl_xor(smax, 2));
    smax = max(smax, (unsigned)__shfl_xor(smax, 4));
    float dmax = s2f(smax);
    float w[8];
    float sum = 0.f;
    #pragma unroll
    for (int i = 0; i < 8; ++i) {
        float e = (rkc[i] < 16u) ? __expf(s2f(s[i]) - dmax) : 0.f;
        w[i] = e;
        sum += e;
    }
    sum += __shfl_xor(sum, 1);
    sum += __shfl_xor(sum, 2);
    sum += __shfl_xor(sum, 4);
    float inv = 1.0f / sum;

    // ---- scatter selected (weight fp16, offset) entries to LDS by rank
    #pragma unroll
    for (int i = 0; i < 8; ++i) {
        if (rkc[i] < 16u) {
            unsigned hb = __half_as_ushort(__float2half(w[i]));
            ent_l[pl * 16 + rkc[i]] = (hb << 16) | (unsigned)(qq * 8 + i);
        }
    }
    __syncthreads();   // V staged + entries visible

    // ================= PV: my channel quad over the 16 selected offsets ==========
    uint4 ea = *(const uint4*)(ent_l + pl * 16);
    uint4 eb = *(const uint4*)(ent_l + pl * 16 + 4);
    uint4 ec = *(const uint4*)(ent_l + pl * 16 + 8);
    uint4 ed = *(const uint4*)(ent_l + pl * 16 + 12);
    unsigned ent[16] = {ea.x, ea.y, ea.z, ea.w, eb.x, eb.y, eb.z, eb.w,
                        ec.x, ec.y, ec.z, ec.w, ed.x, ed.y, ed.z, ed.w};
    float a0 = 0.f, a1 = 0.f, a2 = 0.f, a3 = 0.f;
    const float* base = reg_l + (py * 15 + px) * 36 + qq * 4;
    #pragma unroll
    for (int e = 0; e < 16; ++e) {
        unsigned en = ent[e];
        int tt = en & 63;
        int dy = tt >> 3, dx = tt & 7;
        float wg = __half2float(__ushort_as_half((unsigned short)(en >> 16)));
        const float4 v4 = *(const float4*)(base + (dy * 15 + dx) * 36);
        a0 = fmaf(wg, v4.x, a0);
        a1 = fmaf(wg, v4.y, a1);
        a2 = fmaf(wg, v4.z, a2);
        a3 = fmaf(wg, v4.w, a3);
    }

    float* op = att + (bn * 32 + qq * 4) * HWc + gq;
    op[0]       = a0 * inv;
    op[HWc]     = a1 * inv;
    op[2 * HWc] = a2 * inv;
    op[3 * HWc] = a3 * inv;
}

// ---------------------------------- launcher ------------------------------------------
extern "C" void kernel_launch(void* const* d_in, const int* in_sizes, int n_in,
                              void* d_out, int out_size, void* d_ws, size_t ws_size,
                              hipStream_t stream)
{
    const float* vid  = (const float*)d_in[0];
    const float* qdww = (const float*)d_in[1];
    const float* qdwb = (const float*)d_in[2];
    const float* qpww = (const float*)d_in[3];
    const float* qpwb = (const float*)d_in[4];
    const float* kdww = (const float*)d_in[5];
    const float* kdwb = (const float*)d_in[6];
    const float* kpww = (const float*)d_in[7];
    const float* kpwb = (const float*)d_in[8];
    const float* vdww = (const float*)d_in[9];
    const float* vdwb = (const float*)d_in[10];
    const float* vpww = (const float*)d_in[11];
    const float* vpwb = (const float*)d_in[12];
    const float* pjw  = (const float*)d_in[13];
    const float* pjb  = (const float*)d_in[14];

    float* ws = (float*)d_ws;
    const size_t SZ = (size_t)Bc * Cc * HWc;   // 16 MB each; total ws use 48 MB
    float* buf0 = ws;            // q-dw -> q -> att (in-place, own-tile accesses only)
    float* buf1 = ws + SZ;       // k-dw -> k
    float* buf2 = ws + 2 * SZ;   // v-dw -> v

    hipFuncSetAttribute((const void*)pw_kernel, hipFuncAttributeMaxDynamicSharedMemorySize, 66560);

    dw3_kernel<<<dim3(HWc / 256, Bc * Cc), 256, 0, stream>>>(
        vid, qdww, qdwb, kdww, kdwb, vdww, vdwb, buf0, buf1, buf2);

    const float scale = 0.17677669529663687f;
    pw_kernel<<<dim3((Bc * HWc) / 128, 1, 3), 256, 66560, stream>>>(
        buf0, buf1, buf2, qpww, kpww, vpww, qpwb, kpwb, vpwb, buf0, buf1, buf2, scale);

    attn_kernel<<<dim3(4096, 1, 1), 256, 0, stream>>>(
        buf0, buf1, buf2, buf0);

    pw_kernel<<<dim3((Bc * HWc) / 128, 1, 1), 256, 66560, stream>>>(
        buf0, buf0, buf0, pjw, pjw, pjw, pjb, pjb, pjb, (float*)d_out, (float*)d_out, (float*)d_out, 1.f);
}

// Round 17
// 193.657 us; speedup vs baseline: 7.9271x; 1.0110x over previous
//
#include <hip/hip_runtime.h>
#include <hip/hip_fp16.h>

static constexpr int Wd  = 128;
static constexpr int Hd  = 128;
static constexpr int HWc = Wd * Hd;    // 16384
static constexpr int Cc  = 128;
static constexpr int NHc = 4;
static constexpr int Bc  = 2;

__device__ __forceinline__ int refl(int i, int L) {
    i = i < 0 ? -i : i;
    return i >= L ? 2 * (L - 1) - i : i;
}

// float -> sortable u32 (strictly increasing bijection), and inverse
__device__ __forceinline__ unsigned f2s(float f) {
    unsigned u = __float_as_uint(f);
    return u ^ (0x80000000u | (unsigned)((int)u >> 31));
}
__device__ __forceinline__ float s2f(unsigned s) {
    unsigned u = (s & 0x80000000u) ? (s ^ 0x80000000u) : ~s;
    return __uint_as_float(u);
}

// ---------------- Kernel A: fused depthwise 3x3 (q,k,v) + bias + relu ----------------
__global__ __launch_bounds__(256) void dw3_kernel(
    const float* __restrict__ vid,
    const float* __restrict__ wq, const float* __restrict__ bq,
    const float* __restrict__ wk, const float* __restrict__ bk,
    const float* __restrict__ wv, const float* __restrict__ bv,
    float* __restrict__ yq, float* __restrict__ yk, float* __restrict__ yv)
{
    int pix = blockIdx.x * 256 + threadIdx.x;
    int bc  = blockIdx.y;            // b*C + c
    int c   = bc & (Cc - 1);
    int y = pix >> 7, x = pix & (Wd - 1);
    const float* src = vid + bc * HWc;
    const float* wpq = wq + c * 9;
    const float* wpk = wk + c * 9;
    const float* wpv = wv + c * 9;
    float aq = 0.f, ak = 0.f, av = 0.f;
    #pragma unroll
    for (int ky = 0; ky < 3; ++ky) {
        int iy = y + ky - 1;
        if (iy < 0 || iy >= Hd) continue;
        #pragma unroll
        for (int kx = 0; kx < 3; ++kx) {
            int ix = x + kx - 1;
            if (ix < 0 || ix >= Wd) continue;
            float v = src[iy * Wd + ix];
            int k = ky * 3 + kx;
            aq = fmaf(v, wpq[k], aq);
            ak = fmaf(v, wpk[k], ak);
            av = fmaf(v, wpv[k], av);
        }
    }
    int o = bc * HWc + pix;
    yq[o] = fmaxf(aq + bq[c], 0.f);
    yk[o] = fmaxf(ak + bk[c], 0.f);
    yv[o] = fmaxf(av + bv[c], 0.f);
}

// ---------------- Kernel B/D: pointwise GEMM, float4 micro-tile, direct stores -------
__global__ __launch_bounds__(256) void pw_kernel(
    const float* y0p, const float* y1p, const float* y2p,
    const float* __restrict__ w0,  const float* __restrict__ w1,  const float* __restrict__ w2,
    const float* __restrict__ b0,  const float* __restrict__ b1,  const float* __restrict__ b2,
    float* o0, float* o1, float* o2,
    float scale0)
{
    extern __shared__ float lds[];
    float* wl = lds;            // [64 cc][132]
    float* yl = lds + 8448;     // [64 cc][128 p]

    int z = blockIdx.z;
    const float* yin  = z == 0 ? y0p : (z == 1 ? y1p : y2p);
    const float* wmat = z == 0 ? w0  : (z == 1 ? w1  : w2);
    const float* bias = z == 0 ? b0  : (z == 1 ? b1  : b2);
    float* out        = z == 0 ? o0  : (z == 1 ? o1  : o2);
    float scale       = z == 0 ? scale0 : 1.f;

    int tid = threadIdx.x;
    int ot = tid & 15, pt = tid >> 4;
    int gp  = blockIdx.x * 128;
    int b   = gp >> 14;
    int pof = gp & (HWc - 1);
    const float* yb = yin + b * Cc * HWc + pof;

    float acc[2][2][4][4];
    #pragma unroll
    for (int a = 0; a < 2; ++a)
        #pragma unroll
        for (int c = 0; c < 2; ++c)
            #pragma unroll
            for (int i = 0; i < 4; ++i)
                #pragma unroll
                for (int j = 0; j < 4; ++j) acc[a][c][i][j] = 0.f;

    for (int kh = 0; kh < 2; ++kh) {
        int c0 = kh * 64;
        for (int i = tid; i < 8192; i += 256) {
            int cc = i & 63, o = i >> 6;
            wl[cc * 132 + o] = wmat[o * 128 + c0 + cc];
        }
        for (int i = tid; i < 8192; i += 256) {
            int p = i & 127, cc = i >> 7;
            yl[cc * 128 + p] = yb[(c0 + cc) * HWc + p];
        }
        __syncthreads();
        #pragma unroll 4
        for (int cc = 0; cc < 64; ++cc) {
            float4 wv[2], pv[2];
            wv[0] = *(const float4*)(wl + cc * 132 + 4 * ot);
            wv[1] = *(const float4*)(wl + cc * 132 + 64 + 4 * ot);
            pv[0] = *(const float4*)(yl + cc * 128 + 4 * pt);
            pv[1] = *(const float4*)(yl + cc * 128 + 64 + 4 * pt);
            #pragma unroll
            for (int oh = 0; oh < 2; ++oh) {
                const float wo[4] = {wv[oh].x, wv[oh].y, wv[oh].z, wv[oh].w};
                #pragma unroll
                for (int ph = 0; ph < 2; ++ph) {
                    const float pp[4] = {pv[ph].x, pv[ph].y, pv[ph].z, pv[ph].w};
                    #pragma unroll
                    for (int oi = 0; oi < 4; ++oi)
                        #pragma unroll
                        for (int pi = 0; pi < 4; ++pi)
                            acc[oh][ph][oi][pi] = fmaf(wo[oi], pp[pi], acc[oh][ph][oi][pi]);
                }
            }
        }
        __syncthreads();
    }

    float* ob = out + b * Cc * HWc + pof;
    #pragma unroll
    for (int oh = 0; oh < 2; ++oh)
        #pragma unroll
        for (int oi = 0; oi < 4; ++oi) {
            int o = oh * 64 + 4 * ot + oi;
            float bo = bias[o];
            float* row = ob + o * HWc;
            #pragma unroll
            for (int ph = 0; ph < 2; ++ph) {
                float4 v;
                v.x = (acc[oh][ph][oi][0] + bo) * scale;
                v.y = (acc[oh][ph][oi][1] + bo) * scale;
                v.z = (acc[oh][ph][oi][2] + bo) * scale;
                v.w = (acc[oh][ph][oi][3] + bo) * scale;
                *(float4*)(row + ph * 64 + 4 * pt) = v;
            }
        }
}

// ---------------- Kernel C: fused neighborhood attention, 8x8 tile, swizzled LDS ------
// 512 threads, 8 lanes/pixel (pl=tid>>3, qq=tid&7). 8x8 pixel tile: halo ratio
// 450/64 staged-pixels-per-output vs 330/32 at 8x4 (-35% staging). Region 15x15=225,
// LDS 46.6 KB -> 3 blocks/CU (24 waves = 75% ceiling vs 31% measured at 8x4).
// K/V region is QUAD-XOR-SWIZZLED: quad cb of pixel pix lives at
// pix*36 + ((cb ^ (pix>>3))&7)*4. Rationale: QK lanes (px,qq) read pixel
// p=15(py+qq)+px+j; any linear layout maps the 64 lanes onto 8 bank-groups with an
// 8-lane kernel (class px-qq mod 8) -> 8-way conflict (measured 1.04e7 cyc). The
// (pix>>3) XOR bit differs across the class (p spans 16*qq) -> ~2-way residual, free.
// XCD-head affinity (bn=bid&7) kept: FETCH 123->24.7 MB proven in round 16.
__global__ __launch_bounds__(512, 2) void attn_kernel(
    const float* q, const float* __restrict__ kk,
    const float* __restrict__ vv, float* att)
{
    __shared__ float reg_l[225 * 36];      // K then V region, quad-swizzled
    __shared__ float q_l[64 * 36];         // q [64 pix][36], linear
    __shared__ int go_l[225];
    __shared__ unsigned ent_l[64 * 16];
    int tid = threadIdx.x;
    int bid = blockIdx.x;
    int bn = bid & 7;                      // head-on-XCD affinity
    int t  = bid >> 3;                     // 0..255
    int x0 = (t & 15) * 8, y0 = (t >> 4) * 8;
    const float* kb = kk + bn * 32 * HWc;
    const float* vb = vv + bn * 32 * HWc;

    if (tid < 225) {
        int ry = tid / 15, rx = tid - ry * 15;
        go_l[tid] = refl(y0 - 4 + ry, Hd) * Wd + refl(x0 - 4 + rx, Wd);
    }
    __syncthreads();

    int qq = tid & 7;
    int pl = tid >> 3;             // pixel 0..63
    int px = pl & 7, py = pl >> 3;
    int gq = (y0 + py) * Wd + (x0 + px);

    // ================= stage K (1800 quad units) + q (2048 floats) ===============
    {
        int cb = tid & 7;
        const float* kc = kb + cb * 4 * HWc;
        for (int u = tid; u < 1800; u += 512) {
            int pix = u >> 3;
            int go = go_l[pix];
            float4 v;
            v.x = kc[go];
            v.y = kc[HWc + go];
            v.z = kc[2 * HWc + go];
            v.w = kc[3 * HWc + go];
            int sw = (cb ^ (pix >> 3)) & 7;
            *(float4*)(reg_l + pix * 36 + sw * 4) = v;
        }
        const float* qb = q + bn * 32 * HWc;
        for (int u = tid; u < 2048; u += 512) {
            int c = u >> 6, pix = u & 63;
            q_l[pix * 36 + c] = qb[c * HWc + (y0 + (pix >> 3)) * Wd + x0 + (pix & 7)];
        }
    }
    __syncthreads();

    // ================= QK: my 8 offsets (row dy=qq) x all 32 channels ============
    float d[8];
    #pragma unroll
    for (int i = 0; i < 8; ++i) d[i] = 0.f;
    {
        int base_p = (py + qq) * 15 + px;
        int roff[8];
        unsigned swb[8];
        #pragma unroll
        for (int j = 0; j < 8; ++j) {
            roff[j] = (base_p + j) * 36;
            swb[j] = (unsigned)(((base_p + j) >> 3) & 7);
        }
        const float* myq = q_l + pl * 36;
        #pragma unroll
        for (int cq = 0; cq < 8; ++cq) {
            const float4 q4 = *(const float4*)(myq + cq * 4);
            #pragma unroll
            for (int j = 0; j < 8; ++j) {
                const float4 kv = *(const float4*)(reg_l + roff[j] + (((unsigned)cq ^ swb[j]) << 2));
                d[j] = fmaf(q4.x, kv.x, fmaf(q4.y, kv.y, fmaf(q4.z, kv.z, fmaf(q4.w, kv.w, d[j]))));
            }
        }
    }
    unsigned s[8];
    #pragma unroll
    for (int i = 0; i < 8; ++i) s[i] = f2s(d[i]);
    __syncthreads();   // all QK reads of the K region complete

    // ================= stage V (overwrites region; latency overlaps ranking) =====
    {
        int cb = tid & 7;
        const float* vc = vb + cb * 4 * HWc;
        for (int u = tid; u < 1800; u += 512) {
            int pix = u >> 3;
            int go = go_l[pix];
            float4 v;
            v.x = vc[go];
            v.y = vc[HWc + go];
            v.z = vc[2 * HWc + go];
            v.w = vc[3 * HWc + go];
            int sw = (cb ^ (pix >> 3)) & 7;
            *(float4*)(reg_l + pix * 36 + sw * 4) = v;
        }
    }

    // ================= cooperative top-16 ranking (byte counters) ================
    unsigned rkc[8];
    #pragma unroll
    for (int i = 0; i < 8; ++i) rkc[i] = 0u;
    #pragma unroll
    for (int i = 0; i < 7; ++i) {
        #pragma unroll
        for (int j = i + 1; j < 8; ++j) {
            rkc[i] += (unsigned)(s[j] > s[i]);   // j (higher idx) beats i on strict >
            rkc[j] += (unsigned)(s[i] >= s[j]);  // i (lower idx) beats j on >=
        }
    }
    #pragma unroll
    for (int m = 1; m <= 7; ++m) {
        unsigned plow = ((m >= 4) ? (qq >> 2) : (m >= 2) ? (qq >> 1) : qq) & 1;
        #pragma unroll
        for (int j = 0; j < 8; ++j) {
            unsigned spa = __shfl_xor(s[j], m) + plow;   // beat <=> spa > s_i
            #pragma unroll
            for (int i = 0; i < 8; ++i)
                rkc[i] += (unsigned)(spa > s[i]);
        }
    }

    // ================= softmax over the selected 16 (8-lane butterfly) ===========
    unsigned smax = s[0];
    #pragma unroll
    for (int i = 1; i < 8; ++i) smax = max(smax, s[i]);
    smax = max(smax, (unsigned)__shfl_xor(smax, 1));
    smax = max(smax, (unsigned)__shfl_xor(smax, 2));
    smax = max(smax, (unsigned)__shfl_xor(smax, 4));
    float dmax = s2f(smax);
    float w[8];
    float sum = 0.f;
    #pragma unroll
    for (int i = 0; i < 8; ++i) {
        float e = (rkc[i] < 16u) ? __expf(s2f(s[i]) - dmax) : 0.f;
        w[i] = e;
        sum += e;
    }
    sum += __shfl_xor(sum, 1);
    sum += __shfl_xor(sum, 2);
    sum += __shfl_xor(sum, 4);
    float inv = 1.0f / sum;

    // ---- scatter selected (weight fp16, offset) entries to LDS by rank
    #pragma unroll
    for (int i = 0; i < 8; ++i) {
        if (rkc[i] < 16u) {
            unsigned hb = __half_as_ushort(__float2half(w[i]));
            ent_l[pl * 16 + rkc[i]] = (hb << 16) | (unsigned)(qq * 8 + i);
        }
    }
    __syncthreads();   // V staged + entries visible

    // ================= PV: my channel quad (qq) over the 16 selected offsets =====
    uint4 ea = *(const uint4*)(ent_l + pl * 16);
    uint4 eb = *(const uint4*)(ent_l + pl * 16 + 4);
    uint4 ec = *(const uint4*)(ent_l + pl * 16 + 8);
    uint4 ed = *(const uint4*)(ent_l + pl * 16 + 12);
    unsigned ent[16] = {ea.x, ea.y, ea.z, ea.w, eb.x, eb.y, eb.z, eb.w,
                        ec.x, ec.y, ec.z, ec.w, ed.x, ed.y, ed.z, ed.w};
    float a0 = 0.f, a1 = 0.f, a2 = 0.f, a3 = 0.f;
    int pbase = py * 15 + px;
    #pragma unroll
    for (int e = 0; e < 16; ++e) {
        unsigned en = ent[e];
        int tt = en & 63;
        int dy = tt >> 3, dx = tt & 7;
        int pe = pbase + dy * 15 + dx;
        float wg = __half2float(__ushort_as_half((unsigned short)(en >> 16)));
        const float4 v4 = *(const float4*)(reg_l + pe * 36 + ((((unsigned)qq ^ (unsigned)((pe >> 3) & 7))) << 2));
        a0 = fmaf(wg, v4.x, a0);
        a1 = fmaf(wg, v4.y, a1);
        a2 = fmaf(wg, v4.z, a2);
        a3 = fmaf(wg, v4.w, a3);
    }

    float* op = att + (bn * 32 + qq * 4) * HWc + gq;
    op[0]       = a0 * inv;
    op[HWc]     = a1 * inv;
    op[2 * HWc] = a2 * inv;
    op[3 * HWc] = a3 * inv;
}

// ---------------------------------- launcher ------------------------------------------
extern "C" void kernel_launch(void* const* d_in, const int* in_sizes, int n_in,
                              void* d_out, int out_size, void* d_ws, size_t ws_size,
                              hipStream_t stream)
{
    const float* vid  = (const float*)d_in[0];
    const float* qdww = (const float*)d_in[1];
    const float* qdwb = (const float*)d_in[2];
    const float* qpww = (const float*)d_in[3];
    const float* qpwb = (const float*)d_in[4];
    const float* kdww = (const float*)d_in[5];
    const float* kdwb = (const float*)d_in[6];
    const float* kpww = (const float*)d_in[7];
    const float* kpwb = (const float*)d_in[8];
    const float* vdww = (const float*)d_in[9];
    const float* vdwb = (const float*)d_in[10];
    const float* vpww = (const float*)d_in[11];
    const float* vpwb = (const float*)d_in[12];
    const float* pjw  = (const float*)d_in[13];
    const float* pjb  = (const float*)d_in[14];

    float* ws = (float*)d_ws;
    const size_t SZ = (size_t)Bc * Cc * HWc;   // 16 MB each; total ws use 48 MB
    float* buf0 = ws;            // q-dw -> q -> att (in-place, own-tile accesses only)
    float* buf1 = ws + SZ;       // k-dw -> k
    float* buf2 = ws + 2 * SZ;   // v-dw -> v

    hipFuncSetAttribute((const void*)pw_kernel, hipFuncAttributeMaxDynamicSharedMemorySize, 66560);

    dw3_kernel<<<dim3(HWc / 256, Bc * Cc), 256, 0, stream>>>(
        vid, qdww, qdwb, kdww, kdwb, vdww, vdwb, buf0, buf1, buf2);

    const float scale = 0.17677669529663687f;
    pw_kernel<<<dim3((Bc * HWc) / 128, 1, 3), 256, 66560, stream>>>(
        buf0, buf1, buf2, qpww, kpww, vpww, qpwb, kpwb, vpwb, buf0, buf1, buf2, scale);

    attn_kernel<<<dim3(2048, 1, 1), 512, 0, stream>>>(
        buf0, buf1, buf2, buf0);

    pw_kernel<<<dim3((Bc * HWc) / 128, 1, 1), 256, 66560, stream>>>(
        buf0, buf0, buf0, pjw, pjw, pjw, pjb, pjb, pjb, (float*)d_out, (float*)d_out, (float*)d_out, 1.f);
}

// Round 18
// 190.784 us; speedup vs baseline: 8.0465x; 1.0151x over previous
//
#include <hip/hip_runtime.h>
#include <hip/hip_fp16.h>

static constexpr int Wd  = 128;
static constexpr int Hd  = 128;
static constexpr int HWc = Wd * Hd;    // 16384
static constexpr int Cc  = 128;
static constexpr int NHc = 4;
static constexpr int Bc  = 2;

__device__ __forceinline__ int refl(int i, int L) {
    i = i < 0 ? -i : i;
    return i >= L ? 2 * (L - 1) - i : i;
}

// float -> sortable u32 (strictly increasing bijection), and inverse
__device__ __forceinline__ unsigned f2s(float f) {
    unsigned u = __float_as_uint(f);
    return u ^ (0x80000000u | (unsigned)((int)u >> 31));
}
__device__ __forceinline__ float s2f(unsigned s) {
    unsigned u = (s & 0x80000000u) ? (s ^ 0x80000000u) : ~s;
    return __uint_as_float(u);
}

// ---------------- Kernel A: fused depthwise 3x3 (q,k,v) + bias + relu ----------------
__global__ __launch_bounds__(256) void dw3_kernel(
    const float* __restrict__ vid,
    const float* __restrict__ wq, const float* __restrict__ bq,
    const float* __restrict__ wk, const float* __restrict__ bk,
    const float* __restrict__ wv, const float* __restrict__ bv,
    float* __restrict__ yq, float* __restrict__ yk, float* __restrict__ yv)
{
    int pix = blockIdx.x * 256 + threadIdx.x;
    int bc  = blockIdx.y;            // b*C + c
    int c   = bc & (Cc - 1);
    int y = pix >> 7, x = pix & (Wd - 1);
    const float* src = vid + bc * HWc;
    const float* wpq = wq + c * 9;
    const float* wpk = wk + c * 9;
    const float* wpv = wv + c * 9;
    float aq = 0.f, ak = 0.f, av = 0.f;
    #pragma unroll
    for (int ky = 0; ky < 3; ++ky) {
        int iy = y + ky - 1;
        if (iy < 0 || iy >= Hd) continue;
        #pragma unroll
        for (int kx = 0; kx < 3; ++kx) {
            int ix = x + kx - 1;
            if (ix < 0 || ix >= Wd) continue;
            float v = src[iy * Wd + ix];
            int k = ky * 3 + kx;
            aq = fmaf(v, wpq[k], aq);
            ak = fmaf(v, wpk[k], ak);
            av = fmaf(v, wpv[k], av);
        }
    }
    int o = bc * HWc + pix;
    yq[o] = fmaxf(aq + bq[c], 0.f);
    yk[o] = fmaxf(ak + bk[c], 0.f);
    yv[o] = fmaxf(av + bv[c], 0.f);
}

// ---------------- Kernel B/D: pointwise GEMM, float4 micro-tile, direct stores -------
__global__ __launch_bounds__(256) void pw_kernel(
    const float* y0p, const float* y1p, const float* y2p,
    const float* __restrict__ w0,  const float* __restrict__ w1,  const float* __restrict__ w2,
    const float* __restrict__ b0,  const float* __restrict__ b1,  const float* __restrict__ b2,
    float* o0, float* o1, float* o2,
    float scale0)
{
    extern __shared__ float lds[];
    float* wl = lds;            // [64 cc][132]
    float* yl = lds + 8448;     // [64 cc][128 p]

    int z = blockIdx.z;
    const float* yin  = z == 0 ? y0p : (z == 1 ? y1p : y2p);
    const float* wmat = z == 0 ? w0  : (z == 1 ? w1  : w2);
    const float* bias = z == 0 ? b0  : (z == 1 ? b1  : b2);
    float* out        = z == 0 ? o0  : (z == 1 ? o1  : o2);
    float scale       = z == 0 ? scale0 : 1.f;

    int tid = threadIdx.x;
    int ot = tid & 15, pt = tid >> 4;
    int gp  = blockIdx.x * 128;
    int b   = gp >> 14;
    int pof = gp & (HWc - 1);
    const float* yb = yin + b * Cc * HWc + pof;

    float acc[2][2][4][4];
    #pragma unroll
    for (int a = 0; a < 2; ++a)
        #pragma unroll
        for (int c = 0; c < 2; ++c)
            #pragma unroll
            for (int i = 0; i < 4; ++i)
                #pragma unroll
                for (int j = 0; j < 4; ++j) acc[a][c][i][j] = 0.f;

    for (int kh = 0; kh < 2; ++kh) {
        int c0 = kh * 64;
        for (int i = tid; i < 8192; i += 256) {
            int cc = i & 63, o = i >> 6;
            wl[cc * 132 + o] = wmat[o * 128 + c0 + cc];
        }
        for (int i = tid; i < 8192; i += 256) {
            int p = i & 127, cc = i >> 7;
            yl[cc * 128 + p] = yb[(c0 + cc) * HWc + p];
        }
        __syncthreads();
        #pragma unroll 4
        for (int cc = 0; cc < 64; ++cc) {
            float4 wv[2], pv[2];
            wv[0] = *(const float4*)(wl + cc * 132 + 4 * ot);
            wv[1] = *(const float4*)(wl + cc * 132 + 64 + 4 * ot);
            pv[0] = *(const float4*)(yl + cc * 128 + 4 * pt);
            pv[1] = *(const float4*)(yl + cc * 128 + 64 + 4 * pt);
            #pragma unroll
            for (int oh = 0; oh < 2; ++oh) {
                const float wo[4] = {wv[oh].x, wv[oh].y, wv[oh].z, wv[oh].w};
                #pragma unroll
                for (int ph = 0; ph < 2; ++ph) {
                    const float pp[4] = {pv[ph].x, pv[ph].y, pv[ph].z, pv[ph].w};
                    #pragma unroll
                    for (int oi = 0; oi < 4; ++oi)
                        #pragma unroll
                        for (int pi = 0; pi < 4; ++pi)
                            acc[oh][ph][oi][pi] = fmaf(wo[oi], pp[pi], acc[oh][ph][oi][pi]);
                }
            }
        }
        __syncthreads();
    }

    float* ob = out + b * Cc * HWc + pof;
    #pragma unroll
    for (int oh = 0; oh < 2; ++oh)
        #pragma unroll
        for (int oi = 0; oi < 4; ++oi) {
            int o = oh * 64 + 4 * ot + oi;
            float bo = bias[o];
            float* row = ob + o * HWc;
            #pragma unroll
            for (int ph = 0; ph < 2; ++ph) {
                float4 v;
                v.x = (acc[oh][ph][oi][0] + bo) * scale;
                v.y = (acc[oh][ph][oi][1] + bo) * scale;
                v.z = (acc[oh][ph][oi][2] + bo) * scale;
                v.w = (acc[oh][ph][oi][3] + bo) * scale;
                *(float4*)(row + ph * 64 + 4 * pt) = v;
            }
        }
}

// ---------------- Kernel C: fused neighborhood attention, 4-blocks/CU LDS diet --------
// 8x8 tile, 512 threads, 8 lanes/pixel (pl=tid>>3, qq=tid&7).
// LDS budget (round-18 lever): SoA region [8 quads][225 pix][4] = 28.8 KB (no pad
// waste; bank class (quad+pix)%8 uniform for staging/QK/PV), q_l [64][36] = 9.2 KB
// with ent_l ALIASED into it (q_l reads all finish before the mid-barrier; ent writes
// all after -> race-free union), go 0.9 KB. Total 38.9 KB -> 4 blocks/CU -> 32-wave
// ceiling (round-17: 47.1 KB -> 3 blocks, occupancy 43%). Swizzle removed: measured
// null (conflicts 1.04e7 -> 1.06e7); access classes already uniform.
// XCD-head affinity (bn=bid&7) kept: FETCH 123 -> 24.7 MB proven in round 16.
__global__ __launch_bounds__(512, 2) void attn_kernel(
    const float* q, const float* __restrict__ kk,
    const float* __restrict__ vv, float* att)
{
    __shared__ float reg_l[8 * 225 * 4];   // SoA K/V region: quad*900 + pix*4
    __shared__ float q_l[64 * 36];         // q during QK; ent_l aliases afterwards
    __shared__ int go_l[225];
    unsigned* ent_l = (unsigned*)q_l;
    int tid = threadIdx.x;
    int bid = blockIdx.x;
    int bn = bid & 7;                      // head-on-XCD affinity
    int t  = bid >> 3;                     // 0..255
    int x0 = (t & 15) * 8, y0 = (t >> 4) * 8;
    const float* kb = kk + bn * 32 * HWc;
    const float* vb = vv + bn * 32 * HWc;

    if (tid < 225) {
        int ry = tid / 15, rx = tid - ry * 15;
        go_l[tid] = refl(y0 - 4 + ry, Hd) * Wd + refl(x0 - 4 + rx, Wd);
    }
    __syncthreads();

    int qq = tid & 7;
    int pl = tid >> 3;             // pixel 0..63
    int px = pl & 7, py = pl >> 3;
    int gq = (y0 + py) * Wd + (x0 + px);

    // ================= stage K (1800 quad units, SoA) + q (2048 floats) ==========
    {
        int cb = tid & 7;
        const float* kc = kb + cb * 4 * HWc;
        float* rq = reg_l + cb * 900;
        for (int u = tid; u < 1800; u += 512) {
            int pix = u >> 3;
            int go = go_l[pix];
            float4 v;
            v.x = kc[go];
            v.y = kc[HWc + go];
            v.z = kc[2 * HWc + go];
            v.w = kc[3 * HWc + go];
            *(float4*)(rq + pix * 4) = v;
        }
        const float* qb = q + bn * 32 * HWc;
        for (int u = tid; u < 2048; u += 512) {
            int c = u >> 6, pix = u & 63;
            q_l[pix * 36 + c] = qb[c * HWc + (y0 + (pix >> 3)) * Wd + x0 + (pix & 7)];
        }
    }
    __syncthreads();

    // ================= QK: my 8 offsets (row dy=qq) x all 32 channels ============
    float d[8];
    #pragma unroll
    for (int i = 0; i < 8; ++i) d[i] = 0.f;
    {
        int base_p = (py + qq) * 15 + px;
        const float* myq = q_l + pl * 36;
        #pragma unroll
        for (int cq = 0; cq < 8; ++cq) {
            const float4 q4 = *(const float4*)(myq + cq * 4);
            const float* rq = reg_l + cq * 900 + base_p * 4;
            #pragma unroll
            for (int j = 0; j < 8; ++j) {
                const float4 kv = *(const float4*)(rq + j * 4);
                d[j] = fmaf(q4.x, kv.x, fmaf(q4.y, kv.y, fmaf(q4.z, kv.z, fmaf(q4.w, kv.w, d[j]))));
            }
        }
    }
    unsigned s[8];
    #pragma unroll
    for (int i = 0; i < 8; ++i) s[i] = f2s(d[i]);
    __syncthreads();   // all QK reads (region K + q_l) complete

    // ================= stage V (overwrites region; latency overlaps ranking) =====
    {
        int cb = tid & 7;
        const float* vc = vb + cb * 4 * HWc;
        float* rq = reg_l + cb * 900;
        for (int u = tid; u < 1800; u += 512) {
            int pix = u >> 3;
            int go = go_l[pix];
            float4 v;
            v.x = vc[go];
            v.y = vc[HWc + go];
            v.z = vc[2 * HWc + go];
            v.w = vc[3 * HWc + go];
            *(float4*)(rq + pix * 4) = v;
        }
    }

    // ================= cooperative top-16 ranking (byte counters) ================
    unsigned rkc[8];
    #pragma unroll
    for (int i = 0; i < 8; ++i) rkc[i] = 0u;
    #pragma unroll
    for (int i = 0; i < 7; ++i) {
        #pragma unroll
        for (int j = i + 1; j < 8; ++j) {
            rkc[i] += (unsigned)(s[j] > s[i]);   // j (higher idx) beats i on strict >
            rkc[j] += (unsigned)(s[i] >= s[j]);  // i (lower idx) beats j on >=
        }
    }
    #pragma unroll
    for (int m = 1; m <= 7; ++m) {
        unsigned plow = ((m >= 4) ? (qq >> 2) : (m >= 2) ? (qq >> 1) : qq) & 1;
        #pragma unroll
        for (int j = 0; j < 8; ++j) {
            unsigned spa = __shfl_xor(s[j], m) + plow;   // beat <=> spa > s_i
            #pragma unroll
            for (int i = 0; i < 8; ++i)
                rkc[i] += (unsigned)(spa > s[i]);
        }
    }

    // ================= softmax over the selected 16 (8-lane butterfly) ===========
    unsigned smax = s[0];
    #pragma unroll
    for (int i = 1; i < 8; ++i) smax = max(smax, s[i]);
    smax = max(smax, (unsigned)__shfl_xor(smax, 1));
    smax = max(smax, (unsigned)__shfl_xor(smax, 2));
    smax = max(smax, (unsigned)__shfl_xor(smax, 4));
    float dmax = s2f(smax);
    float w[8];
    float sum = 0.f;
    #pragma unroll
    for (int i = 0; i < 8; ++i) {
        float e = (rkc[i] < 16u) ? __expf(s2f(s[i]) - dmax) : 0.f;
        w[i] = e;
        sum += e;
    }
    sum += __shfl_xor(sum, 1);
    sum += __shfl_xor(sum, 2);
    sum += __shfl_xor(sum, 4);
    float inv = 1.0f / sum;

    // ---- scatter selected (weight fp16, offset) entries into ent_l (aliases q_l;
    //      safe: all q_l reads completed before the mid-barrier above)
    #pragma unroll
    for (int i = 0; i < 8; ++i) {
        if (rkc[i] < 16u) {
            unsigned hb = __half_as_ushort(__float2half(w[i]));
            ent_l[pl * 16 + rkc[i]] = (hb << 16) | (unsigned)(qq * 8 + i);
        }
    }
    __syncthreads();   // V staged + entries visible

    // ================= PV: my channel quad (qq) over the 16 selected offsets =====
    uint4 ea = *(const uint4*)(ent_l + pl * 16);
    uint4 eb = *(const uint4*)(ent_l + pl * 16 + 4);
    uint4 ec = *(const uint4*)(ent_l + pl * 16 + 8);
    uint4 ed = *(const uint4*)(ent_l + pl * 16 + 12);
    unsigned ent[16] = {ea.x, ea.y, ea.z, ea.w, eb.x, eb.y, eb.z, eb.w,
                        ec.x, ec.y, ec.z, ec.w, ed.x, ed.y, ed.z, ed.w};
    float a0 = 0.f, a1 = 0.f, a2 = 0.f, a3 = 0.f;
    int pbase = py * 15 + px;
    const float* rq = reg_l + qq * 900;
    #pragma unroll
    for (int e = 0; e < 16; ++e) {
        unsigned en = ent[e];
        int tt = en & 63;
        int dy = tt >> 3, dx = tt & 7;
        float wg = __half2float(__ushort_as_half((unsigned short)(en >> 16)));
        const float4 v4 = *(const float4*)(rq + (pbase + dy * 15 + dx) * 4);
        a0 = fmaf(wg, v4.x, a0);
        a1 = fmaf(wg, v4.y, a1);
        a2 = fmaf(wg, v4.z, a2);
        a3 = fmaf(wg, v4.w, a3);
    }

    float* op = att + (bn * 32 + qq * 4) * HWc + gq;
    op[0]       = a0 * inv;
    op[HWc]     = a1 * inv;
    op[2 * HWc] = a2 * inv;
    op[3 * HWc] = a3 * inv;
}

// ---------------------------------- launcher ------------------------------------------
extern "C" void kernel_launch(void* const* d_in, const int* in_sizes, int n_in,
                              void* d_out, int out_size, void* d_ws, size_t ws_size,
                              hipStream_t stream)
{
    const float* vid  = (const float*)d_in[0];
    const float* qdww = (const float*)d_in[1];
    const float* qdwb = (const float*)d_in[2];
    const float* qpww = (const float*)d_in[3];
    const float* qpwb = (const float*)d_in[4];
    const float* kdww = (const float*)d_in[5];
    const float* kdwb = (const float*)d_in[6];
    const float* kpww = (const float*)d_in[7];
    const float* kpwb = (const float*)d_in[8];
    const float* vdww = (const float*)d_in[9];
    const float* vdwb = (const float*)d_in[10];
    const float* vpww = (const float*)d_in[11];
    const float* vpwb = (const float*)d_in[12];
    const float* pjw  = (const float*)d_in[13];
    const float* pjb  = (const float*)d_in[14];

    float* ws = (float*)d_ws;
    const size_t SZ = (size_t)Bc * Cc * HWc;   // 16 MB each; total ws use 48 MB
    float* buf0 = ws;            // q-dw -> q -> att (in-place, own-tile accesses only)
    float* buf1 = ws + SZ;       // k-dw -> k
    float* buf2 = ws + 2 * SZ;   // v-dw -> v

    hipFuncSetAttribute((const void*)pw_kernel, hipFuncAttributeMaxDynamicSharedMemorySize, 66560);

    dw3_kernel<<<dim3(HWc / 256, Bc * Cc), 256, 0, stream>>>(
        vid, qdww, qdwb, kdww, kdwb, vdww, vdwb, buf0, buf1, buf2);

    const float scale = 0.17677669529663687f;
    pw_kernel<<<dim3((Bc * HWc) / 128, 1, 3), 256, 66560, stream>>>(
        buf0, buf1, buf2, qpww, kpww, vpww, qpwb, kpwb, vpwb, buf0, buf1, buf2, scale);

    attn_kernel<<<dim3(2048, 1, 1), 512, 0, stream>>>(
        buf0, buf1, buf2, buf0);

    pw_kernel<<<dim3((Bc * HWc) / 128, 1, 1), 256, 66560, stream>>>(
        buf0, buf0, buf0, pjw, pjw, pjw, pjb, pjb, pjb, (float*)d_out, (float*)d_out, (float*)d_out, 1.f);
}

// Round 19
// 189.791 us; speedup vs baseline: 8.0886x; 1.0052x over previous
//
#include <hip/hip_runtime.h>
#include <hip/hip_fp16.h>

static constexpr int Wd  = 128;
static constexpr int Hd  = 128;
static constexpr int HWc = Wd * Hd;    // 16384
static constexpr int Cc  = 128;
static constexpr int NHc = 4;
static constexpr int Bc  = 2;

__device__ __forceinline__ int refl(int i, int L) {
    i = i < 0 ? -i : i;
    return i >= L ? 2 * (L - 1) - i : i;
}

// float -> sortable u32 (strictly increasing bijection), and inverse
__device__ __forceinline__ unsigned f2s(float f) {
    unsigned u = __float_as_uint(f);
    return u ^ (0x80000000u | (unsigned)((int)u >> 31));
}
__device__ __forceinline__ float s2f(unsigned s) {
    unsigned u = (s & 0x80000000u) ? (s ^ 0x80000000u) : ~s;
    return __uint_as_float(u);
}

// ---------------- Kernel A: fused depthwise 3x3 (q,k,v) + bias + relu ----------------
__global__ __launch_bounds__(256) void dw3_kernel(
    const float* __restrict__ vid,
    const float* __restrict__ wq, const float* __restrict__ bq,
    const float* __restrict__ wk, const float* __restrict__ bk,
    const float* __restrict__ wv, const float* __restrict__ bv,
    float* __restrict__ yq, float* __restrict__ yk, float* __restrict__ yv)
{
    int pix = blockIdx.x * 256 + threadIdx.x;
    int bc  = blockIdx.y;            // b*C + c
    int c   = bc & (Cc - 1);
    int y = pix >> 7, x = pix & (Wd - 1);
    const float* src = vid + bc * HWc;
    const float* wpq = wq + c * 9;
    const float* wpk = wk + c * 9;
    const float* wpv = wv + c * 9;
    float aq = 0.f, ak = 0.f, av = 0.f;
    #pragma unroll
    for (int ky = 0; ky < 3; ++ky) {
        int iy = y + ky - 1;
        if (iy < 0 || iy >= Hd) continue;
        #pragma unroll
        for (int kx = 0; kx < 3; ++kx) {
            int ix = x + kx - 1;
            if (ix < 0 || ix >= Wd) continue;
            float v = src[iy * Wd + ix];
            int k = ky * 3 + kx;
            aq = fmaf(v, wpq[k], aq);
            ak = fmaf(v, wpk[k], ak);
            av = fmaf(v, wpv[k], av);
        }
    }
    int o = bc * HWc + pix;
    yq[o] = fmaxf(aq + bq[c], 0.f);
    yk[o] = fmaxf(ak + bk[c], 0.f);
    yv[o] = fmaxf(av + bv[c], 0.f);
}

// ---------------- Kernel B/D: pointwise GEMM, 128o x 64p tile -------------------------
// Round-19 re-tile: 64 pixels/block halves LDS to 51.2 KB -> 3 blocks/CU (was 66.5 KB
// -> 2) and doubles the grid (qkv 1536, proj 512) -> occupancy ceiling 37.5%/25% vs
// 25%/12.5%. pw was occupancy-bound: fp32 VALU floor for all 4 convs is ~27 us but
// they took ~62 us at 1-2 blocks/CU. In-place safe: p-split only -- each block reads
// exactly its own 64-pixel column (all c) before the final barrier, then writes it.
__global__ __launch_bounds__(256) void pw_kernel(
    const float* y0p, const float* y1p, const float* y2p,
    const float* __restrict__ w0,  const float* __restrict__ w1,  const float* __restrict__ w2,
    const float* __restrict__ b0,  const float* __restrict__ b1,  const float* __restrict__ b2,
    float* o0, float* o1, float* o2,
    float scale0)
{
    extern __shared__ float lds[];
    float* wl = lds;            // [64 cc][132]  (o-transposed weights)
    float* yl = lds + 8448;     // [64 cc][68]   (64 pixels + pad)

    int z = blockIdx.z;
    const float* yin  = z == 0 ? y0p : (z == 1 ? y1p : y2p);
    const float* wmat = z == 0 ? w0  : (z == 1 ? w1  : w2);
    const float* bias = z == 0 ? b0  : (z == 1 ? b1  : b2);
    float* out        = z == 0 ? o0  : (z == 1 ? o1  : o2);
    float scale       = z == 0 ? scale0 : 1.f;

    int tid = threadIdx.x;
    int ot = tid & 15, pt = tid >> 4;
    int gp  = blockIdx.x * 64;
    int b   = gp >> 14;
    int pof = gp & (HWc - 1);
    const float* yb = yin + b * Cc * HWc + pof;

    float acc[2][4][4];            // [oh][oi][pi]
    #pragma unroll
    for (int a = 0; a < 2; ++a)
        #pragma unroll
        for (int i = 0; i < 4; ++i)
            #pragma unroll
            for (int j = 0; j < 4; ++j) acc[a][i][j] = 0.f;

    for (int kh = 0; kh < 2; ++kh) {
        int c0 = kh * 64;
        // stage weights: 64c x 128o (transposed; lanes vary cc -> coalesced)
        for (int i = tid; i < 8192; i += 256) {
            int cc = i & 63, o = i >> 6;
            wl[cc * 132 + o] = wmat[o * 128 + c0 + cc];
        }
        // stage y tile: 64c x 64p (lanes vary p -> coalesced)
        for (int i = tid; i < 4096; i += 256) {
            int p = i & 63, cc = i >> 6;
            yl[cc * 68 + p] = yb[(c0 + cc) * HWc + p];
        }
        __syncthreads();
        #pragma unroll 4
        for (int cc = 0; cc < 64; ++cc) {
            float4 wv[2];
            wv[0] = *(const float4*)(wl + cc * 132 + 4 * ot);
            wv[1] = *(const float4*)(wl + cc * 132 + 64 + 4 * ot);
            const float4 pv = *(const float4*)(yl + cc * 68 + 4 * pt);
            const float pp[4] = {pv.x, pv.y, pv.z, pv.w};
            #pragma unroll
            for (int oh = 0; oh < 2; ++oh) {
                const float wo[4] = {wv[oh].x, wv[oh].y, wv[oh].z, wv[oh].w};
                #pragma unroll
                for (int oi = 0; oi < 4; ++oi)
                    #pragma unroll
                    for (int pi = 0; pi < 4; ++pi)
                        acc[oh][oi][pi] = fmaf(wo[oi], pp[pi], acc[oh][oi][pi]);
            }
        }
        __syncthreads();
    }

    float* ob = out + b * Cc * HWc + pof;
    #pragma unroll
    for (int oh = 0; oh < 2; ++oh)
        #pragma unroll
        for (int oi = 0; oi < 4; ++oi) {
            int o = oh * 64 + 4 * ot + oi;
            float bo = bias[o];
            float4 v;
            v.x = (acc[oh][oi][0] + bo) * scale;
            v.y = (acc[oh][oi][1] + bo) * scale;
            v.z = (acc[oh][oi][2] + bo) * scale;
            v.w = (acc[oh][oi][3] + bo) * scale;
            *(float4*)(ob + o * HWc + 4 * pt) = v;
        }
}

// ---------------- Kernel C: fused neighborhood attention (unchanged from r18) ---------
__global__ __launch_bounds__(512, 2) void attn_kernel(
    const float* q, const float* __restrict__ kk,
    const float* __restrict__ vv, float* att)
{
    __shared__ float reg_l[8 * 225 * 4];   // SoA K/V region: quad*900 + pix*4
    __shared__ float q_l[64 * 36];         // q during QK; ent_l aliases afterwards
    __shared__ int go_l[225];
    unsigned* ent_l = (unsigned*)q_l;
    int tid = threadIdx.x;
    int bid = blockIdx.x;
    int bn = bid & 7;                      // head-on-XCD affinity
    int t  = bid >> 3;                     // 0..255
    int x0 = (t & 15) * 8, y0 = (t >> 4) * 8;
    const float* kb = kk + bn * 32 * HWc;
    const float* vb = vv + bn * 32 * HWc;

    if (tid < 225) {
        int ry = tid / 15, rx = tid - ry * 15;
        go_l[tid] = refl(y0 - 4 + ry, Hd) * Wd + refl(x0 - 4 + rx, Wd);
    }
    __syncthreads();

    int qq = tid & 7;
    int pl = tid >> 3;             // pixel 0..63
    int px = pl & 7, py = pl >> 3;
    int gq = (y0 + py) * Wd + (x0 + px);

    // ================= stage K (1800 quad units, SoA) + q (2048 floats) ==========
    {
        int cb = tid & 7;
        const float* kc = kb + cb * 4 * HWc;
        float* rq = reg_l + cb * 900;
        for (int u = tid; u < 1800; u += 512) {
            int pix = u >> 3;
            int go = go_l[pix];
            float4 v;
            v.x = kc[go];
            v.y = kc[HWc + go];
            v.z = kc[2 * HWc + go];
            v.w = kc[3 * HWc + go];
            *(float4*)(rq + pix * 4) = v;
        }
        const float* qb = q + bn * 32 * HWc;
        for (int u = tid; u < 2048; u += 512) {
            int c = u >> 6, pix = u & 63;
            q_l[pix * 36 + c] = qb[c * HWc + (y0 + (pix >> 3)) * Wd + x0 + (pix & 7)];
        }
    }
    __syncthreads();

    // ================= QK: my 8 offsets (row dy=qq) x all 32 channels ============
    float d[8];
    #pragma unroll
    for (int i = 0; i < 8; ++i) d[i] = 0.f;
    {
        int base_p = (py + qq) * 15 + px;
        const float* myq = q_l + pl * 36;
        #pragma unroll
        for (int cq = 0; cq < 8; ++cq) {
            const float4 q4 = *(const float4*)(myq + cq * 4);
            const float* rq = reg_l + cq * 900 + base_p * 4;
            #pragma unroll
            for (int j = 0; j < 8; ++j) {
                const float4 kv = *(const float4*)(rq + j * 4);
                d[j] = fmaf(q4.x, kv.x, fmaf(q4.y, kv.y, fmaf(q4.z, kv.z, fmaf(q4.w, kv.w, d[j]))));
            }
        }
    }
    unsigned s[8];
    #pragma unroll
    for (int i = 0; i < 8; ++i) s[i] = f2s(d[i]);
    __syncthreads();   // all QK reads (region K + q_l) complete

    // ================= stage V (overwrites region; latency overlaps ranking) =====
    {
        int cb = tid & 7;
        const float* vc = vb + cb * 4 * HWc;
        float* rq = reg_l + cb * 900;
        for (int u = tid; u < 1800; u += 512) {
            int pix = u >> 3;
            int go = go_l[pix];
            float4 v;
            v.x = vc[go];
            v.y = vc[HWc + go];
            v.z = vc[2 * HWc + go];
            v.w = vc[3 * HWc + go];
            *(float4*)(rq + pix * 4) = v;
        }
    }

    // ================= cooperative top-16 ranking (byte counters) ================
    unsigned rkc[8];
    #pragma unroll
    for (int i = 0; i < 8; ++i) rkc[i] = 0u;
    #pragma unroll
    for (int i = 0; i < 7; ++i) {
        #pragma unroll
        for (int j = i + 1; j < 8; ++j) {
            rkc[i] += (unsigned)(s[j] > s[i]);   // j (higher idx) beats i on strict >
            rkc[j] += (unsigned)(s[i] >= s[j]);  // i (lower idx) beats j on >=
        }
    }
    #pragma unroll
    for (int m = 1; m <= 7; ++m) {
        unsigned plow = ((m >= 4) ? (qq >> 2) : (m >= 2) ? (qq >> 1) : qq) & 1;
        #pragma unroll
        for (int j = 0; j < 8; ++j) {
            unsigned spa = __shfl_xor(s[j], m) + plow;   // beat <=> spa > s_i
            #pragma unroll
            for (int i = 0; i < 8; ++i)
                rkc[i] += (unsigned)(spa > s[i]);
        }
    }

    // ================= softmax over the selected 16 (8-lane butterfly) ===========
    unsigned smax = s[0];
    #pragma unroll
    for (int i = 1; i < 8; ++i) smax = max(smax, s[i]);
    smax = max(smax, (unsigned)__shfl_xor(smax, 1));
    smax = max(smax, (unsigned)__shfl_xor(smax, 2));
    smax = max(smax, (unsigned)__shfl_xor(smax, 4));
    float dmax = s2f(smax);
    float w[8];
    float sum = 0.f;
    #pragma unroll
    for (int i = 0; i < 8; ++i) {
        float e = (rkc[i] < 16u) ? __expf(s2f(s[i]) - dmax) : 0.f;
        w[i] = e;
        sum += e;
    }
    sum += __shfl_xor(sum, 1);
    sum += __shfl_xor(sum, 2);
    sum += __shfl_xor(sum, 4);
    float inv = 1.0f / sum;

    // ---- scatter selected (weight fp16, offset) entries into ent_l (aliases q_l;
    //      safe: all q_l reads completed before the mid-barrier above)
    #pragma unroll
    for (int i = 0; i < 8; ++i) {
        if (rkc[i] < 16u) {
            unsigned hb = __half_as_ushort(__float2half(w[i]));
            ent_l[pl * 16 + rkc[i]] = (hb << 16) | (unsigned)(qq * 8 + i);
        }
    }
    __syncthreads();   // V staged + entries visible

    // ================= PV: my channel quad (qq) over the 16 selected offsets =====
    uint4 ea = *(const uint4*)(ent_l + pl * 16);
    uint4 eb = *(const uint4*)(ent_l + pl * 16 + 4);
    uint4 ec = *(const uint4*)(ent_l + pl * 16 + 8);
    uint4 ed = *(const uint4*)(ent_l + pl * 16 + 12);
    unsigned ent[16] = {ea.x, ea.y, ea.z, ea.w, eb.x, eb.y, eb.z, eb.w,
                        ec.x, ec.y, ec.z, ec.w, ed.x, ed.y, ed.z, ed.w};
    float a0 = 0.f, a1 = 0.f, a2 = 0.f, a3 = 0.f;
    int pbase = py * 15 + px;
    const float* rq = reg_l + qq * 900;
    #pragma unroll
    for (int e = 0; e < 16; ++e) {
        unsigned en = ent[e];
        int tt = en & 63;
        int dy = tt >> 3, dx = tt & 7;
        float wg = __half2float(__ushort_as_half((unsigned short)(en >> 16)));
        const float4 v4 = *(const float4*)(rq + (pbase + dy * 15 + dx) * 4);
        a0 = fmaf(wg, v4.x, a0);
        a1 = fmaf(wg, v4.y, a1);
        a2 = fmaf(wg, v4.z, a2);
        a3 = fmaf(wg, v4.w, a3);
    }

    float* op = att + (bn * 32 + qq * 4) * HWc + gq;
    op[0]       = a0 * inv;
    op[HWc]     = a1 * inv;
    op[2 * HWc] = a2 * inv;
    op[3 * HWc] = a3 * inv;
}

// ---------------------------------- launcher ------------------------------------------
extern "C" void kernel_launch(void* const* d_in, const int* in_sizes, int n_in,
                              void* d_out, int out_size, void* d_ws, size_t ws_size,
                              hipStream_t stream)
{
    const float* vid  = (const float*)d_in[0];
    const float* qdww = (const float*)d_in[1];
    const float* qdwb = (const float*)d_in[2];
    const float* qpww = (const float*)d_in[3];
    const float* qpwb = (const float*)d_in[4];
    const float* kdww = (const float*)d_in[5];
    const float* kdwb = (const float*)d_in[6];
    const float* kpww = (const float*)d_in[7];
    const float* kpwb = (const float*)d_in[8];
    const float* vdww = (const float*)d_in[9];
    const float* vdwb = (const float*)d_in[10];
    const float* vpww = (const float*)d_in[11];
    const float* vpwb = (const float*)d_in[12];
    const float* pjw  = (const float*)d_in[13];
    const float* pjb  = (const float*)d_in[14];

    float* ws = (float*)d_ws;
    const size_t SZ = (size_t)Bc * Cc * HWc;   // 16 MB each; total ws use 48 MB
    float* buf0 = ws;            // q-dw -> q -> att (in-place, own-tile accesses only)
    float* buf1 = ws + SZ;       // k-dw -> k
    float* buf2 = ws + 2 * SZ;   // v-dw -> v

    hipFuncSetAttribute((const void*)pw_kernel, hipFuncAttributeMaxDynamicSharedMemorySize, 51200);

    dw3_kernel<<<dim3(HWc / 256, Bc * Cc), 256, 0, stream>>>(
        vid, qdww, qdwb, kdww, kdwb, vdww, vdwb, buf0, buf1, buf2);

    const float scale = 0.17677669529663687f;
    pw_kernel<<<dim3((Bc * HWc) / 64, 1, 3), 256, 51200, stream>>>(
        buf0, buf1, buf2, qpww, kpww, vpww, qpwb, kpwb, vpwb, buf0, buf1, buf2, scale);

    attn_kernel<<<dim3(2048, 1, 1), 512, 0, stream>>>(
        buf0, buf1, buf2, buf0);

    pw_kernel<<<dim3((Bc * HWc) / 64, 1, 1), 256, 51200, stream>>>(
        buf0, buf0, buf0, pjw, pjw, pjw, pjb, pjb, pjb, (float*)d_out, (float*)d_out, (float*)d_out, 1.f);
}

// Round 20
// 180.664 us; speedup vs baseline: 8.4973x; 1.0505x over previous
//
#include <hip/hip_runtime.h>
#include <hip/hip_fp16.h>

static constexpr int Wd  = 128;
static constexpr int Hd  = 128;
static constexpr int HWc = Wd * Hd;    // 16384
static constexpr int Cc  = 128;
static constexpr int NHc = 4;
static constexpr int Bc  = 2;

__device__ __forceinline__ int refl(int i, int L) {
    i = i < 0 ? -i : i;
    return i >= L ? 2 * (L - 1) - i : i;
}

// float -> sortable u32 (strictly increasing bijection), and inverse
__device__ __forceinline__ unsigned f2s(float f) {
    unsigned u = __float_as_uint(f);
    return u ^ (0x80000000u | (unsigned)((int)u >> 31));
}
__device__ __forceinline__ float s2f(unsigned s) {
    unsigned u = (s & 0x80000000u) ? (s ^ 0x80000000u) : ~s;
    return __uint_as_float(u);
}

// ---------------- Kernel A: fused depthwise 3x3 (q,k,v) + bias + relu ----------------
__global__ __launch_bounds__(256) void dw3_kernel(
    const float* __restrict__ vid,
    const float* __restrict__ wq, const float* __restrict__ bq,
    const float* __restrict__ wk, const float* __restrict__ bk,
    const float* __restrict__ wv, const float* __restrict__ bv,
    float* __restrict__ yq, float* __restrict__ yk, float* __restrict__ yv)
{
    int pix = blockIdx.x * 256 + threadIdx.x;
    int bc  = blockIdx.y;            // b*C + c
    int c   = bc & (Cc - 1);
    int y = pix >> 7, x = pix & (Wd - 1);
    const float* src = vid + bc * HWc;
    const float* wpq = wq + c * 9;
    const float* wpk = wk + c * 9;
    const float* wpv = wv + c * 9;
    float aq = 0.f, ak = 0.f, av = 0.f;
    #pragma unroll
    for (int ky = 0; ky < 3; ++ky) {
        int iy = y + ky - 1;
        if (iy < 0 || iy >= Hd) continue;
        #pragma unroll
        for (int kx = 0; kx < 3; ++kx) {
            int ix = x + kx - 1;
            if (ix < 0 || ix >= Wd) continue;
            float v = src[iy * Wd + ix];
            int k = ky * 3 + kx;
            aq = fmaf(v, wpq[k], aq);
            ak = fmaf(v, wpk[k], ak);
            av = fmaf(v, wpv[k], av);
        }
    }
    int o = bc * HWc + pix;
    yq[o] = fmaxf(aq + bq[c], 0.f);
    yk[o] = fmaxf(ak + bk[c], 0.f);
    yv[o] = fmaxf(av + bv[c], 0.f);
}

// ---------------- Kernel B/D: pointwise GEMM, 128o x 64p tile -------------------------
__global__ __launch_bounds__(256) void pw_kernel(
    const float* y0p, const float* y1p, const float* y2p,
    const float* __restrict__ w0,  const float* __restrict__ w1,  const float* __restrict__ w2,
    const float* __restrict__ b0,  const float* __restrict__ b1,  const float* __restrict__ b2,
    float* o0, float* o1, float* o2,
    float scale0)
{
    extern __shared__ float lds[];
    float* wl = lds;            // [64 cc][132]  (o-transposed weights)
    float* yl = lds + 8448;     // [64 cc][68]   (64 pixels + pad)

    int z = blockIdx.z;
    const float* yin  = z == 0 ? y0p : (z == 1 ? y1p : y2p);
    const float* wmat = z == 0 ? w0  : (z == 1 ? w1  : w2);
    const float* bias = z == 0 ? b0  : (z == 1 ? b1  : b2);
    float* out        = z == 0 ? o0  : (z == 1 ? o1  : o2);
    float scale       = z == 0 ? scale0 : 1.f;

    int tid = threadIdx.x;
    int ot = tid & 15, pt = tid >> 4;
    int gp  = blockIdx.x * 64;
    int b   = gp >> 14;
    int pof = gp & (HWc - 1);
    const float* yb = yin + b * Cc * HWc + pof;

    float acc[2][4][4];            // [oh][oi][pi]
    #pragma unroll
    for (int a = 0; a < 2; ++a)
        #pragma unroll
        for (int i = 0; i < 4; ++i)
            #pragma unroll
            for (int j = 0; j < 4; ++j) acc[a][i][j] = 0.f;

    for (int kh = 0; kh < 2; ++kh) {
        int c0 = kh * 64;
        for (int i = tid; i < 8192; i += 256) {
            int cc = i & 63, o = i >> 6;
            wl[cc * 132 + o] = wmat[o * 128 + c0 + cc];
        }
        for (int i = tid; i < 4096; i += 256) {
            int p = i & 63, cc = i >> 6;
            yl[cc * 68 + p] = yb[(c0 + cc) * HWc + p];
        }
        __syncthreads();
        #pragma unroll 4
        for (int cc = 0; cc < 64; ++cc) {
            float4 wv[2];
            wv[0] = *(const float4*)(wl + cc * 132 + 4 * ot);
            wv[1] = *(const float4*)(wl + cc * 132 + 64 + 4 * ot);
            const float4 pv = *(const float4*)(yl + cc * 68 + 4 * pt);
            const float pp[4] = {pv.x, pv.y, pv.z, pv.w};
            #pragma unroll
            for (int oh = 0; oh < 2; ++oh) {
                const float wo[4] = {wv[oh].x, wv[oh].y, wv[oh].z, wv[oh].w};
                #pragma unroll
                for (int oi = 0; oi < 4; ++oi)
                    #pragma unroll
                    for (int pi = 0; pi < 4; ++pi)
                        acc[oh][oi][pi] = fmaf(wo[oi], pp[pi], acc[oh][oi][pi]);
            }
        }
        __syncthreads();
    }

    float* ob = out + b * Cc * HWc + pof;
    #pragma unroll
    for (int oh = 0; oh < 2; ++oh)
        #pragma unroll
        for (int oi = 0; oi < 4; ++oi) {
            int o = oh * 64 + 4 * ot + oi;
            float bo = bias[o];
            float4 v;
            v.x = (acc[oh][oi][0] + bo) * scale;
            v.y = (acc[oh][oi][1] + bo) * scale;
            v.z = (acc[oh][oi][2] + bo) * scale;
            v.w = (acc[oh][oi][3] + bo) * scale;
            *(float4*)(ob + o * HWc + 4 * pt) = v;
        }
}

// ---------------- Kernel C: fused neighborhood attention, SINGLE BARRIER --------------
// Round-20 structural change: rounds 17-19 showed attn pinned at ~118 us regardless of
// occupancy ceiling -> the cost is the 4-barrier phase chain (two serialized global
// staging latencies + 8-wave convergence each). New structure: K, V and q staged
// TOGETHER in one load burst into 66.8 KB dynamic LDS (single latency exposure), go
// table removed (reflect inline), and the entry scatter/readback made wave-internal:
// ent slots alias the pixel's own q slot (q_l + pl*36); a wave only reads its OWN 8
// pixels' q (all reads precede the scatter in program order) and the 8 producer lanes
// == the 8 consumer lanes -> no barrier needed. ONE __syncthreads total.
// XCD-head affinity kept (FETCH 123->24.7 MB, round 16). 2 blocks/CU.
__global__ __launch_bounds__(512, 2) void attn_kernel(
    const float* q, const float* __restrict__ kk,
    const float* __restrict__ vv, float* att)
{
    extern __shared__ float alds[];
    float* kreg = alds;                 // [8][225][4] K SoA
    float* vreg = alds + 7200;          // [8][225][4] V SoA
    float* q_l  = alds + 14400;         // [64][36]; ent aliases first 16 words/pixel
    int tid = threadIdx.x;
    int bid = blockIdx.x;
    int bn = bid & 7;                      // head-on-XCD affinity
    int t  = bid >> 3;                     // 0..255
    int x0 = (t & 15) * 8, y0 = (t >> 4) * 8;
    const float* kb = kk + bn * 32 * HWc;
    const float* vb = vv + bn * 32 * HWc;

    int qq = tid & 7;
    int pl = tid >> 3;             // pixel 0..63
    int px = pl & 7, py = pl >> 3;
    int gq = (y0 + py) * Wd + (x0 + px);

    // ========== stage K + V (1800 quad units each) + q (2048 floats), one burst =====
    {
        int cb = tid & 7;
        const float* kc = kb + cb * 4 * HWc;
        const float* vc = vb + cb * 4 * HWc;
        float* kq = kreg + cb * 900;
        float* vq = vreg + cb * 900;
        for (int u = tid; u < 1800; u += 512) {
            int pix = u >> 3;
            int ry = pix / 15, rx = pix - ry * 15;
            int go = refl(y0 - 4 + ry, Hd) * Wd + refl(x0 - 4 + rx, Wd);
            float4 a, b;
            a.x = kc[go];
            a.y = kc[HWc + go];
            a.z = kc[2 * HWc + go];
            a.w = kc[3 * HWc + go];
            b.x = vc[go];
            b.y = vc[HWc + go];
            b.z = vc[2 * HWc + go];
            b.w = vc[3 * HWc + go];
            *(float4*)(kq + pix * 4) = a;
            *(float4*)(vq + pix * 4) = b;
        }
        const float* qb = q + bn * 32 * HWc;
        for (int u = tid; u < 2048; u += 512) {
            int c = u >> 6, pix = u & 63;
            q_l[pix * 36 + c] = qb[c * HWc + (y0 + (pix >> 3)) * Wd + x0 + (pix & 7)];
        }
    }
    __syncthreads();   // the ONLY barrier

    // ========== QK: my 8 offsets (row dy=qq) x all 32 channels ======================
    float d[8];
    #pragma unroll
    for (int i = 0; i < 8; ++i) d[i] = 0.f;
    {
        int base_p = (py + qq) * 15 + px;
        const float* myq = q_l + pl * 36;
        #pragma unroll
        for (int cq = 0; cq < 8; ++cq) {
            const float4 q4 = *(const float4*)(myq + cq * 4);
            const float* rq = kreg + cq * 900 + base_p * 4;
            #pragma unroll
            for (int j = 0; j < 8; ++j) {
                const float4 kv = *(const float4*)(rq + j * 4);
                d[j] = fmaf(q4.x, kv.x, fmaf(q4.y, kv.y, fmaf(q4.z, kv.z, fmaf(q4.w, kv.w, d[j]))));
            }
        }
    }
    unsigned s[8];
    #pragma unroll
    for (int i = 0; i < 8; ++i) s[i] = f2s(d[i]);

    // ========== cooperative top-16 ranking (byte counters) ==========================
    unsigned rkc[8];
    #pragma unroll
    for (int i = 0; i < 8; ++i) rkc[i] = 0u;
    #pragma unroll
    for (int i = 0; i < 7; ++i) {
        #pragma unroll
        for (int j = i + 1; j < 8; ++j) {
            rkc[i] += (unsigned)(s[j] > s[i]);   // j (higher idx) beats i on strict >
            rkc[j] += (unsigned)(s[i] >= s[j]);  // i (lower idx) beats j on >=
        }
    }
    #pragma unroll
    for (int m = 1; m <= 7; ++m) {
        unsigned plow = ((m >= 4) ? (qq >> 2) : (m >= 2) ? (qq >> 1) : qq) & 1;
        #pragma unroll
        for (int j = 0; j < 8; ++j) {
            unsigned spa = __shfl_xor(s[j], m) + plow;   // beat <=> spa > s_i
            #pragma unroll
            for (int i = 0; i < 8; ++i)
                rkc[i] += (unsigned)(spa > s[i]);
        }
    }

    // ========== softmax over the selected 16 (8-lane butterfly) =====================
    unsigned smax = s[0];
    #pragma unroll
    for (int i = 1; i < 8; ++i) smax = max(smax, s[i]);
    smax = max(smax, (unsigned)__shfl_xor(smax, 1));
    smax = max(smax, (unsigned)__shfl_xor(smax, 2));
    smax = max(smax, (unsigned)__shfl_xor(smax, 4));
    float dmax = s2f(smax);
    float w[8];
    float sum = 0.f;
    #pragma unroll
    for (int i = 0; i < 8; ++i) {
        float e = (rkc[i] < 16u) ? __expf(s2f(s[i]) - dmax) : 0.f;
        w[i] = e;
        sum += e;
    }
    sum += __shfl_xor(sum, 1);
    sum += __shfl_xor(sum, 2);
    sum += __shfl_xor(sum, 4);
    float inv = 1.0f / sum;

    // ---- scatter selected entries into the pixel's own q slot (wave-internal:
    //      producers == consumers == the 8 lanes of this pixel group; this wave's
    //      q reads all completed above -> no barrier required)
    unsigned* entp = (unsigned*)(q_l + pl * 36);
    #pragma unroll
    for (int i = 0; i < 8; ++i) {
        if (rkc[i] < 16u) {
            unsigned hb = __half_as_ushort(__float2half(w[i]));
            entp[rkc[i]] = (hb << 16) | (unsigned)(qq * 8 + i);
        }
    }

    // ========== PV: my channel quad (qq) over the 16 selected offsets ===============
    uint4 ea = *(const uint4*)(entp);
    uint4 eb = *(const uint4*)(entp + 4);
    uint4 ec = *(const uint4*)(entp + 8);
    uint4 ed = *(const uint4*)(entp + 12);
    unsigned ent[16] = {ea.x, ea.y, ea.z, ea.w, eb.x, eb.y, eb.z, eb.w,
                        ec.x, ec.y, ec.z, ec.w, ed.x, ed.y, ed.z, ed.w};
    float a0 = 0.f, a1 = 0.f, a2 = 0.f, a3 = 0.f;
    int pbase = py * 15 + px;
    const float* rq = vreg + qq * 900;
    #pragma unroll
    for (int e = 0; e < 16; ++e) {
        unsigned en = ent[e];
        int tt = en & 63;
        int dy = tt >> 3, dx = tt & 7;
        float wg = __half2float(__ushort_as_half((unsigned short)(en >> 16)));
        const float4 v4 = *(const float4*)(rq + (pbase + dy * 15 + dx) * 4);
        a0 = fmaf(wg, v4.x, a0);
        a1 = fmaf(wg, v4.y, a1);
        a2 = fmaf(wg, v4.z, a2);
        a3 = fmaf(wg, v4.w, a3);
    }

    float* op = att + (bn * 32 + qq * 4) * HWc + gq;
    op[0]       = a0 * inv;
    op[HWc]     = a1 * inv;
    op[2 * HWc] = a2 * inv;
    op[3 * HWc] = a3 * inv;
}

// ---------------------------------- launcher ------------------------------------------
extern "C" void kernel_launch(void* const* d_in, const int* in_sizes, int n_in,
                              void* d_out, int out_size, void* d_ws, size_t ws_size,
                              hipStream_t stream)
{
    const float* vid  = (const float*)d_in[0];
    const float* qdww = (const float*)d_in[1];
    const float* qdwb = (const float*)d_in[2];
    const float* qpww = (const float*)d_in[3];
    const float* qpwb = (const float*)d_in[4];
    const float* kdww = (const float*)d_in[5];
    const float* kdwb = (const float*)d_in[6];
    const float* kpww = (const float*)d_in[7];
    const float* kpwb = (const float*)d_in[8];
    const float* vdww = (const float*)d_in[9];
    const float* vdwb = (const float*)d_in[10];
    const float* vpww = (const float*)d_in[11];
    const float* vpwb = (const float*)d_in[12];
    const float* pjw  = (const float*)d_in[13];
    const float* pjb  = (const float*)d_in[14];

    float* ws = (float*)d_ws;
    const size_t SZ = (size_t)Bc * Cc * HWc;   // 16 MB each; total ws use 48 MB
    float* buf0 = ws;            // q-dw -> q -> att (in-place, own-tile accesses only)
    float* buf1 = ws + SZ;       // k-dw -> k
    float* buf2 = ws + 2 * SZ;   // v-dw -> v

    hipFuncSetAttribute((const void*)pw_kernel,   hipFuncAttributeMaxDynamicSharedMemorySize, 51200);
    hipFuncSetAttribute((const void*)attn_kernel, hipFuncAttributeMaxDynamicSharedMemorySize, 66816);

    dw3_kernel<<<dim3(HWc / 256, Bc * Cc), 256, 0, stream>>>(
        vid, qdww, qdwb, kdww, kdwb, vdww, vdwb, buf0, buf1, buf2);

    const float scale = 0.17677669529663687f;
    pw_kernel<<<dim3((Bc * HWc) / 64, 1, 3), 256, 51200, stream>>>(
        buf0, buf1, buf2, qpww, kpww, vpww, qpwb, kpwb, vpwb, buf0, buf1, buf2, scale);

    attn_kernel<<<dim3(2048, 1, 1), 512, 66816, stream>>>(
        buf0, buf1, buf2, buf0);

    pw_kernel<<<dim3((Bc * HWc) / 64, 1, 1), 256, 51200, stream>>>(
        buf0, buf0, buf0, pjw, pjw, pjw, pjb, pjb, pjb, (float*)d_out, (float*)d_out, (float*)d_out, 1.f);
}